// Round 7
// baseline (989.626 us; speedup 1.0000x reference)
//
#include <hip/hip_runtime.h>
#include <hip/hip_bf16.h>
#include <stdint.h>

typedef __attribute__((ext_vector_type(8))) short bf16x8;
typedef __attribute__((ext_vector_type(4))) float f32x4;
typedef __attribute__((ext_vector_type(2))) float f32x2;
typedef __attribute__((ext_vector_type(4))) unsigned int u32x4;
typedef unsigned long long ull;

__device__ __forceinline__ void load_lds16(const void* g, void* l){
  __builtin_amdgcn_global_load_lds((const __attribute__((address_space(1))) void*)g,
                                   (__attribute__((address_space(3))) void*)l, 16, 0, 0);
}

__device__ __forceinline__ float bf2f(unsigned int u){
  union { unsigned int i; float f; } x; x.i = u << 16; return x.f;
}
__device__ __forceinline__ unsigned short f2bf(float f){
  __hip_bfloat16 h = __float2bfloat16(f);
  unsigned short u;
  __builtin_memcpy(&u, &h, 2);
  return u;
}

// ---------- conversions ----------
__global__ void cvt_x_kernel(const float4* __restrict__ in, ushort4* __restrict__ out, int n4){
  int i = blockIdx.x*256 + threadIdx.x;
  if (i < n4){
    float4 v = in[i];
    ushort4 o;
    o.x = f2bf(v.x); o.y = f2bf(v.y); o.z = f2bf(v.z); o.w = f2bf(v.w);
    out[i] = o;
  }
}

// Wt[n][k] = bf16(W[k][n]) for n < N, 0 for N <= n < Npad
__global__ void wtrans_kernel(const float* __restrict__ W, unsigned short* __restrict__ Wt,
                              int K, int N, int Npad){
  int idx = blockIdx.x*256 + threadIdx.x;
  if (idx >= Npad*K) return;
  int nn = idx / K, kk = idx - nn*K;
  float v = (nn < N) ? W[(size_t)kk*N + nn] : 0.f;
  Wt[idx] = f2bf(v);
}

// ---------- graph preprocessing ----------
// fused histogram over both edge sets
__global__ void hist2_kernel(const int* __restrict__ ei1, int E1, int* __restrict__ deg1,
                             const int* __restrict__ ei2, int E2, int* __restrict__ deg2){
  int set = blockIdx.y;
  const int* col = set ? (ei2 + E2) : (ei1 + E1);
  int E = set ? E2 : E1;
  int* deg = set ? deg2 : deg1;
  int i = blockIdx.x*256 + threadIdx.x;
  if (i < E) atomicAdd(&deg[col[i]], 1);
}

__global__ void dis_kernel(const int* __restrict__ d1, const int* __restrict__ d2,
                           float* __restrict__ s1, float* __restrict__ s2, int n){
  int i = blockIdx.x*256 + threadIdx.x;
  if (i < n){
    int a = d1[i]; s1[i] = (a > 0) ? (1.0f/sqrtf((float)a)) : 0.f;
    int b = d2[i]; s2[i] = (b > 0) ? (1.0f/sqrtf((float)b)) : 0.f;
  }
}

// pad CSR capacity with row index n (points at the zeroed table row)
__global__ void fill_kernel(unsigned* __restrict__ csr, size_t cap, unsigned padrow){
  size_t i = (size_t)blockIdx.x*256 + threadIdx.x;
  if (i < cap) csr[i] = padrow;
}

// scans run on PADDED degrees: pdeg = (deg+7)&~7  (8-edge multiples per node)
__global__ void scan1_kernel(const int* __restrict__ deg1, const int* __restrict__ deg2,
                             int* __restrict__ off1, int* __restrict__ off2,
                             int* __restrict__ bsum, int n){
  __shared__ int s[1024];
  int set = blockIdx.y;
  const int* deg = set ? deg2 : deg1;
  int* off = set ? off2 : off1;
  int tid = threadIdx.x;
  int i = blockIdx.x*1024 + tid;
  int v = (i < n) ? ((deg[i] + 7) & ~7) : 0;
  s[tid] = v;
  __syncthreads();
  for (int o = 1; o < 1024; o <<= 1){
    int t = (tid >= o) ? s[tid - o] : 0;
    __syncthreads();
    s[tid] += t;
    __syncthreads();
  }
  if (i < n) off[i] = s[tid];          // inclusive, chunk-local (fixed in pass 3)
  if (tid == 1023) bsum[set*64 + blockIdx.x] = s[1023];
}

__global__ void scan2_kernel(const int* __restrict__ bsum, int* __restrict__ bbase,
                             int nch, int* __restrict__ off1, int* __restrict__ off2, int n){
  int set = threadIdx.x;
  if (set < 2){
    int run = 0;
    for (int j = 0; j < nch; ++j){ bbase[set*64 + j] = run; run += bsum[set*64 + j]; }
    (set ? off2 : off1)[n] = run;      // total padded edge count
  }
}

__global__ void scan3_kernel(const int* __restrict__ deg1, const int* __restrict__ deg2,
                             int* __restrict__ off1, int* __restrict__ off2,
                             const int* __restrict__ bbase, int n){
  int set = blockIdx.y;
  const int* deg = set ? deg2 : deg1;
  int* off = set ? off2 : off1;
  int i = blockIdx.x*1024 + threadIdx.x;
  if (i < n){
    int e = off[i] + bbase[set*64 + blockIdx.x];
    off[i] = e - ((deg[i] + 7) & ~7);  // exclusive global padded prefix
  }
}

// ---------- XCD-local scatter with work stealing ----------
// Nodes are split into 8 ranges; range x's csr segment (~1.6MB) is written
// (in the common case) only by blocks on XCD x, so every csr line is dirtied
// in exactly ONE per-XCD L2 -> one full-line writeback instead of 8 partial
// ones (R6 profile: WRITE_SIZE == E*64B == 8 partial writebacks/line).
// Each wave claims 1024-edge chunks from its own range's queue, scattering
// only edges whose destination is in range; empty queue -> steal from next
// range (correctness never depends on XCD placement, G16). Edge list is read
// up to 8x, but 7/8 of that is L3-resident (~154MB @ >5TB/s).
__global__ __launch_bounds__(256) void scatterx_kernel(
    const int* __restrict__ ei1, int E1, const int* __restrict__ off1,
    int* __restrict__ cur1, unsigned* __restrict__ csr1,
    const int* __restrict__ ei2, int E2, const int* __restrict__ off2,
    int* __restrict__ cur2, unsigned* __restrict__ csr2,
    int* __restrict__ claim, int n)
{
  int xcd;
  asm volatile("s_getreg_b32 %0, hwreg(HW_REG_XCC_ID)" : "=s"(xcd));
  xcd &= 7;
  const int rsize = (n + 7) >> 3;
  const int nch1 = (E1 + 1023) >> 10;
  const int nch2 = (E2 + 1023) >> 10;
  const int ncht = nch1 + nch2;
  const int lane = threadIdx.x & 63;

  for (int dx = 0; dx < 8; ++dx){
    const int rx = (xcd + dx) & 7;
    const int clo = rx * rsize;
    const int chi = min(n, clo + rsize);
    while (true){
      int c0 = 0;
      if (lane == 0) c0 = atomicAdd(&claim[rx], 1);
      c0 = __shfl(c0, 0, 64);
      if (c0 >= ncht) break;
      const int set = (c0 >= nch1);
      const int* __restrict__ ei = set ? ei2 : ei1;
      const int E = set ? E2 : E1;
      const int* __restrict__ off = set ? off2 : off1;
      int* __restrict__ cur = set ? cur2 : cur1;
      unsigned* __restrict__ csr = set ? csr2 : csr1;
      const int base = (set ? (c0 - nch1) : c0) << 10;
      #pragma unroll
      for (int i = 0; i < 16; ++i){
        int e = base + i*64 + lane;
        if (e < E){
          int c = ei[E + e];
          if (c >= clo && c < chi){
            int r = ei[e];
            int p = off[c] + atomicAdd(&cur[c], 1);
            csr[p] = (unsigned)r;
          }
        }
      }
    }
  }
}

// ---------- GCN aggregation: out[c] = dis[c] * sum_e T_set[r] + b ----------
// T_set rows are PRE-SCALED by dis_set[r] and stored fp8 e4m3: 128B/row = 2 lines
// per edge (vs 4 at bf16) -> halves beyond-L2 line traffic at the MSHR wall.
// Half-wave h consumes edges 8b+4h..8b+4h+3 (one contiguous uint4 record load);
// lane covers 4 features (4B gather). 2-stage pipeline, padded CSR (pad row = n).
__global__ __launch_bounds__(256) void conv_kernel(
    const int* __restrict__ off1, const unsigned* __restrict__ csr1, const float* __restrict__ dis1,
    const int* __restrict__ off2, const unsigned* __restrict__ csr2, const float* __restrict__ dis2,
    const unsigned char* __restrict__ Tbase,   // [2][ntab][128] fp8
    const float* __restrict__ bias, unsigned short* __restrict__ outR,
    int n, int ntab)
{
  const int set = blockIdx.y;
  const int* __restrict__ off = set ? off2 : off1;
  const float* __restrict__ dis = set ? dis2 : dis1;
  const unsigned* __restrict__ csrq = set ? csr2 : csr1;
  const int col_ofs = set ? 128 : 0;
  const unsigned* __restrict__ tab =
      (const unsigned*)(Tbase + (size_t)set * ntab * 128);

  int wv = blockIdx.x*4 + (threadIdx.x >> 6);
  if (wv >= n) return;
  const int l = threadIdx.x & 63;
  const int half = l >> 5, lf = l & 31;
  const int s = off[wv], e = off[wv+1];
  const int nb = (e - s) >> 3;               // 8-edge batches (exact, padded)
  const unsigned* cp = csrq + s + half*4;    // this half's 4 records per batch

  float ax = 0.f, ay = 0.f, az = 0.f, aw = 0.f;

  if (nb > 0){
    u32x4 qa, qb;
    unsigned va0, va1, va2, va3, vb0, vb1, vb2, vb3;

#define LQ(q, B) q = __builtin_nontemporal_load((const u32x4*)(cp + (B)*8));
#define GATH(v, q) \
    v##0 = tab[(size_t)q.x * 32 + lf]; \
    v##1 = tab[(size_t)q.y * 32 + lf]; \
    v##2 = tab[(size_t)q.z * 32 + lf]; \
    v##3 = tab[(size_t)q.w * 32 + lf];
#define FMA1(v) { \
    f32x2 lo = __builtin_amdgcn_cvt_pk_f32_fp8((int)v, false); \
    f32x2 hi = __builtin_amdgcn_cvt_pk_f32_fp8((int)v, true);  \
    ax += lo.x; ay += lo.y; az += hi.x; aw += hi.y; }
#define FMAB(v) { FMA1(v##0) FMA1(v##1) FMA1(v##2) FMA1(v##3) }

    LQ(qa, 0)
    GATH(va, qa)
    LQ(qb, 1)
    int b = 0;
    while (b + 2 <= nb){
      LQ(qa, b + 2)              // speculative reads stay inside filled csr capacity
      GATH(vb, qb)
      FMAB(va)
      LQ(qb, b + 3)
      GATH(va, qa)               // may gather next node's rows / pad rows; unused unless valid
      FMAB(vb)
      b += 2;
    }
    if (b < nb) FMAB(va)
#undef LQ
#undef GATH
#undef FMA1
#undef FMAB
  }

  // combine the two half-wave partial sums
  ax += __shfl_xor(ax, 32, 64);
  ay += __shfl_xor(ay, 32, 64);
  az += __shfl_xor(az, 32, 64);
  aw += __shfl_xor(aw, 32, 64);

  if (half == 0){
    const float dc = dis[wv];
    float b0 = bias[lf*4 + 0], b1 = bias[lf*4 + 1];
    float b2 = bias[lf*4 + 2], b3 = bias[lf*4 + 3];
    ull ov = (ull)((unsigned)f2bf(fmaf(dc, ax, b0)) | ((unsigned)f2bf(fmaf(dc, ay, b1)) << 16))
           | ((ull)((unsigned)f2bf(fmaf(dc, az, b2)) | ((unsigned)f2bf(fmaf(dc, aw, b3)) << 16)) << 32);
    __builtin_nontemporal_store(ov, (ull*)&outR[(size_t)wv*256 + col_ofs + lf*4]);
  }
}

// ---------- bf16 MFMA GEMM, m97-style 2-barrier loop ----------
// A [M x K] bf16 row-major (lda), Bt = B^T stored [BN_total x K] bf16.
// EPI 0: plain bf16 store; EPI 1: +bias, relu, bf16 store;
// EPI 2: A = 3 slabs (h|R1|R2, lda=256 each), +bias, fused log_softmax, f32 store;
// EPI 4: dual fp8 table store T[set][row][col] = fp8(vv * dis_set[row]).
template<int FM, int FN, int WGM, int WGN, int EPI>
__global__ __launch_bounds__(256, 2) void gemm_kernel(
    const unsigned short* __restrict__ A0, const unsigned short* __restrict__ A1,
    const unsigned short* __restrict__ A2,
    const unsigned short* __restrict__ Bt, const float* __restrict__ bias,
    void* __restrict__ Cout, int M, int K, int lda, int ldc,
    const float* __restrict__ d1, const float* __restrict__ d2, int ntab)
{
  constexpr int BM = WGM*FM*16;
  constexpr int BN = WGN*FN*16;
  constexpr int BK = 32;
  static_assert(BM == 128, "staging assumes BM==128");
  __shared__ unsigned short As[BM][BK];
  __shared__ unsigned short Bs[BN][BK];
  const int tid = threadIdx.x;
  const int w = tid >> 6, l = tid & 63;
  const int wr = w / WGN, wc = w % WGN;
  const int m0 = blockIdx.x*BM, n0 = blockIdx.y*BN;
  f32x4 acc[FM][FN] = {};
  const int nsteps = K / BK;
  for (int s = 0; s < nsteps; ++s){
    const int k0 = s*BK;
    const unsigned short* Asrc = A0;
    int kin = k0;
    if constexpr (EPI == 2){
      int slab = k0 >> 8;
      Asrc = (slab == 0) ? A0 : ((slab == 1) ? A1 : A2);
      kin = k0 & 255;
    }
    __syncthreads();
    #pragma unroll
    for (int j = 0; j < 2; ++j){           // A: 8KB = 2 x 4KB issues
      int idx = j*256 + tid;
      int row = idx >> 2, kq = idx & 3;
      int rg = m0 + row; rg = (rg < M) ? rg : (M - 1);
      load_lds16(Asrc + (size_t)rg*lda + kin + kq*8,
                 ((char*)&As[0][0]) + (size_t)(j*256 + w*64)*16);
    }
    #pragma unroll
    for (int j = 0; j < BN/64; ++j){       // Bt: [n][k] layout, same pattern as A
      int idx = j*256 + tid;
      int row = idx >> 2, kq = idx & 3;
      load_lds16(Bt + (size_t)(n0 + row)*K + k0 + kq*8,
                 ((char*)&Bs[0][0]) + (size_t)(j*256 + w*64)*16);
    }
    __syncthreads();
    bf16x8 af[FM], bfr[FN];
    const int kofs = (l >> 4)*8, l16 = l & 15;
    #pragma unroll
    for (int mi = 0; mi < FM; ++mi)
      af[mi] = *(const bf16x8*)&As[wr*FM*16 + mi*16 + l16][kofs];
    #pragma unroll
    for (int ni = 0; ni < FN; ++ni)
      bfr[ni] = *(const bf16x8*)&Bs[wc*FN*16 + ni*16 + l16][kofs];
    #pragma unroll
    for (int mi = 0; mi < FM; ++mi)
      #pragma unroll
      for (int ni = 0; ni < FN; ++ni)
        acc[mi][ni] = __builtin_amdgcn_mfma_f32_16x16x32_bf16(af[mi], bfr[ni], acc[mi][ni], 0, 0, 0);
  }
  const int lg = l >> 4, lc = l & 15;
  if constexpr (EPI == 2){
    float* O = (float*)Cout;
    #pragma unroll
    for (int mi = 0; mi < FM; ++mi){
      #pragma unroll
      for (int i = 0; i < 4; ++i){
        int row = m0 + wr*FM*16 + mi*16 + lg*4 + i;
        float v[FN];
        float mx = -1e30f;
        #pragma unroll
        for (int ni = 0; ni < FN; ++ni){
          int col = ni*16 + lc;                       // WGN==1, n0==0
          v[ni] = acc[mi][ni][i] + ((col < 40) ? bias[col] : 0.f);
          if (col < 40) mx = fmaxf(mx, v[ni]);
        }
        #pragma unroll
        for (int d = 1; d < 16; d <<= 1) mx = fmaxf(mx, __shfl_xor(mx, d, 64));
        float se = 0.f;
        #pragma unroll
        for (int ni = 0; ni < FN; ++ni){
          int col = ni*16 + lc;
          if (col < 40) se += expf(v[ni] - mx);
        }
        #pragma unroll
        for (int d = 1; d < 16; d <<= 1) se += __shfl_xor(se, d, 64);
        float lse = logf(se);
        if (row < M){
          #pragma unroll
          for (int ni = 0; ni < FN; ++ni){
            int col = ni*16 + lc;
            if (col < 40) O[(size_t)row*40 + col] = v[ni] - mx - lse;
          }
        }
      }
    }
  } else if constexpr (EPI == 4){
    unsigned char* T = (unsigned char*)Cout;            // [2][ntab][128]
    #pragma unroll
    for (int mi = 0; mi < FM; ++mi){
      #pragma unroll
      for (int i = 0; i < 4; ++i){
        int row = m0 + wr*FM*16 + mi*16 + lg*4 + i;
        if (row >= M) continue;
        float s1 = d1[row], s2 = d2[row];
        #pragma unroll
        for (int ni = 0; ni < FN; ++ni){
          int col = n0 + wc*FN*16 + ni*16 + lc;        // [0,128)
          float vv = acc[mi][ni][i];
          unsigned p1 = (unsigned)__builtin_amdgcn_cvt_pk_fp8_f32(vv*s1, vv*s1, 0, false);
          unsigned p2 = (unsigned)__builtin_amdgcn_cvt_pk_fp8_f32(vv*s2, vv*s2, 0, false);
          T[(size_t)row*128 + col] = (unsigned char)(p1 & 0xff);
          T[((size_t)ntab + row)*128 + col] = (unsigned char)(p2 & 0xff);
        }
      }
    }
  } else {
    unsigned short* C = (unsigned short*)Cout;
    #pragma unroll
    for (int mi = 0; mi < FM; ++mi){
      #pragma unroll
      for (int i = 0; i < 4; ++i){
        int row = m0 + wr*FM*16 + mi*16 + lg*4 + i;
        if (row >= M) continue;
        #pragma unroll
        for (int ni = 0; ni < FN; ++ni){
          int col = n0 + wc*FN*16 + ni*16 + lc;
          float vv = acc[mi][ni][i];
          if constexpr (EPI == 1){ vv += bias[col]; vv = fmaxf(vv, 0.f); }
          C[(size_t)row*ldc + col] = f2bf(vv);
        }
      }
    }
  }
}

extern "C" void kernel_launch(void* const* d_in, const int* in_sizes, int n_in,
                              void* d_out, int out_size, void* d_ws, size_t ws_size,
                              hipStream_t stream)
{
  (void)n_in; (void)out_size;
  const float* x      = (const float*)d_in[0];
  const int*   ei1    = (const int*)d_in[1];
  const int*   ei2    = (const int*)d_in[2];
  const float* W_lin1 = (const float*)d_in[3];
  const float* b_lin1 = (const float*)d_in[4];
  const float* W_c1   = (const float*)d_in[5];
  const float* b_c1   = (const float*)d_in[6];
  const float* W_c2   = (const float*)d_in[7];
  const float* b_c2   = (const float*)d_in[8];
  const float* W_lin2 = (const float*)d_in[9];
  const float* b_lin2 = (const float*)d_in[10];

  const int N  = in_sizes[0] / 512;
  const int E1 = in_sizes[1] / 2;
  const int E2 = in_sizes[2] / 2;
  const int ntab = N + 1;                    // +1 zero row for pad edges

  char* base = (char*)d_ws;
  size_t off = 0;
  auto alloc = [&](size_t bytes) -> char* {
    off = (off + 255) & ~(size_t)255;
    char* r = base + off;
    off += bytes;
    return r;
  };
  // padded-CSR capacities in 4B records (pad <= 7 per node, + speculative slack)
  const size_t cap1 = (size_t)E1 + 8*(size_t)N + 64;
  const size_t cap2 = (size_t)E2 + 8*(size_t)N + 64;

  unsigned short* xb   = (unsigned short*)alloc((size_t)N*512*2);  // reused as CSR after GEMM1
  unsigned short* h    = (unsigned short*)alloc((size_t)N*256*2);
  unsigned char*  T    = (unsigned char*)alloc((size_t)2*ntab*128); // fp8 scaled tables
  unsigned short* R1   = (unsigned short*)alloc((size_t)N*256*2);
  unsigned short* R2   = (unsigned short*)alloc((size_t)N*256*2);
  unsigned short* Wt1  = (unsigned short*)alloc((size_t)256*512*2);
  unsigned short* Wtc1 = (unsigned short*)alloc((size_t)128*256*2);
  unsigned short* Wtc2 = (unsigned short*)alloc((size_t)128*256*2);
  unsigned short* Wtf  = (unsigned short*)alloc((size_t)64*768*2); // W_lin2^T padded to 64 cols
  int* degblk = (int*)alloc((size_t)4*N*4);
  int* deg1 = degblk, *deg2 = degblk + N, *cur1 = degblk + 2*N, *cur2 = degblk + 3*N;
  float* dis1 = (float*)alloc((size_t)N*4);
  float* dis2 = (float*)alloc((size_t)N*4);
  int* off1 = (int*)alloc((size_t)(N+1)*4);
  int* off2 = (int*)alloc((size_t)(N+1)*4);
  int* bsum  = (int*)alloc(128*4);
  int* bbase = (int*)alloc(128*4);
  int* claim = (int*)alloc(16*4);
  // CSR aliases the xb slab (xb is dead after GEMM1; 51.2MB >= ~14MB needed)
  unsigned* csr1 = (unsigned*)xb;
  unsigned* csr2 = csr1 + cap1;
  if (off > ws_size) return;   // workspace insufficient -> visible validation failure

  int mt = (N + 127)/128;
  int cb = (N + 3)/4;

  // --- dense front: x->bf16, weight transposes, GEMM1 (uses xb before CSR aliases it) ---
  cvt_x_kernel<<<(N*512/4 + 255)/256, 256, 0, stream>>>((const float4*)x, (ushort4*)xb, N*512/4);
  wtrans_kernel<<<(256*512 + 255)/256, 256, 0, stream>>>(W_lin1, Wt1, 512, 256, 256);
  wtrans_kernel<<<(128*256 + 255)/256, 256, 0, stream>>>(W_c1, Wtc1, 256, 128, 128);
  wtrans_kernel<<<(128*256 + 255)/256, 256, 0, stream>>>(W_c2, Wtc2, 256, 128, 128);
  wtrans_kernel<<<(64*768 + 255)/256, 256, 0, stream>>>(W_lin2, Wtf, 768, 40, 64);
  // h = relu(x @ W_lin1 + b)
  gemm_kernel<4,4,2,2,1><<<dim3(mt, 2), 256, 0, stream>>>(xb, nullptr, nullptr, Wt1, b_lin1, h,
                                                          N, 512, 512, 256, nullptr, nullptr, 0);

  // --- graph preprocessing (overwrites xb slab with padded 4B-record CSR) ---
  (void)hipMemsetAsync(degblk, 0, (size_t)4*N*4, stream);
  (void)hipMemsetAsync(claim, 0, 16*4, stream);
  (void)hipMemsetAsync(T + (size_t)N*128, 0, 128, stream);            // zero row, set 0
  (void)hipMemsetAsync(T + ((size_t)ntab + N)*128, 0, 128, stream);   // zero row, set 1
  fill_kernel<<<(int)((cap1 + cap2 + 255)/256), 256, 0, stream>>>(csr1, cap1 + cap2, (unsigned)N);
  hist2_kernel<<<dim3((E2 + 255)/256, 2), 256, 0, stream>>>(ei1, E1, deg1, ei2, E2, deg2);
  dis_kernel<<<(N + 255)/256, 256, 0, stream>>>(deg1, deg2, dis1, dis2, N);
  int nch = (N + 1023)/1024;
  scan1_kernel<<<dim3(nch, 2), 1024, 0, stream>>>(deg1, deg2, off1, off2, bsum, N);
  scan2_kernel<<<1, 64, 0, stream>>>(bsum, bbase, nch, off1, off2, N);
  scan3_kernel<<<dim3(nch, 2), 1024, 0, stream>>>(deg1, deg2, off1, off2, bbase, N);
  scatterx_kernel<<<1024, 256, 0, stream>>>(ei1, E1, off1, cur1, csr1,
                                            ei2, E2, off2, cur2, csr2, claim, N);

  // --- layer 1: T = fp8(dis_set[r] * (h @ W_c1)[r]), then one conv pass ---
  gemm_kernel<4,4,2,2,4><<<dim3(mt, 1), 256, 0, stream>>>(h, nullptr, nullptr, Wtc1, nullptr, T,
                                                          N, 256, 256, 0, dis1, dis2, ntab);
  conv_kernel<<<dim3(cb, 2), 256, 0, stream>>>(off1, csr1, dis1, off2, csr2, dis2,
                                               T, b_c1, R1, N, ntab);
  // --- layer 2: T = fp8(dis_set[r] * (R1 @ W_c2)[r]), conv ---
  gemm_kernel<4,4,2,2,4><<<dim3(mt, 1), 256, 0, stream>>>(R1, nullptr, nullptr, Wtc2, nullptr, T,
                                                          N, 256, 256, 0, dis1, dis2, ntab);
  conv_kernel<<<dim3(cb, 2), 256, 0, stream>>>(off1, csr1, dis1, off2, csr2, dis2,
                                               T, b_c2, R2, N, ntab);
  // --- head: logits = [h|R1|R2] @ W_lin2 + b, fused log_softmax ---
  gemm_kernel<2,4,4,1,2><<<dim3(mt, 1), 256, 0, stream>>>(h, R1, R2, Wtf, b_lin2, d_out,
                                                          N, 768, 256, 40, nullptr, nullptr, 0);
}

// Round 8
// 444.898 us; speedup vs baseline: 2.2244x; 2.2244x over previous
//
#include <hip/hip_runtime.h>
#include <hip/hip_bf16.h>
#include <stdint.h>

typedef __attribute__((ext_vector_type(8))) short bf16x8;
typedef __attribute__((ext_vector_type(4))) float f32x4;
typedef __attribute__((ext_vector_type(2))) float f32x2;
typedef __attribute__((ext_vector_type(4))) unsigned int u32x4;
typedef unsigned long long ull;

__device__ __forceinline__ void load_lds16(const void* g, void* l){
  __builtin_amdgcn_global_load_lds((const __attribute__((address_space(1))) void*)g,
                                   (__attribute__((address_space(3))) void*)l, 16, 0, 0);
}

__device__ __forceinline__ float bf2f(unsigned int u){
  union { unsigned int i; float f; } x; x.i = u << 16; return x.f;
}
__device__ __forceinline__ unsigned short f2bf(float f){
  __hip_bfloat16 h = __float2bfloat16(f);
  unsigned short u;
  __builtin_memcpy(&u, &h, 2);
  return u;
}

// ---------- conversions ----------
__global__ void cvt_x_kernel(const float4* __restrict__ in, ushort4* __restrict__ out, int n4){
  int i = blockIdx.x*256 + threadIdx.x;
  if (i < n4){
    float4 v = in[i];
    ushort4 o;
    o.x = f2bf(v.x); o.y = f2bf(v.y); o.z = f2bf(v.z); o.w = f2bf(v.w);
    out[i] = o;
  }
}

// Wt[n][k] = bf16(W[k][n]) for n < N, 0 for N <= n < Npad
__global__ void wtrans_kernel(const float* __restrict__ W, unsigned short* __restrict__ Wt,
                              int K, int N, int Npad){
  int idx = blockIdx.x*256 + threadIdx.x;
  if (idx >= Npad*K) return;
  int nn = idx / K, kk = idx - nn*K;
  float v = (nn < N) ? W[(size_t)kk*N + nn] : 0.f;
  Wt[idx] = f2bf(v);
}

// ---------- graph preprocessing ----------
// fused histogram over both edge sets
__global__ void hist2_kernel(const int* __restrict__ ei1, int E1, int* __restrict__ deg1,
                             const int* __restrict__ ei2, int E2, int* __restrict__ deg2){
  int set = blockIdx.y;
  const int* col = set ? (ei2 + E2) : (ei1 + E1);
  int E = set ? E2 : E1;
  int* deg = set ? deg2 : deg1;
  int i = blockIdx.x*256 + threadIdx.x;
  if (i < E) atomicAdd(&deg[col[i]], 1);
}

__global__ void dis_kernel(const int* __restrict__ d1, const int* __restrict__ d2,
                           float* __restrict__ s1, float* __restrict__ s2, int n){
  int i = blockIdx.x*256 + threadIdx.x;
  if (i < n){
    int a = d1[i]; s1[i] = (a > 0) ? (1.0f/sqrtf((float)a)) : 0.f;
    int b = d2[i]; s2[i] = (b > 0) ? (1.0f/sqrtf((float)b)) : 0.f;
  }
}

// scans run on PADDED degrees: pdeg = (deg+7)&~7  (8-edge multiples per node)
__global__ void scan1_kernel(const int* __restrict__ deg1, const int* __restrict__ deg2,
                             int* __restrict__ off1, int* __restrict__ off2,
                             int* __restrict__ bsum, int n){
  __shared__ int s[1024];
  int set = blockIdx.y;
  const int* deg = set ? deg2 : deg1;
  int* off = set ? off2 : off1;
  int tid = threadIdx.x;
  int i = blockIdx.x*1024 + tid;
  int v = (i < n) ? ((deg[i] + 7) & ~7) : 0;
  s[tid] = v;
  __syncthreads();
  for (int o = 1; o < 1024; o <<= 1){
    int t = (tid >= o) ? s[tid - o] : 0;
    __syncthreads();
    s[tid] += t;
    __syncthreads();
  }
  if (i < n) off[i] = s[tid];          // inclusive, chunk-local (fixed in pass 3)
  if (tid == 1023) bsum[set*64 + blockIdx.x] = s[1023];
}

__global__ void scan2_kernel(const int* __restrict__ bsum, int* __restrict__ bbase,
                             int nch, int* __restrict__ off1, int* __restrict__ off2, int n){
  int set = threadIdx.x;
  if (set < 2){
    int run = 0;
    for (int j = 0; j < nch; ++j){ bbase[set*64 + j] = run; run += bsum[set*64 + j]; }
    (set ? off2 : off1)[n] = run;      // total padded edge count
  }
}

__global__ void scan3_kernel(const int* __restrict__ deg1, const int* __restrict__ deg2,
                             int* __restrict__ off1, int* __restrict__ off2,
                             const int* __restrict__ bbase, int n){
  int set = blockIdx.y;
  const int* deg = set ? deg2 : deg1;
  int* off = set ? off2 : off1;
  int i = blockIdx.x*1024 + threadIdx.x;
  if (i < n){
    int e = off[i] + bbase[set*64 + blockIdx.x];
    off[i] = e - ((deg[i] + 7) & ~7);  // exclusive global padded prefix
  }
}

// ---------- two-pass bucketed scatter ----------
// Buckets of 128 destination nodes. Pass A partitions edges into per-bucket
// staging (packed (r<<7)|c_local, 4B) with per-block LDS histograms and one
// global reservation per (block,bucket) -> contiguous ~84B write runs, full
// cache lines. Pass B scatters each bucket's records into its ~20KB csr
// region with LDS cursors (NO global atomics); region stays L2-hot so every
// csr line is written back once, fixing R5/R6/R7's 8x partial-line writeback
// (WRITE_SIZE == E*64B). Pass B also writes the <=7 pad slots per node,
// replacing the full-capacity fill_kernel.

// per-bucket unpadded edge counts: bcnt[set][b] = sum deg over bucket nodes
__global__ void bsum_kernel(const int* __restrict__ deg1, const int* __restrict__ deg2,
                            int* __restrict__ bcnt, int NB, int n){
  int set = blockIdx.y;
  const int* deg = set ? deg2 : deg1;
  int b = blockIdx.x;
  int c = (b << 7) + threadIdx.x;          // block = 128 threads
  int v = (c < n) ? deg[c] : 0;
  for (int d = 1; d < 64; d <<= 1) v += __shfl_xor(v, d, 64);
  __shared__ int partial[2];
  if ((threadIdx.x & 63) == 0) partial[threadIdx.x >> 6] = v;
  __syncthreads();
  if (threadIdx.x == 0) bcnt[set*NB + b] = partial[0] + partial[1];
}

// exclusive scan of bucket counts -> absolute staging bases (set1 after set0);
// bcur = working cursors for pass A
__global__ void bscan_kernel(const int* __restrict__ bcnt, int* __restrict__ bbase2,
                             int* __restrict__ bcur, int NB, int E1){
  int set = threadIdx.x;
  if (set < 2){
    int run = set ? E1 : 0;
    for (int b = 0; b < NB; ++b){
      bbase2[set*(NB+1) + b] = run;
      bcur[set*NB + b] = run;
      run += bcnt[set*NB + b];
    }
    bbase2[set*(NB+1) + NB] = run;
  }
}

// Pass A: partition 8192-edge chunks into bucket staging
__global__ __launch_bounds__(256) void partA_kernel(
    const int* __restrict__ ei1, int E1, const int* __restrict__ ei2, int E2,
    int* __restrict__ bcur, unsigned* __restrict__ staging, int NB)
{
  const int set = blockIdx.y;
  const int* __restrict__ ei = set ? ei2 : ei1;
  const int E = set ? E2 : E1;
  int* __restrict__ cur = bcur + set*NB;
  __shared__ int hist[400];
  __shared__ int resv[400];
  const int tid = threadIdx.x;
  const int base = blockIdx.x * 8192;
  if (base >= E) return;
  for (int b = tid; b < NB; b += 256) hist[b] = 0;
  __syncthreads();
  #pragma unroll 4
  for (int i = 0; i < 32; ++i){
    int e = base + i*256 + tid;
    if (e < E) atomicAdd(&hist[ei[E + e] >> 7], 1);
  }
  __syncthreads();
  for (int b = tid; b < NB; b += 256){
    int hc = hist[b];
    resv[b] = hc ? atomicAdd(&cur[b], hc) : 0;
    hist[b] = 0;                      // reuse as local cursor
  }
  __syncthreads();
  #pragma unroll 4
  for (int i = 0; i < 32; ++i){
    int e = base + i*256 + tid;
    if (e < E){
      int c = ei[E + e], r = ei[e];
      int b = c >> 7;
      int s = resv[b] + atomicAdd(&hist[b], 1);
      staging[s] = ((unsigned)r << 7) | (unsigned)(c & 127);
    }
  }
}

// Pass B: per-bucket local scatter + padding (pad record = padrow)
__global__ __launch_bounds__(256) void partB_kernel(
    const unsigned* __restrict__ staging, const int* __restrict__ bbase2,
    const int* __restrict__ off1, const int* __restrict__ off2,
    unsigned* __restrict__ csr1, unsigned* __restrict__ csr2,
    int NB, int n, unsigned padrow)
{
  const int set = blockIdx.y;
  const int* __restrict__ off = set ? off2 : off1;
  unsigned* __restrict__ csr = set ? csr2 : csr1;
  const int* __restrict__ bb = bbase2 + set*(NB+1);
  const int b = blockIdx.x;
  const int nodebase = b << 7;
  const int nn = min(128, n - nodebase);
  if (nn <= 0) return;
  __shared__ int offv[129];
  __shared__ int curl[128];
  const int tid = threadIdx.x;
  if (tid <= nn) offv[tid] = off[nodebase + tid];
  if (tid < 128) curl[tid] = 0;
  __syncthreads();
  const int s0 = bb[b], s1 = bb[b+1];
  for (int i = s0 + tid; i < s1; i += 256){
    unsigned v = staging[i];
    int cl = v & 127;
    int p = offv[cl] + atomicAdd(&curl[cl], 1);
    csr[p] = v >> 7;
  }
  __syncthreads();
  for (int c = tid; c < nn; c += 256){
    int p1 = offv[c+1];
    for (int p = offv[c] + curl[c]; p < p1; ++p) csr[p] = padrow;
  }
}

// fill speculative-prefetch slack past off[n]
__global__ void fillslack_kernel(unsigned* __restrict__ csr1, const int* __restrict__ off1,
                                 unsigned* __restrict__ csr2, const int* __restrict__ off2,
                                 int n, unsigned padrow){
  int tid = threadIdx.x;
  if (tid < 64) csr1[off1[n] + tid] = padrow;
  else if (tid < 128) csr2[off2[n] + (tid - 64)] = padrow;
}

// ---------- GCN aggregation: out[c] = dis[c] * sum_e T_set[r] + b ----------
// T_set rows are PRE-SCALED by dis_set[r] and stored fp8 e4m3: 128B/row = 2 lines
// per edge (vs 4 at bf16) -> halves beyond-L2 line traffic at the MSHR wall.
// Half-wave h consumes edges 8b+4h..8b+4h+3 (one contiguous uint4 record load);
// lane covers 4 features (4B gather). 2-stage pipeline, padded CSR (pad row = n).
__global__ __launch_bounds__(256) void conv_kernel(
    const int* __restrict__ off1, const unsigned* __restrict__ csr1, const float* __restrict__ dis1,
    const int* __restrict__ off2, const unsigned* __restrict__ csr2, const float* __restrict__ dis2,
    const unsigned char* __restrict__ Tbase,   // [2][ntab][128] fp8
    const float* __restrict__ bias, unsigned short* __restrict__ outR,
    int n, int ntab)
{
  const int set = blockIdx.y;
  const int* __restrict__ off = set ? off2 : off1;
  const float* __restrict__ dis = set ? dis2 : dis1;
  const unsigned* __restrict__ csrq = set ? csr2 : csr1;
  const int col_ofs = set ? 128 : 0;
  const unsigned* __restrict__ tab =
      (const unsigned*)(Tbase + (size_t)set * ntab * 128);

  int wv = blockIdx.x*4 + (threadIdx.x >> 6);
  if (wv >= n) return;
  const int l = threadIdx.x & 63;
  const int half = l >> 5, lf = l & 31;
  const int s = off[wv], e = off[wv+1];
  const int nb = (e - s) >> 3;               // 8-edge batches (exact, padded)
  const unsigned* cp = csrq + s + half*4;    // this half's 4 records per batch

  float ax = 0.f, ay = 0.f, az = 0.f, aw = 0.f;

  if (nb > 0){
    u32x4 qa, qb;
    unsigned va0, va1, va2, va3, vb0, vb1, vb2, vb3;

#define LQ(q, B) q = __builtin_nontemporal_load((const u32x4*)(cp + (B)*8));
#define GATH(v, q) \
    v##0 = tab[(size_t)q.x * 32 + lf]; \
    v##1 = tab[(size_t)q.y * 32 + lf]; \
    v##2 = tab[(size_t)q.z * 32 + lf]; \
    v##3 = tab[(size_t)q.w * 32 + lf];
#define FMA1(v) { \
    f32x2 lo = __builtin_amdgcn_cvt_pk_f32_fp8((int)v, false); \
    f32x2 hi = __builtin_amdgcn_cvt_pk_f32_fp8((int)v, true);  \
    ax += lo.x; ay += lo.y; az += hi.x; aw += hi.y; }
#define FMAB(v) { FMA1(v##0) FMA1(v##1) FMA1(v##2) FMA1(v##3) }

    LQ(qa, 0)
    GATH(va, qa)
    LQ(qb, 1)
    int b = 0;
    while (b + 2 <= nb){
      LQ(qa, b + 2)              // speculative reads stay inside filled csr capacity
      GATH(vb, qb)
      FMAB(va)
      LQ(qb, b + 3)
      GATH(va, qa)               // may gather next node's rows / pad rows; unused unless valid
      FMAB(vb)
      b += 2;
    }
    if (b < nb) FMAB(va)
#undef LQ
#undef GATH
#undef FMA1
#undef FMAB
  }

  // combine the two half-wave partial sums
  ax += __shfl_xor(ax, 32, 64);
  ay += __shfl_xor(ay, 32, 64);
  az += __shfl_xor(az, 32, 64);
  aw += __shfl_xor(aw, 32, 64);

  if (half == 0){
    const float dc = dis[wv];
    float b0 = bias[lf*4 + 0], b1 = bias[lf*4 + 1];
    float b2 = bias[lf*4 + 2], b3 = bias[lf*4 + 3];
    ull ov = (ull)((unsigned)f2bf(fmaf(dc, ax, b0)) | ((unsigned)f2bf(fmaf(dc, ay, b1)) << 16))
           | ((ull)((unsigned)f2bf(fmaf(dc, az, b2)) | ((unsigned)f2bf(fmaf(dc, aw, b3)) << 16)) << 32);
    __builtin_nontemporal_store(ov, (ull*)&outR[(size_t)wv*256 + col_ofs + lf*4]);
  }
}

// ---------- bf16 MFMA GEMM, m97-style 2-barrier loop ----------
// A [M x K] bf16 row-major (lda), Bt = B^T stored [BN_total x K] bf16.
// EPI 0: plain bf16 store; EPI 1: +bias, relu, bf16 store;
// EPI 2: A = 3 slabs (h|R1|R2, lda=256 each), +bias, fused log_softmax, f32 store;
// EPI 4: dual fp8 table store T[set][row][col] = fp8(vv * dis_set[row]).
template<int FM, int FN, int WGM, int WGN, int EPI>
__global__ __launch_bounds__(256, 2) void gemm_kernel(
    const unsigned short* __restrict__ A0, const unsigned short* __restrict__ A1,
    const unsigned short* __restrict__ A2,
    const unsigned short* __restrict__ Bt, const float* __restrict__ bias,
    void* __restrict__ Cout, int M, int K, int lda, int ldc,
    const float* __restrict__ d1, const float* __restrict__ d2, int ntab)
{
  constexpr int BM = WGM*FM*16;
  constexpr int BN = WGN*FN*16;
  constexpr int BK = 32;
  static_assert(BM == 128, "staging assumes BM==128");
  __shared__ unsigned short As[BM][BK];
  __shared__ unsigned short Bs[BN][BK];
  const int tid = threadIdx.x;
  const int w = tid >> 6, l = tid & 63;
  const int wr = w / WGN, wc = w % WGN;
  const int m0 = blockIdx.x*BM, n0 = blockIdx.y*BN;
  f32x4 acc[FM][FN] = {};
  const int nsteps = K / BK;
  for (int s = 0; s < nsteps; ++s){
    const int k0 = s*BK;
    const unsigned short* Asrc = A0;
    int kin = k0;
    if constexpr (EPI == 2){
      int slab = k0 >> 8;
      Asrc = (slab == 0) ? A0 : ((slab == 1) ? A1 : A2);
      kin = k0 & 255;
    }
    __syncthreads();
    #pragma unroll
    for (int j = 0; j < 2; ++j){           // A: 8KB = 2 x 4KB issues
      int idx = j*256 + tid;
      int row = idx >> 2, kq = idx & 3;
      int rg = m0 + row; rg = (rg < M) ? rg : (M - 1);
      load_lds16(Asrc + (size_t)rg*lda + kin + kq*8,
                 ((char*)&As[0][0]) + (size_t)(j*256 + w*64)*16);
    }
    #pragma unroll
    for (int j = 0; j < BN/64; ++j){       // Bt: [n][k] layout, same pattern as A
      int idx = j*256 + tid;
      int row = idx >> 2, kq = idx & 3;
      load_lds16(Bt + (size_t)(n0 + row)*K + k0 + kq*8,
                 ((char*)&Bs[0][0]) + (size_t)(j*256 + w*64)*16);
    }
    __syncthreads();
    bf16x8 af[FM], bfr[FN];
    const int kofs = (l >> 4)*8, l16 = l & 15;
    #pragma unroll
    for (int mi = 0; mi < FM; ++mi)
      af[mi] = *(const bf16x8*)&As[wr*FM*16 + mi*16 + l16][kofs];
    #pragma unroll
    for (int ni = 0; ni < FN; ++ni)
      bfr[ni] = *(const bf16x8*)&Bs[wc*FN*16 + ni*16 + l16][kofs];
    #pragma unroll
    for (int mi = 0; mi < FM; ++mi)
      #pragma unroll
      for (int ni = 0; ni < FN; ++ni)
        acc[mi][ni] = __builtin_amdgcn_mfma_f32_16x16x32_bf16(af[mi], bfr[ni], acc[mi][ni], 0, 0, 0);
  }
  const int lg = l >> 4, lc = l & 15;
  if constexpr (EPI == 2){
    float* O = (float*)Cout;
    #pragma unroll
    for (int mi = 0; mi < FM; ++mi){
      #pragma unroll
      for (int i = 0; i < 4; ++i){
        int row = m0 + wr*FM*16 + mi*16 + lg*4 + i;
        float v[FN];
        float mx = -1e30f;
        #pragma unroll
        for (int ni = 0; ni < FN; ++ni){
          int col = ni*16 + lc;                       // WGN==1, n0==0
          v[ni] = acc[mi][ni][i] + ((col < 40) ? bias[col] : 0.f);
          if (col < 40) mx = fmaxf(mx, v[ni]);
        }
        #pragma unroll
        for (int d = 1; d < 16; d <<= 1) mx = fmaxf(mx, __shfl_xor(mx, d, 64));
        float se = 0.f;
        #pragma unroll
        for (int ni = 0; ni < FN; ++ni){
          int col = ni*16 + lc;
          if (col < 40) se += expf(v[ni] - mx);
        }
        #pragma unroll
        for (int d = 1; d < 16; d <<= 1) se += __shfl_xor(se, d, 64);
        float lse = logf(se);
        if (row < M){
          #pragma unroll
          for (int ni = 0; ni < FN; ++ni){
            int col = ni*16 + lc;
            if (col < 40) O[(size_t)row*40 + col] = v[ni] - mx - lse;
          }
        }
      }
    }
  } else if constexpr (EPI == 4){
    unsigned char* T = (unsigned char*)Cout;            // [2][ntab][128]
    #pragma unroll
    for (int mi = 0; mi < FM; ++mi){
      #pragma unroll
      for (int i = 0; i < 4; ++i){
        int row = m0 + wr*FM*16 + mi*16 + lg*4 + i;
        if (row >= M) continue;
        float s1 = d1[row], s2 = d2[row];
        #pragma unroll
        for (int ni = 0; ni < FN; ++ni){
          int col = n0 + wc*FN*16 + ni*16 + lc;        // [0,128)
          float vv = acc[mi][ni][i];
          unsigned p1 = (unsigned)__builtin_amdgcn_cvt_pk_fp8_f32(vv*s1, vv*s1, 0, false);
          unsigned p2 = (unsigned)__builtin_amdgcn_cvt_pk_fp8_f32(vv*s2, vv*s2, 0, false);
          T[(size_t)row*128 + col] = (unsigned char)(p1 & 0xff);
          T[((size_t)ntab + row)*128 + col] = (unsigned char)(p2 & 0xff);
        }
      }
    }
  } else {
    unsigned short* C = (unsigned short*)Cout;
    #pragma unroll
    for (int mi = 0; mi < FM; ++mi){
      #pragma unroll
      for (int i = 0; i < 4; ++i){
        int row = m0 + wr*FM*16 + mi*16 + lg*4 + i;
        if (row >= M) continue;
        #pragma unroll
        for (int ni = 0; ni < FN; ++ni){
          int col = n0 + wc*FN*16 + ni*16 + lc;
          float vv = acc[mi][ni][i];
          if constexpr (EPI == 1){ vv += bias[col]; vv = fmaxf(vv, 0.f); }
          C[(size_t)row*ldc + col] = f2bf(vv);
        }
      }
    }
  }
}

extern "C" void kernel_launch(void* const* d_in, const int* in_sizes, int n_in,
                              void* d_out, int out_size, void* d_ws, size_t ws_size,
                              hipStream_t stream)
{
  (void)n_in; (void)out_size;
  const float* x      = (const float*)d_in[0];
  const int*   ei1    = (const int*)d_in[1];
  const int*   ei2    = (const int*)d_in[2];
  const float* W_lin1 = (const float*)d_in[3];
  const float* b_lin1 = (const float*)d_in[4];
  const float* W_c1   = (const float*)d_in[5];
  const float* b_c1   = (const float*)d_in[6];
  const float* W_c2   = (const float*)d_in[7];
  const float* b_c2   = (const float*)d_in[8];
  const float* W_lin2 = (const float*)d_in[9];
  const float* b_lin2 = (const float*)d_in[10];

  const int N  = in_sizes[0] / 512;
  const int E1 = in_sizes[1] / 2;
  const int E2 = in_sizes[2] / 2;
  const int ntab = N + 1;                    // +1 zero row for pad edges
  const int NB = (N + 127) >> 7;             // destination buckets of 128 nodes

  char* base = (char*)d_ws;
  size_t off = 0;
  auto alloc = [&](size_t bytes) -> char* {
    off = (off + 255) & ~(size_t)255;
    char* r = base + off;
    off += bytes;
    return r;
  };
  // padded-CSR capacities in 4B records (pad <= 7 per node, + speculative slack)
  const size_t cap1 = (size_t)E1 + 8*(size_t)N + 64;
  const size_t cap2 = (size_t)E2 + 8*(size_t)N + 64;

  unsigned short* xb   = (unsigned short*)alloc((size_t)N*512*2);  // reused as CSR+staging after GEMM1
  unsigned short* h    = (unsigned short*)alloc((size_t)N*256*2);
  unsigned char*  T    = (unsigned char*)alloc((size_t)2*ntab*128); // fp8 scaled tables
  unsigned short* R1   = (unsigned short*)alloc((size_t)N*256*2);
  unsigned short* R2   = (unsigned short*)alloc((size_t)N*256*2);
  unsigned short* Wt1  = (unsigned short*)alloc((size_t)256*512*2);
  unsigned short* Wtc1 = (unsigned short*)alloc((size_t)128*256*2);
  unsigned short* Wtc2 = (unsigned short*)alloc((size_t)128*256*2);
  unsigned short* Wtf  = (unsigned short*)alloc((size_t)64*768*2); // W_lin2^T padded to 64 cols
  int* degblk = (int*)alloc((size_t)2*N*4);
  int* deg1 = degblk, *deg2 = degblk + N;
  float* dis1 = (float*)alloc((size_t)N*4);
  float* dis2 = (float*)alloc((size_t)N*4);
  int* off1 = (int*)alloc((size_t)(N+1)*4);
  int* off2 = (int*)alloc((size_t)(N+1)*4);
  int* bsum  = (int*)alloc(128*4);
  int* bbase = (int*)alloc(128*4);
  int* bcnt   = (int*)alloc((size_t)2*NB*4);
  int* bbase2 = (int*)alloc((size_t)2*(NB+1)*4);
  int* bcur   = (int*)alloc((size_t)2*NB*4);
  // CSR + staging alias the xb slab (xb is dead after GEMM1; 51.2MB >= ~23MB needed)
  unsigned* csr1 = (unsigned*)xb;
  unsigned* csr2 = csr1 + cap1;
  unsigned* staging = csr2 + cap2;
  if (off > ws_size) return;   // workspace insufficient -> visible validation failure

  int mt = (N + 127)/128;
  int cb = (N + 3)/4;

  // --- dense front: x->bf16, weight transposes, GEMM1 (uses xb before CSR aliases it) ---
  cvt_x_kernel<<<(N*512/4 + 255)/256, 256, 0, stream>>>((const float4*)x, (ushort4*)xb, N*512/4);
  wtrans_kernel<<<(256*512 + 255)/256, 256, 0, stream>>>(W_lin1, Wt1, 512, 256, 256);
  wtrans_kernel<<<(128*256 + 255)/256, 256, 0, stream>>>(W_c1, Wtc1, 256, 128, 128);
  wtrans_kernel<<<(128*256 + 255)/256, 256, 0, stream>>>(W_c2, Wtc2, 256, 128, 128);
  wtrans_kernel<<<(64*768 + 255)/256, 256, 0, stream>>>(W_lin2, Wtf, 768, 40, 64);
  // h = relu(x @ W_lin1 + b)
  gemm_kernel<4,4,2,2,1><<<dim3(mt, 2), 256, 0, stream>>>(xb, nullptr, nullptr, Wt1, b_lin1, h,
                                                          N, 512, 512, 256, nullptr, nullptr, 0);

  // --- graph preprocessing (overwrites xb slab with CSR + staging) ---
  (void)hipMemsetAsync(degblk, 0, (size_t)2*N*4, stream);
  (void)hipMemsetAsync(T + (size_t)N*128, 0, 128, stream);            // zero row, set 0
  (void)hipMemsetAsync(T + ((size_t)ntab + N)*128, 0, 128, stream);   // zero row, set 1
  hist2_kernel<<<dim3((E2 + 255)/256, 2), 256, 0, stream>>>(ei1, E1, deg1, ei2, E2, deg2);
  dis_kernel<<<(N + 255)/256, 256, 0, stream>>>(deg1, deg2, dis1, dis2, N);
  int nch = (N + 1023)/1024;
  scan1_kernel<<<dim3(nch, 2), 1024, 0, stream>>>(deg1, deg2, off1, off2, bsum, N);
  scan2_kernel<<<1, 64, 0, stream>>>(bsum, bbase, nch, off1, off2, N);
  scan3_kernel<<<dim3(nch, 2), 1024, 0, stream>>>(deg1, deg2, off1, off2, bbase, N);
  bsum_kernel<<<dim3(NB, 2), 128, 0, stream>>>(deg1, deg2, bcnt, NB, N);
  bscan_kernel<<<1, 64, 0, stream>>>(bcnt, bbase2, bcur, NB, E1);
  partA_kernel<<<dim3((E2 + 8191)/8192, 2), 256, 0, stream>>>(ei1, E1, ei2, E2, bcur, staging, NB);
  partB_kernel<<<dim3(NB, 2), 256, 0, stream>>>(staging, bbase2, off1, off2, csr1, csr2,
                                                NB, N, (unsigned)N);
  fillslack_kernel<<<1, 128, 0, stream>>>(csr1, off1, csr2, off2, N, (unsigned)N);

  // --- layer 1: T = fp8(dis_set[r] * (h @ W_c1)[r]), then one conv pass ---
  gemm_kernel<4,4,2,2,4><<<dim3(mt, 1), 256, 0, stream>>>(h, nullptr, nullptr, Wtc1, nullptr, T,
                                                          N, 256, 256, 0, dis1, dis2, ntab);
  conv_kernel<<<dim3(cb, 2), 256, 0, stream>>>(off1, csr1, dis1, off2, csr2, dis2,
                                               T, b_c1, R1, N, ntab);
  // --- layer 2: T = fp8(dis_set[r] * (R1 @ W_c2)[r]), conv ---
  gemm_kernel<4,4,2,2,4><<<dim3(mt, 1), 256, 0, stream>>>(R1, nullptr, nullptr, Wtc2, nullptr, T,
                                                          N, 256, 256, 0, dis1, dis2, ntab);
  conv_kernel<<<dim3(cb, 2), 256, 0, stream>>>(off1, csr1, dis1, off2, csr2, dis2,
                                               T, b_c2, R2, N, ntab);
  // --- head: logits = [h|R1|R2] @ W_lin2 + b, fused log_softmax ---
  gemm_kernel<2,4,4,1,2><<<dim3(mt, 1), 256, 0, stream>>>(h, R1, R2, Wtf, b_lin2, d_out,
                                                          N, 768, 256, 40, nullptr, nullptr, 0);
}

// Round 9
// 360.711 us; speedup vs baseline: 2.7435x; 1.2334x over previous
//
#include <hip/hip_runtime.h>
#include <hip/hip_bf16.h>
#include <stdint.h>

typedef __attribute__((ext_vector_type(8))) short bf16x8;
typedef __attribute__((ext_vector_type(4))) float f32x4;
typedef __attribute__((ext_vector_type(2))) float f32x2;
typedef __attribute__((ext_vector_type(4))) unsigned int u32x4;
typedef unsigned long long ull;

__device__ __forceinline__ void load_lds16(const void* g, void* l){
  __builtin_amdgcn_global_load_lds((const __attribute__((address_space(1))) void*)g,
                                   (__attribute__((address_space(3))) void*)l, 16, 0, 0);
}

__device__ __forceinline__ float bf2f(unsigned int u){
  union { unsigned int i; float f; } x; x.i = u << 16; return x.f;
}
__device__ __forceinline__ unsigned short f2bf(float f){
  __hip_bfloat16 h = __float2bfloat16(f);
  unsigned short u;
  __builtin_memcpy(&u, &h, 2);
  return u;
}

// ---------- conversions ----------
__global__ void cvt_x_kernel(const float4* __restrict__ in, ushort4* __restrict__ out, int n4){
  int i = blockIdx.x*256 + threadIdx.x;
  if (i < n4){
    float4 v = in[i];
    ushort4 o;
    o.x = f2bf(v.x); o.y = f2bf(v.y); o.z = f2bf(v.z); o.w = f2bf(v.w);
    out[i] = o;
  }
}

// Wt[n][k] = bf16(W[k][n]) for n < N, 0 for N <= n < Npad
__global__ void wtrans_kernel(const float* __restrict__ W, unsigned short* __restrict__ Wt,
                              int K, int N, int Npad){
  int idx = blockIdx.x*256 + threadIdx.x;
  if (idx >= Npad*K) return;
  int nn = idx / K, kk = idx - nn*K;
  float v = (nn < N) ? W[(size_t)kk*N + nn] : 0.f;
  Wt[idx] = f2bf(v);
}

// ---------- graph preprocessing ----------
// Bucketed, atomic-light pipeline. R8 profile: node-granular histogram
// (hist2, 2.4M device atomics over 200KB) cost 101us with WRITE_SIZE 74.7MB
// (cache-line ping-pong across 8 non-coherent L2s -> partial-line writeback
// per ownership migration). Replaced by:
//   cntA: LDS bucket-histogram (391 buckets) -> 1 atomic per (block,bucket)
//   partA: partition edges into per-bucket staging (proven in R8)
//   degB: per-bucket LDS count of staging records -> CONTIGUOUS deg write
// No node-granular global atomics remain anywhere.

// bucket counts via LDS aggregation
__global__ __launch_bounds__(256) void cntA_kernel(
    const int* __restrict__ ei1, int E1, const int* __restrict__ ei2, int E2,
    int* __restrict__ bcnt, int NB)
{
  const int set = blockIdx.y;
  const int* __restrict__ col = set ? (ei2 + E2) : (ei1 + E1);
  const int E = set ? E2 : E1;
  const int base = blockIdx.x * 8192;
  if (base >= E) return;
  __shared__ int hist[400];
  const int tid = threadIdx.x;
  for (int b = tid; b < NB; b += 256) hist[b] = 0;
  __syncthreads();
  #pragma unroll 4
  for (int i = 0; i < 32; ++i){
    int e = base + i*256 + tid;
    if (e < E) atomicAdd(&hist[col[e] >> 7], 1);
  }
  __syncthreads();
  for (int b = tid; b < NB; b += 256)
    if (hist[b]) atomicAdd(&bcnt[set*NB + b], hist[b]);
}

// exclusive scan of bucket counts -> absolute staging bases (set1 after set0);
// bcur = working cursors for pass A
__global__ void bscan_kernel(const int* __restrict__ bcnt, int* __restrict__ bbase2,
                             int* __restrict__ bcur, int NB, int E1){
  int set = threadIdx.x;
  if (set < 2){
    int run = set ? E1 : 0;
    for (int b = 0; b < NB; ++b){
      bbase2[set*(NB+1) + b] = run;
      bcur[set*NB + b] = run;
      run += bcnt[set*NB + b];
    }
    bbase2[set*(NB+1) + NB] = run;
  }
}

// Pass A: partition 8192-edge chunks into bucket staging
__global__ __launch_bounds__(256) void partA_kernel(
    const int* __restrict__ ei1, int E1, const int* __restrict__ ei2, int E2,
    int* __restrict__ bcur, unsigned* __restrict__ staging, int NB)
{
  const int set = blockIdx.y;
  const int* __restrict__ ei = set ? ei2 : ei1;
  const int E = set ? E2 : E1;
  int* __restrict__ cur = bcur + set*NB;
  __shared__ int hist[400];
  __shared__ int resv[400];
  const int tid = threadIdx.x;
  const int base = blockIdx.x * 8192;
  if (base >= E) return;
  for (int b = tid; b < NB; b += 256) hist[b] = 0;
  __syncthreads();
  #pragma unroll 4
  for (int i = 0; i < 32; ++i){
    int e = base + i*256 + tid;
    if (e < E) atomicAdd(&hist[ei[E + e] >> 7], 1);
  }
  __syncthreads();
  for (int b = tid; b < NB; b += 256){
    int hc = hist[b];
    resv[b] = hc ? atomicAdd(&cur[b], hc) : 0;
    hist[b] = 0;                      // reuse as local cursor
  }
  __syncthreads();
  #pragma unroll 4
  for (int i = 0; i < 32; ++i){
    int e = base + i*256 + tid;
    if (e < E){
      int c = ei[E + e], r = ei[e];
      int b = c >> 7;
      int s = resv[b] + atomicAdd(&hist[b], 1);
      staging[s] = ((unsigned)r << 7) | (unsigned)(c & 127);
    }
  }
}

// per-node degrees from staging: LDS counters, contiguous global write
__global__ __launch_bounds__(256) void degB_kernel(
    const unsigned* __restrict__ staging, const int* __restrict__ bbase2,
    int* __restrict__ deg1, int* __restrict__ deg2, int NB, int n)
{
  const int set = blockIdx.y;
  int* __restrict__ deg = set ? deg2 : deg1;
  const int* __restrict__ bb = bbase2 + set*(NB+1);
  const int b = blockIdx.x;
  const int nodebase = b << 7;
  const int nn = min(128, n - nodebase);
  if (nn <= 0) return;
  __shared__ int cnt[128];
  const int tid = threadIdx.x;
  if (tid < 128) cnt[tid] = 0;
  __syncthreads();
  const int s0 = bb[b], s1 = bb[b+1];
  for (int i = s0 + tid; i < s1; i += 256)
    atomicAdd(&cnt[staging[i] & 127], 1);
  __syncthreads();
  if (tid < nn) deg[nodebase + tid] = cnt[tid];
}

__global__ void dis_kernel(const int* __restrict__ d1, const int* __restrict__ d2,
                           float* __restrict__ s1, float* __restrict__ s2, int n){
  int i = blockIdx.x*256 + threadIdx.x;
  if (i < n){
    int a = d1[i]; s1[i] = (a > 0) ? (1.0f/sqrtf((float)a)) : 0.f;
    int b = d2[i]; s2[i] = (b > 0) ? (1.0f/sqrtf((float)b)) : 0.f;
  }
}

// scans run on PADDED degrees: pdeg = (deg+7)&~7  (8-edge multiples per node)
__global__ void scan1_kernel(const int* __restrict__ deg1, const int* __restrict__ deg2,
                             int* __restrict__ off1, int* __restrict__ off2,
                             int* __restrict__ bsum, int n){
  __shared__ int s[1024];
  int set = blockIdx.y;
  const int* deg = set ? deg2 : deg1;
  int* off = set ? off2 : off1;
  int tid = threadIdx.x;
  int i = blockIdx.x*1024 + tid;
  int v = (i < n) ? ((deg[i] + 7) & ~7) : 0;
  s[tid] = v;
  __syncthreads();
  for (int o = 1; o < 1024; o <<= 1){
    int t = (tid >= o) ? s[tid - o] : 0;
    __syncthreads();
    s[tid] += t;
    __syncthreads();
  }
  if (i < n) off[i] = s[tid];          // inclusive, chunk-local (fixed in pass 3)
  if (tid == 1023) bsum[set*64 + blockIdx.x] = s[1023];
}

__global__ void scan2_kernel(const int* __restrict__ bsum, int* __restrict__ bbase,
                             int nch, int* __restrict__ off1, int* __restrict__ off2, int n){
  int set = threadIdx.x;
  if (set < 2){
    int run = 0;
    for (int j = 0; j < nch; ++j){ bbase[set*64 + j] = run; run += bsum[set*64 + j]; }
    (set ? off2 : off1)[n] = run;      // total padded edge count
  }
}

__global__ void scan3_kernel(const int* __restrict__ deg1, const int* __restrict__ deg2,
                             int* __restrict__ off1, int* __restrict__ off2,
                             const int* __restrict__ bbase, int n){
  int set = blockIdx.y;
  const int* deg = set ? deg2 : deg1;
  int* off = set ? off2 : off1;
  int i = blockIdx.x*1024 + threadIdx.x;
  if (i < n){
    int e = off[i] + bbase[set*64 + blockIdx.x];
    off[i] = e - ((deg[i] + 7) & ~7);  // exclusive global padded prefix
  }
}

// Pass B: per-bucket local scatter + padding (pad record = padrow)
__global__ __launch_bounds__(256) void partB_kernel(
    const unsigned* __restrict__ staging, const int* __restrict__ bbase2,
    const int* __restrict__ off1, const int* __restrict__ off2,
    unsigned* __restrict__ csr1, unsigned* __restrict__ csr2,
    int NB, int n, unsigned padrow)
{
  const int set = blockIdx.y;
  const int* __restrict__ off = set ? off2 : off1;
  unsigned* __restrict__ csr = set ? csr2 : csr1;
  const int* __restrict__ bb = bbase2 + set*(NB+1);
  const int b = blockIdx.x;
  const int nodebase = b << 7;
  const int nn = min(128, n - nodebase);
  if (nn <= 0) return;
  __shared__ int offv[129];
  __shared__ int curl[128];
  const int tid = threadIdx.x;
  if (tid <= nn) offv[tid] = off[nodebase + tid];
  if (tid < 128) curl[tid] = 0;
  __syncthreads();
  const int s0 = bb[b], s1 = bb[b+1];
  for (int i = s0 + tid; i < s1; i += 256){
    unsigned v = staging[i];
    int cl = v & 127;
    int p = offv[cl] + atomicAdd(&curl[cl], 1);
    csr[p] = v >> 7;
  }
  __syncthreads();
  for (int c = tid; c < nn; c += 256){
    int p1 = offv[c+1];
    for (int p = offv[c] + curl[c]; p < p1; ++p) csr[p] = padrow;
  }
}

// fill speculative-prefetch slack past off[n]
__global__ void fillslack_kernel(unsigned* __restrict__ csr1, const int* __restrict__ off1,
                                 unsigned* __restrict__ csr2, const int* __restrict__ off2,
                                 int n, unsigned padrow){
  int tid = threadIdx.x;
  if (tid < 64) csr1[off1[n] + tid] = padrow;
  else if (tid < 128) csr2[off2[n] + (tid - 64)] = padrow;
}

// ---------- GCN aggregation: out[c] = dis[c] * sum_e T_set[r] + b ----------
// T_set rows are PRE-SCALED by dis_set[r] and stored fp8 e4m3: 128B/row = 2 lines
// per edge (vs 4 at bf16) -> halves beyond-L2 line traffic at the MSHR wall.
// Half-wave h consumes edges 8b+4h..8b+4h+3 (one contiguous uint4 record load);
// lane covers 4 features (4B gather). 2-stage pipeline, padded CSR (pad row = n).
__global__ __launch_bounds__(256) void conv_kernel(
    const int* __restrict__ off1, const unsigned* __restrict__ csr1, const float* __restrict__ dis1,
    const int* __restrict__ off2, const unsigned* __restrict__ csr2, const float* __restrict__ dis2,
    const unsigned char* __restrict__ Tbase,   // [2][ntab][128] fp8
    const float* __restrict__ bias, unsigned short* __restrict__ outR,
    int n, int ntab)
{
  const int set = blockIdx.y;
  const int* __restrict__ off = set ? off2 : off1;
  const float* __restrict__ dis = set ? dis2 : dis1;
  const unsigned* __restrict__ csrq = set ? csr2 : csr1;
  const int col_ofs = set ? 128 : 0;
  const unsigned* __restrict__ tab =
      (const unsigned*)(Tbase + (size_t)set * ntab * 128);

  int wv = blockIdx.x*4 + (threadIdx.x >> 6);
  if (wv >= n) return;
  const int l = threadIdx.x & 63;
  const int half = l >> 5, lf = l & 31;
  const int s = off[wv], e = off[wv+1];
  const int nb = (e - s) >> 3;               // 8-edge batches (exact, padded)
  const unsigned* cp = csrq + s + half*4;    // this half's 4 records per batch

  float ax = 0.f, ay = 0.f, az = 0.f, aw = 0.f;

  if (nb > 0){
    u32x4 qa, qb;
    unsigned va0, va1, va2, va3, vb0, vb1, vb2, vb3;

#define LQ(q, B) q = __builtin_nontemporal_load((const u32x4*)(cp + (B)*8));
#define GATH(v, q) \
    v##0 = tab[(size_t)q.x * 32 + lf]; \
    v##1 = tab[(size_t)q.y * 32 + lf]; \
    v##2 = tab[(size_t)q.z * 32 + lf]; \
    v##3 = tab[(size_t)q.w * 32 + lf];
#define FMA1(v) { \
    f32x2 lo = __builtin_amdgcn_cvt_pk_f32_fp8((int)v, false); \
    f32x2 hi = __builtin_amdgcn_cvt_pk_f32_fp8((int)v, true);  \
    ax += lo.x; ay += lo.y; az += hi.x; aw += hi.y; }
#define FMAB(v) { FMA1(v##0) FMA1(v##1) FMA1(v##2) FMA1(v##3) }

    LQ(qa, 0)
    GATH(va, qa)
    LQ(qb, 1)
    int b = 0;
    while (b + 2 <= nb){
      LQ(qa, b + 2)              // speculative reads stay inside filled csr capacity
      GATH(vb, qb)
      FMAB(va)
      LQ(qb, b + 3)
      GATH(va, qa)               // may gather next node's rows / pad rows; unused unless valid
      FMAB(vb)
      b += 2;
    }
    if (b < nb) FMAB(va)
#undef LQ
#undef GATH
#undef FMA1
#undef FMAB
  }

  // combine the two half-wave partial sums
  ax += __shfl_xor(ax, 32, 64);
  ay += __shfl_xor(ay, 32, 64);
  az += __shfl_xor(az, 32, 64);
  aw += __shfl_xor(aw, 32, 64);

  if (half == 0){
    const float dc = dis[wv];
    float b0 = bias[lf*4 + 0], b1 = bias[lf*4 + 1];
    float b2 = bias[lf*4 + 2], b3 = bias[lf*4 + 3];
    ull ov = (ull)((unsigned)f2bf(fmaf(dc, ax, b0)) | ((unsigned)f2bf(fmaf(dc, ay, b1)) << 16))
           | ((ull)((unsigned)f2bf(fmaf(dc, az, b2)) | ((unsigned)f2bf(fmaf(dc, aw, b3)) << 16)) << 32);
    __builtin_nontemporal_store(ov, (ull*)&outR[(size_t)wv*256 + col_ofs + lf*4]);
  }
}

// ---------- bf16 MFMA GEMM, m97-style 2-barrier loop ----------
// A [M x K] bf16 row-major (lda), Bt = B^T stored [BN_total x K] bf16.
// EPI 0: plain bf16 store; EPI 1: +bias, relu, bf16 store;
// EPI 2: A = 3 slabs (h|R1|R2, lda=256 each), +bias, fused log_softmax, f32 store;
// EPI 4: dual fp8 table store T[set][row][col] = fp8(vv * dis_set[row]).
template<int FM, int FN, int WGM, int WGN, int EPI>
__global__ __launch_bounds__(256, 2) void gemm_kernel(
    const unsigned short* __restrict__ A0, const unsigned short* __restrict__ A1,
    const unsigned short* __restrict__ A2,
    const unsigned short* __restrict__ Bt, const float* __restrict__ bias,
    void* __restrict__ Cout, int M, int K, int lda, int ldc,
    const float* __restrict__ d1, const float* __restrict__ d2, int ntab)
{
  constexpr int BM = WGM*FM*16;
  constexpr int BN = WGN*FN*16;
  constexpr int BK = 32;
  static_assert(BM == 128, "staging assumes BM==128");
  __shared__ unsigned short As[BM][BK];
  __shared__ unsigned short Bs[BN][BK];
  const int tid = threadIdx.x;
  const int w = tid >> 6, l = tid & 63;
  const int wr = w / WGN, wc = w % WGN;
  const int m0 = blockIdx.x*BM, n0 = blockIdx.y*BN;
  f32x4 acc[FM][FN] = {};
  const int nsteps = K / BK;
  for (int s = 0; s < nsteps; ++s){
    const int k0 = s*BK;
    const unsigned short* Asrc = A0;
    int kin = k0;
    if constexpr (EPI == 2){
      int slab = k0 >> 8;
      Asrc = (slab == 0) ? A0 : ((slab == 1) ? A1 : A2);
      kin = k0 & 255;
    }
    __syncthreads();
    #pragma unroll
    for (int j = 0; j < 2; ++j){           // A: 8KB = 2 x 4KB issues
      int idx = j*256 + tid;
      int row = idx >> 2, kq = idx & 3;
      int rg = m0 + row; rg = (rg < M) ? rg : (M - 1);
      load_lds16(Asrc + (size_t)rg*lda + kin + kq*8,
                 ((char*)&As[0][0]) + (size_t)(j*256 + w*64)*16);
    }
    #pragma unroll
    for (int j = 0; j < BN/64; ++j){       // Bt: [n][k] layout, same pattern as A
      int idx = j*256 + tid;
      int row = idx >> 2, kq = idx & 3;
      load_lds16(Bt + (size_t)(n0 + row)*K + k0 + kq*8,
                 ((char*)&Bs[0][0]) + (size_t)(j*256 + w*64)*16);
    }
    __syncthreads();
    bf16x8 af[FM], bfr[FN];
    const int kofs = (l >> 4)*8, l16 = l & 15;
    #pragma unroll
    for (int mi = 0; mi < FM; ++mi)
      af[mi] = *(const bf16x8*)&As[wr*FM*16 + mi*16 + l16][kofs];
    #pragma unroll
    for (int ni = 0; ni < FN; ++ni)
      bfr[ni] = *(const bf16x8*)&Bs[wc*FN*16 + ni*16 + l16][kofs];
    #pragma unroll
    for (int mi = 0; mi < FM; ++mi)
      #pragma unroll
      for (int ni = 0; ni < FN; ++ni)
        acc[mi][ni] = __builtin_amdgcn_mfma_f32_16x16x32_bf16(af[mi], bfr[ni], acc[mi][ni], 0, 0, 0);
  }
  const int lg = l >> 4, lc = l & 15;
  if constexpr (EPI == 2){
    float* O = (float*)Cout;
    #pragma unroll
    for (int mi = 0; mi < FM; ++mi){
      #pragma unroll
      for (int i = 0; i < 4; ++i){
        int row = m0 + wr*FM*16 + mi*16 + lg*4 + i;
        float v[FN];
        float mx = -1e30f;
        #pragma unroll
        for (int ni = 0; ni < FN; ++ni){
          int col = ni*16 + lc;                       // WGN==1, n0==0
          v[ni] = acc[mi][ni][i] + ((col < 40) ? bias[col] : 0.f);
          if (col < 40) mx = fmaxf(mx, v[ni]);
        }
        #pragma unroll
        for (int d = 1; d < 16; d <<= 1) mx = fmaxf(mx, __shfl_xor(mx, d, 64));
        float se = 0.f;
        #pragma unroll
        for (int ni = 0; ni < FN; ++ni){
          int col = ni*16 + lc;
          if (col < 40) se += expf(v[ni] - mx);
        }
        #pragma unroll
        for (int d = 1; d < 16; d <<= 1) se += __shfl_xor(se, d, 64);
        float lse = logf(se);
        if (row < M){
          #pragma unroll
          for (int ni = 0; ni < FN; ++ni){
            int col = ni*16 + lc;
            if (col < 40) O[(size_t)row*40 + col] = v[ni] - mx - lse;
          }
        }
      }
    }
  } else if constexpr (EPI == 4){
    unsigned char* T = (unsigned char*)Cout;            // [2][ntab][128]
    #pragma unroll
    for (int mi = 0; mi < FM; ++mi){
      #pragma unroll
      for (int i = 0; i < 4; ++i){
        int row = m0 + wr*FM*16 + mi*16 + lg*4 + i;
        if (row >= M) continue;
        float s1 = d1[row], s2 = d2[row];
        #pragma unroll
        for (int ni = 0; ni < FN; ++ni){
          int col = n0 + wc*FN*16 + ni*16 + lc;        // [0,128)
          float vv = acc[mi][ni][i];
          unsigned p1 = (unsigned)__builtin_amdgcn_cvt_pk_fp8_f32(vv*s1, vv*s1, 0, false);
          unsigned p2 = (unsigned)__builtin_amdgcn_cvt_pk_fp8_f32(vv*s2, vv*s2, 0, false);
          T[(size_t)row*128 + col] = (unsigned char)(p1 & 0xff);
          T[((size_t)ntab + row)*128 + col] = (unsigned char)(p2 & 0xff);
        }
      }
    }
  } else {
    unsigned short* C = (unsigned short*)Cout;
    #pragma unroll
    for (int mi = 0; mi < FM; ++mi){
      #pragma unroll
      for (int i = 0; i < 4; ++i){
        int row = m0 + wr*FM*16 + mi*16 + lg*4 + i;
        if (row >= M) continue;
        #pragma unroll
        for (int ni = 0; ni < FN; ++ni){
          int col = n0 + wc*FN*16 + ni*16 + lc;
          float vv = acc[mi][ni][i];
          if constexpr (EPI == 1){ vv += bias[col]; vv = fmaxf(vv, 0.f); }
          C[(size_t)row*ldc + col] = f2bf(vv);
        }
      }
    }
  }
}

extern "C" void kernel_launch(void* const* d_in, const int* in_sizes, int n_in,
                              void* d_out, int out_size, void* d_ws, size_t ws_size,
                              hipStream_t stream)
{
  (void)n_in; (void)out_size;
  const float* x      = (const float*)d_in[0];
  const int*   ei1    = (const int*)d_in[1];
  const int*   ei2    = (const int*)d_in[2];
  const float* W_lin1 = (const float*)d_in[3];
  const float* b_lin1 = (const float*)d_in[4];
  const float* W_c1   = (const float*)d_in[5];
  const float* b_c1   = (const float*)d_in[6];
  const float* W_c2   = (const float*)d_in[7];
  const float* b_c2   = (const float*)d_in[8];
  const float* W_lin2 = (const float*)d_in[9];
  const float* b_lin2 = (const float*)d_in[10];

  const int N  = in_sizes[0] / 512;
  const int E1 = in_sizes[1] / 2;
  const int E2 = in_sizes[2] / 2;
  const int ntab = N + 1;                    // +1 zero row for pad edges
  const int NB = (N + 127) >> 7;             // destination buckets of 128 nodes

  char* base = (char*)d_ws;
  size_t off = 0;
  auto alloc = [&](size_t bytes) -> char* {
    off = (off + 255) & ~(size_t)255;
    char* r = base + off;
    off += bytes;
    return r;
  };
  // padded-CSR capacities in 4B records (pad <= 7 per node, + speculative slack)
  const size_t cap1 = (size_t)E1 + 8*(size_t)N + 64;
  const size_t cap2 = (size_t)E2 + 8*(size_t)N + 64;

  unsigned short* xb   = (unsigned short*)alloc((size_t)N*512*2);  // reused as CSR+staging after GEMM1
  unsigned short* h    = (unsigned short*)alloc((size_t)N*256*2);
  unsigned char*  T    = (unsigned char*)alloc((size_t)2*ntab*128); // fp8 scaled tables
  unsigned short* R1   = (unsigned short*)alloc((size_t)N*256*2);
  unsigned short* R2   = (unsigned short*)alloc((size_t)N*256*2);
  unsigned short* Wt1  = (unsigned short*)alloc((size_t)256*512*2);
  unsigned short* Wtc1 = (unsigned short*)alloc((size_t)128*256*2);
  unsigned short* Wtc2 = (unsigned short*)alloc((size_t)128*256*2);
  unsigned short* Wtf  = (unsigned short*)alloc((size_t)64*768*2); // W_lin2^T padded to 64 cols
  int* degblk = (int*)alloc((size_t)2*N*4);
  int* deg1 = degblk, *deg2 = degblk + N;
  float* dis1 = (float*)alloc((size_t)N*4);
  float* dis2 = (float*)alloc((size_t)N*4);
  int* off1 = (int*)alloc((size_t)(N+1)*4);
  int* off2 = (int*)alloc((size_t)(N+1)*4);
  int* bsum  = (int*)alloc(128*4);
  int* bbase = (int*)alloc(128*4);
  int* bcnt   = (int*)alloc((size_t)2*NB*4);
  int* bbase2 = (int*)alloc((size_t)2*(NB+1)*4);
  int* bcur   = (int*)alloc((size_t)2*NB*4);
  // CSR + staging alias the xb slab (xb is dead after GEMM1; 51.2MB >= ~23MB needed)
  unsigned* csr1 = (unsigned*)xb;
  unsigned* csr2 = csr1 + cap1;
  unsigned* staging = csr2 + cap2;
  if (off > ws_size) return;   // workspace insufficient -> visible validation failure

  int mt = (N + 127)/128;
  int cb = (N + 3)/4;

  // --- dense front: x->bf16, weight transposes, GEMM1 (uses xb before CSR aliases it) ---
  cvt_x_kernel<<<(N*512/4 + 255)/256, 256, 0, stream>>>((const float4*)x, (ushort4*)xb, N*512/4);
  wtrans_kernel<<<(256*512 + 255)/256, 256, 0, stream>>>(W_lin1, Wt1, 512, 256, 256);
  wtrans_kernel<<<(128*256 + 255)/256, 256, 0, stream>>>(W_c1, Wtc1, 256, 128, 128);
  wtrans_kernel<<<(128*256 + 255)/256, 256, 0, stream>>>(W_c2, Wtc2, 256, 128, 128);
  wtrans_kernel<<<(64*768 + 255)/256, 256, 0, stream>>>(W_lin2, Wtf, 768, 40, 64);
  // h = relu(x @ W_lin1 + b)
  gemm_kernel<4,4,2,2,1><<<dim3(mt, 2), 256, 0, stream>>>(xb, nullptr, nullptr, Wt1, b_lin1, h,
                                                          N, 512, 512, 256, nullptr, nullptr, 0);

  // --- graph preprocessing (bucketed; overwrites xb slab with CSR + staging) ---
  (void)hipMemsetAsync(bcnt, 0, (size_t)2*NB*4, stream);
  (void)hipMemsetAsync(T + (size_t)N*128, 0, 128, stream);            // zero row, set 0
  (void)hipMemsetAsync(T + ((size_t)ntab + N)*128, 0, 128, stream);   // zero row, set 1
  cntA_kernel<<<dim3((E2 + 8191)/8192, 2), 256, 0, stream>>>(ei1, E1, ei2, E2, bcnt, NB);
  bscan_kernel<<<1, 64, 0, stream>>>(bcnt, bbase2, bcur, NB, E1);
  partA_kernel<<<dim3((E2 + 8191)/8192, 2), 256, 0, stream>>>(ei1, E1, ei2, E2, bcur, staging, NB);
  degB_kernel<<<dim3(NB, 2), 256, 0, stream>>>(staging, bbase2, deg1, deg2, NB, N);
  dis_kernel<<<(N + 255)/256, 256, 0, stream>>>(deg1, deg2, dis1, dis2, N);
  int nch = (N + 1023)/1024;
  scan1_kernel<<<dim3(nch, 2), 1024, 0, stream>>>(deg1, deg2, off1, off2, bsum, N);
  scan2_kernel<<<1, 64, 0, stream>>>(bsum, bbase, nch, off1, off2, N);
  scan3_kernel<<<dim3(nch, 2), 1024, 0, stream>>>(deg1, deg2, off1, off2, bbase, N);
  partB_kernel<<<dim3(NB, 2), 256, 0, stream>>>(staging, bbase2, off1, off2, csr1, csr2,
                                                NB, N, (unsigned)N);
  fillslack_kernel<<<1, 128, 0, stream>>>(csr1, off1, csr2, off2, N, (unsigned)N);

  // --- layer 1: T = fp8(dis_set[r] * (h @ W_c1)[r]), then one conv pass ---
  gemm_kernel<4,4,2,2,4><<<dim3(mt, 1), 256, 0, stream>>>(h, nullptr, nullptr, Wtc1, nullptr, T,
                                                          N, 256, 256, 0, dis1, dis2, ntab);
  conv_kernel<<<dim3(cb, 2), 256, 0, stream>>>(off1, csr1, dis1, off2, csr2, dis2,
                                               T, b_c1, R1, N, ntab);
  // --- layer 2: T = fp8(dis_set[r] * (R1 @ W_c2)[r]), conv ---
  gemm_kernel<4,4,2,2,4><<<dim3(mt, 1), 256, 0, stream>>>(R1, nullptr, nullptr, Wtc2, nullptr, T,
                                                          N, 256, 256, 0, dis1, dis2, ntab);
  conv_kernel<<<dim3(cb, 2), 256, 0, stream>>>(off1, csr1, dis1, off2, csr2, dis2,
                                               T, b_c2, R2, N, ntab);
  // --- head: logits = [h|R1|R2] @ W_lin2 + b, fused log_softmax ---
  gemm_kernel<2,4,4,1,2><<<dim3(mt, 1), 256, 0, stream>>>(h, R1, R2, Wtf, b_lin2, d_out,
                                                          N, 768, 256, 40, nullptr, nullptr, 0);
}

// Round 10
// 282.322 us; speedup vs baseline: 3.5053x; 1.2777x over previous
//
#include <hip/hip_runtime.h>
#include <hip/hip_bf16.h>
#include <stdint.h>

typedef __attribute__((ext_vector_type(8))) short bf16x8;
typedef __attribute__((ext_vector_type(8))) unsigned short ushort8v;
typedef __attribute__((ext_vector_type(4))) float f32x4;
typedef __attribute__((ext_vector_type(2))) float f32x2;
typedef __attribute__((ext_vector_type(4))) unsigned int u32x4;
typedef unsigned long long ull;

__device__ __forceinline__ void load_lds16(const void* g, void* l){
  __builtin_amdgcn_global_load_lds((const __attribute__((address_space(1))) void*)g,
                                   (__attribute__((address_space(3))) void*)l, 16, 0, 0);
}

__device__ __forceinline__ float bf2f(unsigned int u){
  union { unsigned int i; float f; } x; x.i = u << 16; return x.f;
}
__device__ __forceinline__ unsigned short f2bf(float f){
  __hip_bfloat16 h = __float2bfloat16(f);
  unsigned short u;
  __builtin_memcpy(&u, &h, 2);
  return u;
}

// ---------- fused weight transposes (4 matrices, one dispatch) ----------
__global__ void wtrans4_kernel(const float* __restrict__ W1, unsigned short* __restrict__ Wt1,
                               const float* __restrict__ Wc1, unsigned short* __restrict__ Wtc1,
                               const float* __restrict__ Wc2, unsigned short* __restrict__ Wtc2,
                               const float* __restrict__ Wf, unsigned short* __restrict__ Wtf){
  int idx = blockIdx.x*256 + threadIdx.x;
  const float* W; unsigned short* Wt; int K, N;
  if (idx < 131072){ W = W1; Wt = Wt1; K = 512; N = 256; }
  else if (idx < 163840){ idx -= 131072; W = Wc1; Wt = Wtc1; K = 256; N = 128; }
  else if (idx < 196608){ idx -= 163840; W = Wc2; Wt = Wtc2; K = 256; N = 128; }
  else if (idx < 245760){ idx -= 196608; W = Wf; Wt = Wtf; K = 768; N = 40; }
  else return;
  int nn = idx / K, kk = idx - nn*K;
  float v = (nn < N) ? W[(size_t)kk*N + nn] : 0.f;
  Wt[idx] = f2bf(v);
}

// ---------- graph preprocessing (bucketed, atomic-light, fixed-capacity) ----------
// Buckets of 128 destination nodes, fixed staging capacity per bucket
// (mean + >17 sigma for uniform-random edges -> overflow prob ~1e-50).
// partA partitions edges into staging with per-block LDS histograms; its
// cursors' final values double as per-bucket end markers for degB/partB,
// eliminating the separate count+scan passes (cntA/bscan of R9).

// init bucket cursors to fixed bases; zero the two T pad rows
__global__ void binit_kernel(int* __restrict__ bcur, int NB, int cap1r, int cap2r,
                             unsigned* __restrict__ Tz0, unsigned* __restrict__ Tz1){
  int i = blockIdx.x*256 + threadIdx.x;
  if (i < NB) bcur[i] = i*cap1r;
  else if (i < 2*NB) bcur[i] = NB*cap1r + (i - NB)*cap2r;
  else if (i < 2*NB + 32) Tz0[i - 2*NB] = 0u;
  else if (i < 2*NB + 64) Tz1[i - 2*NB - 32] = 0u;
}

// Pass A: partition 8192-edge chunks into bucket staging
__global__ __launch_bounds__(256) void partA_kernel(
    const int* __restrict__ ei1, int E1, const int* __restrict__ ei2, int E2,
    int* __restrict__ bcur, unsigned* __restrict__ staging, int NB)
{
  const int set = blockIdx.y;
  const int* __restrict__ ei = set ? ei2 : ei1;
  const int E = set ? E2 : E1;
  int* __restrict__ cur = bcur + set*NB;
  __shared__ int hist[400];
  __shared__ int resv[400];
  const int tid = threadIdx.x;
  const int base = blockIdx.x * 8192;
  if (base >= E) return;
  for (int b = tid; b < NB; b += 256) hist[b] = 0;
  __syncthreads();
  #pragma unroll 4
  for (int i = 0; i < 32; ++i){
    int e = base + i*256 + tid;
    if (e < E) atomicAdd(&hist[ei[E + e] >> 7], 1);
  }
  __syncthreads();
  for (int b = tid; b < NB; b += 256){
    int hc = hist[b];
    resv[b] = hc ? atomicAdd(&cur[b], hc) : 0;
    hist[b] = 0;                      // reuse as local cursor
  }
  __syncthreads();
  #pragma unroll 4
  for (int i = 0; i < 32; ++i){
    int e = base + i*256 + tid;
    if (e < E){
      int c = ei[E + e], r = ei[e];
      int b = c >> 7;
      int s = resv[b] + atomicAdd(&hist[b], 1);
      staging[s] = ((unsigned)r << 7) | (unsigned)(c & 127);
    }
  }
}

// per-node degrees + dis from staging: LDS counters, contiguous global writes
__global__ __launch_bounds__(256) void degB_kernel(
    const unsigned* __restrict__ staging, const int* __restrict__ bcur,
    int* __restrict__ deg1, int* __restrict__ deg2,
    float* __restrict__ dis1, float* __restrict__ dis2,
    int NB, int n, int cap1r, int cap2r)
{
  const int set = blockIdx.y;
  int* __restrict__ deg = set ? deg2 : deg1;
  float* __restrict__ dis = set ? dis2 : dis1;
  const int b = blockIdx.x;
  const int nodebase = b << 7;
  const int nn = min(128, n - nodebase);
  if (nn <= 0) return;
  __shared__ int cnt[128];
  const int tid = threadIdx.x;
  if (tid < 128) cnt[tid] = 0;
  __syncthreads();
  const int s0 = set ? (NB*cap1r + b*cap2r) : (b*cap1r);
  const int s1 = bcur[set*NB + b];
  for (int i = s0 + tid; i < s1; i += 256)
    atomicAdd(&cnt[staging[i] & 127], 1);
  __syncthreads();
  if (tid < nn){
    int c = cnt[tid];
    deg[nodebase + tid] = c;
    dis[nodebase + tid] = (c > 0) ? (1.0f/sqrtf((float)c)) : 0.f;
  }
}

// scans run on PADDED degrees: pdeg = (deg+7)&~7  (8-edge multiples per node)
__global__ void scan1_kernel(const int* __restrict__ deg1, const int* __restrict__ deg2,
                             int* __restrict__ off1, int* __restrict__ off2,
                             int* __restrict__ bsum, int n){
  __shared__ int s[1024];
  int set = blockIdx.y;
  const int* deg = set ? deg2 : deg1;
  int* off = set ? off2 : off1;
  int tid = threadIdx.x;
  int i = blockIdx.x*1024 + tid;
  int v = (i < n) ? ((deg[i] + 7) & ~7) : 0;
  s[tid] = v;
  __syncthreads();
  for (int o = 1; o < 1024; o <<= 1){
    int t = (tid >= o) ? s[tid - o] : 0;
    __syncthreads();
    s[tid] += t;
    __syncthreads();
  }
  if (i < n) off[i] = s[tid];          // inclusive, chunk-local (fixed in pass 3)
  if (tid == 1023) bsum[set*64 + blockIdx.x] = s[1023];
}

__global__ void scan2_kernel(const int* __restrict__ bsum, int* __restrict__ bbase,
                             int nch, int* __restrict__ off1, int* __restrict__ off2, int n){
  int set = threadIdx.x;
  if (set < 2){
    int run = 0;
    for (int j = 0; j < nch; ++j){ bbase[set*64 + j] = run; run += bsum[set*64 + j]; }
    (set ? off2 : off1)[n] = run;      // total padded edge count
  }
}

__global__ void scan3_kernel(const int* __restrict__ deg1, const int* __restrict__ deg2,
                             int* __restrict__ off1, int* __restrict__ off2,
                             const int* __restrict__ bbase, int n){
  int set = blockIdx.y;
  const int* deg = set ? deg2 : deg1;
  int* off = set ? off2 : off1;
  int i = blockIdx.x*1024 + threadIdx.x;
  if (i < n){
    int e = off[i] + bbase[set*64 + blockIdx.x];
    off[i] = e - ((deg[i] + 7) & ~7);  // exclusive global padded prefix
  }
}

// Pass B: per-bucket local scatter + padding (pad record = padrow);
// block 0 of each set also fills the speculative-prefetch slack past off[n]
__global__ __launch_bounds__(256) void partB_kernel(
    const unsigned* __restrict__ staging, const int* __restrict__ bcur,
    const int* __restrict__ off1, const int* __restrict__ off2,
    unsigned* __restrict__ csr1, unsigned* __restrict__ csr2,
    int NB, int n, unsigned padrow, int cap1r, int cap2r)
{
  const int set = blockIdx.y;
  const int* __restrict__ off = set ? off2 : off1;
  unsigned* __restrict__ csr = set ? csr2 : csr1;
  const int b = blockIdx.x;
  const int nodebase = b << 7;
  const int nn = min(128, n - nodebase);
  if (nn <= 0) return;
  __shared__ int offv[129];
  __shared__ int curl[128];
  const int tid = threadIdx.x;
  if (tid <= nn) offv[tid] = off[nodebase + tid];
  if (tid < 128) curl[tid] = 0;
  __syncthreads();
  const int s0 = set ? (NB*cap1r + b*cap2r) : (b*cap1r);
  const int s1 = bcur[set*NB + b];
  for (int i = s0 + tid; i < s1; i += 256){
    unsigned v = staging[i];
    int cl = v & 127;
    int p = offv[cl] + atomicAdd(&curl[cl], 1);
    csr[p] = v >> 7;
  }
  __syncthreads();
  for (int c = tid; c < nn; c += 256){
    int p1 = offv[c+1];
    for (int p = offv[c] + curl[c]; p < p1; ++p) csr[p] = padrow;
  }
  if (b == 0 && tid < 64) csr[off[n] + tid] = padrow;   // slack fill
}

// ---------- GCN aggregation: out[c] = dis[c] * sum_e T_set[r] + b ----------
// T_set rows are PRE-SCALED by dis_set[r] and stored fp8 e4m3: 128B/row = 2 lines
// per edge (vs 4 at bf16) -> halves beyond-L2 line traffic at the MSHR wall.
// Half-wave h consumes edges 8b+4h..8b+4h+3 (one contiguous uint4 record load);
// lane covers 4 features (4B gather). 2-stage pipeline, padded CSR (pad row = n).
__global__ __launch_bounds__(256) void conv_kernel(
    const int* __restrict__ off1, const unsigned* __restrict__ csr1, const float* __restrict__ dis1,
    const int* __restrict__ off2, const unsigned* __restrict__ csr2, const float* __restrict__ dis2,
    const unsigned char* __restrict__ Tbase,   // [2][ntab][128] fp8
    const float* __restrict__ bias, unsigned short* __restrict__ outR,
    int n, int ntab)
{
  const int set = blockIdx.y;
  const int* __restrict__ off = set ? off2 : off1;
  const float* __restrict__ dis = set ? dis2 : dis1;
  const unsigned* __restrict__ csrq = set ? csr2 : csr1;
  const int col_ofs = set ? 128 : 0;
  const unsigned* __restrict__ tab =
      (const unsigned*)(Tbase + (size_t)set * ntab * 128);

  int wv = blockIdx.x*4 + (threadIdx.x >> 6);
  if (wv >= n) return;
  const int l = threadIdx.x & 63;
  const int half = l >> 5, lf = l & 31;
  const int s = off[wv], e = off[wv+1];
  const int nb = (e - s) >> 3;               // 8-edge batches (exact, padded)
  const unsigned* cp = csrq + s + half*4;    // this half's 4 records per batch

  float ax = 0.f, ay = 0.f, az = 0.f, aw = 0.f;

  if (nb > 0){
    u32x4 qa, qb;
    unsigned va0, va1, va2, va3, vb0, vb1, vb2, vb3;

#define LQ(q, B) q = __builtin_nontemporal_load((const u32x4*)(cp + (B)*8));
#define GATH(v, q) \
    v##0 = tab[(size_t)q.x * 32 + lf]; \
    v##1 = tab[(size_t)q.y * 32 + lf]; \
    v##2 = tab[(size_t)q.z * 32 + lf]; \
    v##3 = tab[(size_t)q.w * 32 + lf];
#define FMA1(v) { \
    f32x2 lo = __builtin_amdgcn_cvt_pk_f32_fp8((int)v, false); \
    f32x2 hi = __builtin_amdgcn_cvt_pk_f32_fp8((int)v, true);  \
    ax += lo.x; ay += lo.y; az += hi.x; aw += hi.y; }
#define FMAB(v) { FMA1(v##0) FMA1(v##1) FMA1(v##2) FMA1(v##3) }

    LQ(qa, 0)
    GATH(va, qa)
    LQ(qb, 1)
    int b = 0;
    while (b + 2 <= nb){
      LQ(qa, b + 2)              // speculative reads stay inside filled csr capacity
      GATH(vb, qb)
      FMAB(va)
      LQ(qb, b + 3)
      GATH(va, qa)               // may gather next node's rows / pad rows; unused unless valid
      FMAB(vb)
      b += 2;
    }
    if (b < nb) FMAB(va)
#undef LQ
#undef GATH
#undef FMA1
#undef FMAB
  }

  // combine the two half-wave partial sums
  ax += __shfl_xor(ax, 32, 64);
  ay += __shfl_xor(ay, 32, 64);
  az += __shfl_xor(az, 32, 64);
  aw += __shfl_xor(aw, 32, 64);

  if (half == 0){
    const float dc = dis[wv];
    float b0 = bias[lf*4 + 0], b1 = bias[lf*4 + 1];
    float b2 = bias[lf*4 + 2], b3 = bias[lf*4 + 3];
    ull ov = (ull)((unsigned)f2bf(fmaf(dc, ax, b0)) | ((unsigned)f2bf(fmaf(dc, ay, b1)) << 16))
           | ((ull)((unsigned)f2bf(fmaf(dc, az, b2)) | ((unsigned)f2bf(fmaf(dc, aw, b3)) << 16)) << 32);
    __builtin_nontemporal_store(ov, (ull*)&outR[(size_t)wv*256 + col_ofs + lf*4]);
  }
}

// ---------- bf16 MFMA GEMM, m97-style 2-barrier loop ----------
// A [M x K] bf16 row-major (lda); AF32: A is f32, converted to bf16 during
// reg-staging (fuses the former cvt_x pass into GEMM1 -> -102MB traffic).
// Bt = B^T stored [BN_total x K] bf16.
// EPI 1: +bias, relu, bf16 store;
// EPI 2: A = 3 slabs (h|R1|R2, lda=256 each), +bias, fused log_softmax, f32 store;
// EPI 4: dual fp8 table store T[set][row][col] = fp8(vv * dis_set[row]).
template<int FM, int FN, int WGM, int WGN, int EPI, bool AF32>
__global__ __launch_bounds__(256, 2) void gemm_kernel(
    const unsigned short* __restrict__ A0, const float* __restrict__ Af,
    const unsigned short* __restrict__ A1, const unsigned short* __restrict__ A2,
    const unsigned short* __restrict__ Bt, const float* __restrict__ bias,
    void* __restrict__ Cout, int M, int K, int lda, int ldc,
    const float* __restrict__ d1, const float* __restrict__ d2, int ntab)
{
  constexpr int BM = WGM*FM*16;
  constexpr int BN = WGN*FN*16;
  constexpr int BK = 32;
  static_assert(BM == 128, "staging assumes BM==128");
  __shared__ unsigned short As[BM][BK];
  __shared__ unsigned short Bs[BN][BK];
  const int tid = threadIdx.x;
  const int w = tid >> 6, l = tid & 63;
  const int wr = w / WGN, wc = w % WGN;
  const int m0 = blockIdx.x*BM, n0 = blockIdx.y*BN;
  f32x4 acc[FM][FN] = {};
  const int nsteps = K / BK;
  for (int s = 0; s < nsteps; ++s){
    const int k0 = s*BK;
    const unsigned short* Asrc = A0;
    int kin = k0;
    if constexpr (EPI == 2){
      int slab = k0 >> 8;
      Asrc = (slab == 0) ? A0 : ((slab == 1) ? A1 : A2);
      kin = k0 & 255;
    }
    __syncthreads();
    if constexpr (AF32){
      #pragma unroll
      for (int j = 0; j < 2; ++j){         // A: load f32, cvt, store 16B to LDS
        int idx = j*256 + tid;
        int row = idx >> 2, kq = idx & 3;
        int rg = m0 + row; rg = (rg < M) ? rg : (M - 1);
        const float* src = Af + (size_t)rg*lda + kin + kq*8;
        float4 a = *(const float4*)src;
        float4 b2 = *(const float4*)(src + 4);
        ushort8v u;
        u[0] = f2bf(a.x);  u[1] = f2bf(a.y);  u[2] = f2bf(a.z);  u[3] = f2bf(a.w);
        u[4] = f2bf(b2.x); u[5] = f2bf(b2.y); u[6] = f2bf(b2.z); u[7] = f2bf(b2.w);
        *(ushort8v*)((char*)&As[0][0] + (size_t)idx*16) = u;
      }
    } else {
      #pragma unroll
      for (int j = 0; j < 2; ++j){         // A: 8KB = 2 x 4KB issues
        int idx = j*256 + tid;
        int row = idx >> 2, kq = idx & 3;
        int rg = m0 + row; rg = (rg < M) ? rg : (M - 1);
        load_lds16(Asrc + (size_t)rg*lda + kin + kq*8,
                   ((char*)&As[0][0]) + (size_t)(j*256 + w*64)*16);
      }
    }
    #pragma unroll
    for (int j = 0; j < BN/64; ++j){       // Bt: [n][k] layout, same pattern as A
      int idx = j*256 + tid;
      int row = idx >> 2, kq = idx & 3;
      load_lds16(Bt + (size_t)(n0 + row)*K + k0 + kq*8,
                 ((char*)&Bs[0][0]) + (size_t)(j*256 + w*64)*16);
    }
    __syncthreads();
    bf16x8 af[FM], bfr[FN];
    const int kofs = (l >> 4)*8, l16 = l & 15;
    #pragma unroll
    for (int mi = 0; mi < FM; ++mi)
      af[mi] = *(const bf16x8*)&As[wr*FM*16 + mi*16 + l16][kofs];
    #pragma unroll
    for (int ni = 0; ni < FN; ++ni)
      bfr[ni] = *(const bf16x8*)&Bs[wc*FN*16 + ni*16 + l16][kofs];
    #pragma unroll
    for (int mi = 0; mi < FM; ++mi)
      #pragma unroll
      for (int ni = 0; ni < FN; ++ni)
        acc[mi][ni] = __builtin_amdgcn_mfma_f32_16x16x32_bf16(af[mi], bfr[ni], acc[mi][ni], 0, 0, 0);
  }
  const int lg = l >> 4, lc = l & 15;
  if constexpr (EPI == 2){
    float* O = (float*)Cout;
    #pragma unroll
    for (int mi = 0; mi < FM; ++mi){
      #pragma unroll
      for (int i = 0; i < 4; ++i){
        int row = m0 + wr*FM*16 + mi*16 + lg*4 + i;
        float v[FN];
        float mx = -1e30f;
        #pragma unroll
        for (int ni = 0; ni < FN; ++ni){
          int col = ni*16 + lc;                       // WGN==1, n0==0
          v[ni] = acc[mi][ni][i] + ((col < 40) ? bias[col] : 0.f);
          if (col < 40) mx = fmaxf(mx, v[ni]);
        }
        #pragma unroll
        for (int d = 1; d < 16; d <<= 1) mx = fmaxf(mx, __shfl_xor(mx, d, 64));
        float se = 0.f;
        #pragma unroll
        for (int ni = 0; ni < FN; ++ni){
          int col = ni*16 + lc;
          if (col < 40) se += expf(v[ni] - mx);
        }
        #pragma unroll
        for (int d = 1; d < 16; d <<= 1) se += __shfl_xor(se, d, 64);
        float lse = logf(se);
        if (row < M){
          #pragma unroll
          for (int ni = 0; ni < FN; ++ni){
            int col = ni*16 + lc;
            if (col < 40) O[(size_t)row*40 + col] = v[ni] - mx - lse;
          }
        }
      }
    }
  } else if constexpr (EPI == 4){
    unsigned char* T = (unsigned char*)Cout;            // [2][ntab][128]
    #pragma unroll
    for (int mi = 0; mi < FM; ++mi){
      #pragma unroll
      for (int i = 0; i < 4; ++i){
        int row = m0 + wr*FM*16 + mi*16 + lg*4 + i;
        if (row >= M) continue;
        float s1 = d1[row], s2 = d2[row];
        #pragma unroll
        for (int ni = 0; ni < FN; ++ni){
          int col = n0 + wc*FN*16 + ni*16 + lc;        // [0,128)
          float vv = acc[mi][ni][i];
          unsigned p1 = (unsigned)__builtin_amdgcn_cvt_pk_fp8_f32(vv*s1, vv*s1, 0, false);
          unsigned p2 = (unsigned)__builtin_amdgcn_cvt_pk_fp8_f32(vv*s2, vv*s2, 0, false);
          T[(size_t)row*128 + col] = (unsigned char)(p1 & 0xff);
          T[((size_t)ntab + row)*128 + col] = (unsigned char)(p2 & 0xff);
        }
      }
    }
  } else {
    unsigned short* C = (unsigned short*)Cout;
    #pragma unroll
    for (int mi = 0; mi < FM; ++mi){
      #pragma unroll
      for (int i = 0; i < 4; ++i){
        int row = m0 + wr*FM*16 + mi*16 + lg*4 + i;
        if (row >= M) continue;
        #pragma unroll
        for (int ni = 0; ni < FN; ++ni){
          int col = n0 + wc*FN*16 + ni*16 + lc;
          float vv = acc[mi][ni][i];
          if constexpr (EPI == 1){ vv += bias[col]; vv = fmaxf(vv, 0.f); }
          C[(size_t)row*ldc + col] = f2bf(vv);
        }
      }
    }
  }
}

extern "C" void kernel_launch(void* const* d_in, const int* in_sizes, int n_in,
                              void* d_out, int out_size, void* d_ws, size_t ws_size,
                              hipStream_t stream)
{
  (void)n_in; (void)out_size;
  const float* x      = (const float*)d_in[0];
  const int*   ei1    = (const int*)d_in[1];
  const int*   ei2    = (const int*)d_in[2];
  const float* W_lin1 = (const float*)d_in[3];
  const float* b_lin1 = (const float*)d_in[4];
  const float* W_c1   = (const float*)d_in[5];
  const float* b_c1   = (const float*)d_in[6];
  const float* W_c2   = (const float*)d_in[7];
  const float* b_c2   = (const float*)d_in[8];
  const float* W_lin2 = (const float*)d_in[9];
  const float* b_lin2 = (const float*)d_in[10];

  const int N  = in_sizes[0] / 512;
  const int E1 = in_sizes[1] / 2;
  const int E2 = in_sizes[2] / 2;
  const int ntab = N + 1;                    // +1 zero row for pad edges
  const int NB = (N + 127) >> 7;             // destination buckets of 128 nodes
  // fixed per-bucket staging capacities (uniform edges: mean + >17 sigma)
  const int cap1r = ((2*E1/ (NB) ) > 0 ? 0 : 0) + ( (E1 + NB - 1)/NB + 768 + 63 ) & ~63;
  const int cap2r = ( (E2 + NB - 1)/NB + 1536 + 63 ) & ~63;

  char* base = (char*)d_ws;
  size_t off = 0;
  auto alloc = [&](size_t bytes) -> char* {
    off = (off + 255) & ~(size_t)255;
    char* r = base + off;
    off += bytes;
    return r;
  };
  // padded-CSR capacities in 4B records (pad <= 7 per node, + speculative slack)
  const size_t cap1 = (size_t)E1 + 8*(size_t)N + 64;
  const size_t cap2 = (size_t)E2 + 8*(size_t)N + 64;

  unsigned short* h    = (unsigned short*)alloc((size_t)N*256*2);
  unsigned char*  T    = (unsigned char*)alloc((size_t)2*ntab*128); // fp8 scaled tables
  unsigned short* R1   = (unsigned short*)alloc((size_t)N*256*2);
  unsigned short* R2   = (unsigned short*)alloc((size_t)N*256*2);
  unsigned short* Wt1  = (unsigned short*)alloc((size_t)256*512*2);
  unsigned short* Wtc1 = (unsigned short*)alloc((size_t)128*256*2);
  unsigned short* Wtc2 = (unsigned short*)alloc((size_t)128*256*2);
  unsigned short* Wtf  = (unsigned short*)alloc((size_t)64*768*2); // W_lin2^T padded to 64 cols
  int* degblk = (int*)alloc((size_t)2*N*4);
  int* deg1 = degblk, *deg2 = degblk + N;
  float* dis1 = (float*)alloc((size_t)N*4);
  float* dis2 = (float*)alloc((size_t)N*4);
  int* off1 = (int*)alloc((size_t)(N+1)*4);
  int* off2 = (int*)alloc((size_t)(N+1)*4);
  int* bsum  = (int*)alloc(128*4);
  int* bbase = (int*)alloc(128*4);
  int* bcur  = (int*)alloc((size_t)2*NB*4);
  unsigned* csr1 = (unsigned*)alloc(cap1*4);
  unsigned* csr2 = (unsigned*)alloc(cap2*4);
  unsigned* staging = (unsigned*)alloc((size_t)NB*((size_t)cap1r + cap2r)*4);
  if (off > ws_size) return;   // workspace insufficient -> visible validation failure

  int mt = (N + 127)/128;
  int cb = (N + 3)/4;

  // --- dense front: weight transposes + GEMM1 (reads x f32 directly, fused cvt) ---
  wtrans4_kernel<<<960, 256, 0, stream>>>(W_lin1, Wt1, W_c1, Wtc1, W_c2, Wtc2, W_lin2, Wtf);
  gemm_kernel<4,4,2,2,1,true><<<dim3(mt, 2), 256, 0, stream>>>(
      nullptr, x, nullptr, nullptr, Wt1, b_lin1, h, N, 512, 512, 256, nullptr, nullptr, 0);

  // --- graph preprocessing (bucketed, fixed-capacity staging) ---
  binit_kernel<<<(2*NB + 64 + 255)/256, 256, 0, stream>>>(
      bcur, NB, cap1r, cap2r,
      (unsigned*)(T + (size_t)N*128), (unsigned*)(T + ((size_t)ntab + N)*128));
  partA_kernel<<<dim3((E2 + 8191)/8192, 2), 256, 0, stream>>>(ei1, E1, ei2, E2, bcur, staging, NB);
  degB_kernel<<<dim3(NB, 2), 256, 0, stream>>>(staging, bcur, deg1, deg2, dis1, dis2,
                                               NB, N, cap1r, cap2r);
  int nch = (N + 1023)/1024;
  scan1_kernel<<<dim3(nch, 2), 1024, 0, stream>>>(deg1, deg2, off1, off2, bsum, N);
  scan2_kernel<<<1, 64, 0, stream>>>(bsum, bbase, nch, off1, off2, N);
  scan3_kernel<<<dim3(nch, 2), 1024, 0, stream>>>(deg1, deg2, off1, off2, bbase, N);
  partB_kernel<<<dim3(NB, 2), 256, 0, stream>>>(staging, bcur, off1, off2, csr1, csr2,
                                                NB, N, (unsigned)N, cap1r, cap2r);

  // --- layer 1: T = fp8(dis_set[r] * (h @ W_c1)[r]), then one conv pass ---
  gemm_kernel<4,4,2,2,4,false><<<dim3(mt, 1), 256, 0, stream>>>(
      h, nullptr, nullptr, nullptr, Wtc1, nullptr, T, N, 256, 256, 0, dis1, dis2, ntab);
  conv_kernel<<<dim3(cb, 2), 256, 0, stream>>>(off1, csr1, dis1, off2, csr2, dis2,
                                               T, b_c1, R1, N, ntab);
  // --- layer 2: T = fp8(dis_set[r] * (R1 @ W_c2)[r]), conv ---
  gemm_kernel<4,4,2,2,4,false><<<dim3(mt, 1), 256, 0, stream>>>(
      R1, nullptr, nullptr, nullptr, Wtc2, nullptr, T, N, 256, 256, 0, dis1, dis2, ntab);
  conv_kernel<<<dim3(cb, 2), 256, 0, stream>>>(off1, csr1, dis1, off2, csr2, dis2,
                                               T, b_c2, R2, N, ntab);
  // --- head: logits = [h|R1|R2] @ W_lin2 + b, fused log_softmax ---
  gemm_kernel<2,4,4,1,2,false><<<dim3(mt, 1), 256, 0, stream>>>(
      h, nullptr, R1, R2, Wtf, b_lin2, d_out, N, 768, 256, 40, nullptr, nullptr, 0);
}

// Round 11
// 275.697 us; speedup vs baseline: 3.5895x; 1.0240x over previous
//
#include <hip/hip_runtime.h>
#include <hip/hip_bf16.h>
#include <stdint.h>

typedef __attribute__((ext_vector_type(8))) short bf16x8;
typedef __attribute__((ext_vector_type(8))) unsigned short ushort8v;
typedef __attribute__((ext_vector_type(4))) float f32x4;
typedef __attribute__((ext_vector_type(2))) float f32x2;
typedef __attribute__((ext_vector_type(4))) unsigned int u32x4;
typedef unsigned long long ull;

__device__ __forceinline__ void load_lds16(const void* g, void* l){
  __builtin_amdgcn_global_load_lds((const __attribute__((address_space(1))) void*)g,
                                   (__attribute__((address_space(3))) void*)l, 16, 0, 0);
}

__device__ __forceinline__ float bf2f(unsigned int u){
  union { unsigned int i; float f; } x; x.i = u << 16; return x.f;
}
__device__ __forceinline__ unsigned short f2bf(float f){
  __hip_bfloat16 h = __float2bfloat16(f);
  unsigned short u;
  __builtin_memcpy(&u, &h, 2);
  return u;
}

// ---------- fused weight transposes (4 matrices, one dispatch) ----------
__global__ void wtrans4_kernel(const float* __restrict__ W1, unsigned short* __restrict__ Wt1,
                               const float* __restrict__ Wc1, unsigned short* __restrict__ Wtc1,
                               const float* __restrict__ Wc2, unsigned short* __restrict__ Wtc2,
                               const float* __restrict__ Wf, unsigned short* __restrict__ Wtf){
  int idx = blockIdx.x*256 + threadIdx.x;
  const float* W; unsigned short* Wt; int K, N;
  if (idx < 131072){ W = W1; Wt = Wt1; K = 512; N = 256; }
  else if (idx < 163840){ idx -= 131072; W = Wc1; Wt = Wtc1; K = 256; N = 128; }
  else if (idx < 196608){ idx -= 163840; W = Wc2; Wt = Wtc2; K = 256; N = 128; }
  else if (idx < 245760){ idx -= 196608; W = Wf; Wt = Wtf; K = 768; N = 40; }
  else return;
  int nn = idx / K, kk = idx - nn*K;
  float v = (nn < N) ? W[(size_t)kk*N + nn] : 0.f;
  Wt[idx] = f2bf(v);
}

// ---------- graph preprocessing (bucketed, atomic-light, fixed-capacity) ----------
// Buckets of 128 destination nodes, fixed staging capacity per bucket
// (mean + >17 sigma for uniform-random edges -> overflow prob ~1e-50).
// partA partitions edges into staging; its cursors' final values double as
// per-bucket end markers for degB/partB. R10 post-mortem: partA compiled to
// 8 VGPRs -> ~1 load in flight -> latency-serialized at 60us. Now each
// thread owns 16 contiguous edges, loads rows+cols as 8 int4s up front
// (registers held across phases), chunk 4096 -> 782 blocks for overlap.

#define PCH 4096

// init bucket cursors to fixed bases; zero the two T pad rows
__global__ void binit_kernel(int* __restrict__ bcur, int NB, int cap1r, int cap2r,
                             unsigned* __restrict__ Tz0, unsigned* __restrict__ Tz1){
  int i = blockIdx.x*256 + threadIdx.x;
  if (i < NB) bcur[i] = i*cap1r;
  else if (i < 2*NB) bcur[i] = NB*cap1r + (i - NB)*cap2r;
  else if (i < 2*NB + 32) Tz0[i - 2*NB] = 0u;
  else if (i < 2*NB + 64) Tz1[i - 2*NB - 32] = 0u;
}

// Pass A: partition PCH-edge chunks into bucket staging
__global__ __launch_bounds__(256) void partA_kernel(
    const int* __restrict__ ei1, int E1, const int* __restrict__ ei2, int E2,
    int* __restrict__ bcur, unsigned* __restrict__ staging, int NB)
{
  const int set = blockIdx.y;
  const int* __restrict__ ei = set ? ei2 : ei1;
  const int E = set ? E2 : E1;
  int* __restrict__ cur = bcur + set*NB;
  __shared__ int hist[400];
  __shared__ int resv[400];
  const int tid = threadIdx.x;
  const int base = blockIdx.x * PCH;
  if (base >= E) return;
  for (int b = tid; b < NB; b += 256) hist[b] = 0;
  __syncthreads();

  if (base + PCH <= E){
    // fast path: 16 edges/thread, rows+cols vector-loaded up front (8x int4 in flight)
    const int t0 = base + tid*16;
    int4 c[4], r[4];
    #pragma unroll
    for (int j = 0; j < 4; ++j) c[j] = *(const int4*)(ei + E + t0 + j*4);
    #pragma unroll
    for (int j = 0; j < 4; ++j) r[j] = *(const int4*)(ei + t0 + j*4);
    #pragma unroll
    for (int j = 0; j < 4; ++j){
      atomicAdd(&hist[c[j].x >> 7], 1); atomicAdd(&hist[c[j].y >> 7], 1);
      atomicAdd(&hist[c[j].z >> 7], 1); atomicAdd(&hist[c[j].w >> 7], 1);
    }
    __syncthreads();
    for (int b = tid; b < NB; b += 256){
      int hc = hist[b];
      resv[b] = hc ? atomicAdd(&cur[b], hc) : 0;
      hist[b] = 0;                      // reuse as local cursor
    }
    __syncthreads();
    #pragma unroll
    for (int j = 0; j < 4; ++j){
      int cc, rr, b, s;
      cc = c[j].x; rr = r[j].x; b = cc >> 7;
      s = resv[b] + atomicAdd(&hist[b], 1);
      staging[s] = ((unsigned)rr << 7) | (unsigned)(cc & 127);
      cc = c[j].y; rr = r[j].y; b = cc >> 7;
      s = resv[b] + atomicAdd(&hist[b], 1);
      staging[s] = ((unsigned)rr << 7) | (unsigned)(cc & 127);
      cc = c[j].z; rr = r[j].z; b = cc >> 7;
      s = resv[b] + atomicAdd(&hist[b], 1);
      staging[s] = ((unsigned)rr << 7) | (unsigned)(cc & 127);
      cc = c[j].w; rr = r[j].w; b = cc >> 7;
      s = resv[b] + atomicAdd(&hist[b], 1);
      staging[s] = ((unsigned)rr << 7) | (unsigned)(cc & 127);
    }
  } else {
    // tail path: guarded scalar
    for (int i = 0; i < PCH/256; ++i){
      int e = base + i*256 + tid;
      if (e < E) atomicAdd(&hist[ei[E + e] >> 7], 1);
    }
    __syncthreads();
    for (int b = tid; b < NB; b += 256){
      int hc = hist[b];
      resv[b] = hc ? atomicAdd(&cur[b], hc) : 0;
      hist[b] = 0;
    }
    __syncthreads();
    for (int i = 0; i < PCH/256; ++i){
      int e = base + i*256 + tid;
      if (e < E){
        int c = ei[E + e], r = ei[e];
        int b = c >> 7;
        int s = resv[b] + atomicAdd(&hist[b], 1);
        staging[s] = ((unsigned)r << 7) | (unsigned)(c & 127);
      }
    }
  }
}

// per-node degrees + dis from staging: LDS counters, contiguous global writes
__global__ __launch_bounds__(256) void degB_kernel(
    const unsigned* __restrict__ staging, const int* __restrict__ bcur,
    int* __restrict__ deg1, int* __restrict__ deg2,
    float* __restrict__ dis1, float* __restrict__ dis2,
    int NB, int n, int cap1r, int cap2r)
{
  const int set = blockIdx.y;
  int* __restrict__ deg = set ? deg2 : deg1;
  float* __restrict__ dis = set ? dis2 : dis1;
  const int b = blockIdx.x;
  const int nodebase = b << 7;
  const int nn = min(128, n - nodebase);
  if (nn <= 0) return;
  __shared__ int cnt[128];
  const int tid = threadIdx.x;
  if (tid < 128) cnt[tid] = 0;
  __syncthreads();
  const int s0 = set ? (NB*cap1r + b*cap2r) : (b*cap1r);
  const int s1 = bcur[set*NB + b];
  for (int i = s0 + tid; i < s1; i += 256)
    atomicAdd(&cnt[staging[i] & 127], 1);
  __syncthreads();
  if (tid < nn){
    int c = cnt[tid];
    deg[nodebase + tid] = c;
    dis[nodebase + tid] = (c > 0) ? (1.0f/sqrtf((float)c)) : 0.f;
  }
}

// scans run on PADDED degrees: pdeg = (deg+7)&~7  (8-edge multiples per node)
__global__ void scan1_kernel(const int* __restrict__ deg1, const int* __restrict__ deg2,
                             int* __restrict__ off1, int* __restrict__ off2,
                             int* __restrict__ bsum, int n){
  __shared__ int s[1024];
  int set = blockIdx.y;
  const int* deg = set ? deg2 : deg1;
  int* off = set ? off2 : off1;
  int tid = threadIdx.x;
  int i = blockIdx.x*1024 + tid;
  int v = (i < n) ? ((deg[i] + 7) & ~7) : 0;
  s[tid] = v;
  __syncthreads();
  for (int o = 1; o < 1024; o <<= 1){
    int t = (tid >= o) ? s[tid - o] : 0;
    __syncthreads();
    s[tid] += t;
    __syncthreads();
  }
  if (i < n) off[i] = s[tid];          // inclusive, chunk-local (fixed in pass 3)
  if (tid == 1023) bsum[set*64 + blockIdx.x] = s[1023];
}

__global__ void scan2_kernel(const int* __restrict__ bsum, int* __restrict__ bbase,
                             int nch, int* __restrict__ off1, int* __restrict__ off2, int n){
  int set = threadIdx.x;
  if (set < 2){
    int run = 0;
    for (int j = 0; j < nch; ++j){ bbase[set*64 + j] = run; run += bsum[set*64 + j]; }
    (set ? off2 : off1)[n] = run;      // total padded edge count
  }
}

__global__ void scan3_kernel(const int* __restrict__ deg1, const int* __restrict__ deg2,
                             int* __restrict__ off1, int* __restrict__ off2,
                             const int* __restrict__ bbase, int n){
  int set = blockIdx.y;
  const int* deg = set ? deg2 : deg1;
  int* off = set ? off2 : off1;
  int i = blockIdx.x*1024 + threadIdx.x;
  if (i < n){
    int e = off[i] + bbase[set*64 + blockIdx.x];
    off[i] = e - ((deg[i] + 7) & ~7);  // exclusive global padded prefix
  }
}

// Pass B: per-bucket local scatter + padding (pad record = padrow);
// block 0 of each set also fills the speculative-prefetch slack past off[n]
__global__ __launch_bounds__(256) void partB_kernel(
    const unsigned* __restrict__ staging, const int* __restrict__ bcur,
    const int* __restrict__ off1, const int* __restrict__ off2,
    unsigned* __restrict__ csr1, unsigned* __restrict__ csr2,
    int NB, int n, unsigned padrow, int cap1r, int cap2r)
{
  const int set = blockIdx.y;
  const int* __restrict__ off = set ? off2 : off1;
  unsigned* __restrict__ csr = set ? csr2 : csr1;
  const int b = blockIdx.x;
  const int nodebase = b << 7;
  const int nn = min(128, n - nodebase);
  if (nn <= 0) return;
  __shared__ int offv[129];
  __shared__ int curl[128];
  const int tid = threadIdx.x;
  if (tid <= nn) offv[tid] = off[nodebase + tid];
  if (tid < 128) curl[tid] = 0;
  __syncthreads();
  const int s0 = set ? (NB*cap1r + b*cap2r) : (b*cap1r);
  const int s1 = bcur[set*NB + b];
  for (int i = s0 + tid; i < s1; i += 256){
    unsigned v = staging[i];
    int cl = v & 127;
    int p = offv[cl] + atomicAdd(&curl[cl], 1);
    csr[p] = v >> 7;
  }
  __syncthreads();
  for (int c = tid; c < nn; c += 256){
    int p1 = offv[c+1];
    for (int p = offv[c] + curl[c]; p < p1; ++p) csr[p] = padrow;
  }
  if (b == 0 && tid < 64) csr[off[n] + tid] = padrow;   // slack fill
}

// ---------- GCN aggregation: out[c] = dis[c] * sum_e T_set[r] + b ----------
// T_set rows are PRE-SCALED by dis_set[r] and stored fp8 e4m3: 128B/row = 2 lines
// per edge (vs 4 at bf16) -> halves beyond-L2 line traffic at the MSHR wall.
// Half-wave h consumes edges 8b+4h..8b+4h+3 (one contiguous uint4 record load);
// lane covers 4 features (4B gather). 2-stage pipeline, padded CSR (pad row = n).
__global__ __launch_bounds__(256) void conv_kernel(
    const int* __restrict__ off1, const unsigned* __restrict__ csr1, const float* __restrict__ dis1,
    const int* __restrict__ off2, const unsigned* __restrict__ csr2, const float* __restrict__ dis2,
    const unsigned char* __restrict__ Tbase,   // [2][ntab][128] fp8
    const float* __restrict__ bias, unsigned short* __restrict__ outR,
    int n, int ntab)
{
  const int set = blockIdx.y;
  const int* __restrict__ off = set ? off2 : off1;
  const float* __restrict__ dis = set ? dis2 : dis1;
  const unsigned* __restrict__ csrq = set ? csr2 : csr1;
  const int col_ofs = set ? 128 : 0;
  const unsigned* __restrict__ tab =
      (const unsigned*)(Tbase + (size_t)set * ntab * 128);

  int wv = blockIdx.x*4 + (threadIdx.x >> 6);
  if (wv >= n) return;
  const int l = threadIdx.x & 63;
  const int half = l >> 5, lf = l & 31;
  const int s = off[wv], e = off[wv+1];
  const int nb = (e - s) >> 3;               // 8-edge batches (exact, padded)
  const unsigned* cp = csrq + s + half*4;    // this half's 4 records per batch

  float ax = 0.f, ay = 0.f, az = 0.f, aw = 0.f;

  if (nb > 0){
    u32x4 qa, qb;
    unsigned va0, va1, va2, va3, vb0, vb1, vb2, vb3;

#define LQ(q, B) q = __builtin_nontemporal_load((const u32x4*)(cp + (B)*8));
#define GATH(v, q) \
    v##0 = tab[(size_t)q.x * 32 + lf]; \
    v##1 = tab[(size_t)q.y * 32 + lf]; \
    v##2 = tab[(size_t)q.z * 32 + lf]; \
    v##3 = tab[(size_t)q.w * 32 + lf];
#define FMA1(v) { \
    f32x2 lo = __builtin_amdgcn_cvt_pk_f32_fp8((int)v, false); \
    f32x2 hi = __builtin_amdgcn_cvt_pk_f32_fp8((int)v, true);  \
    ax += lo.x; ay += lo.y; az += hi.x; aw += hi.y; }
#define FMAB(v) { FMA1(v##0) FMA1(v##1) FMA1(v##2) FMA1(v##3) }

    LQ(qa, 0)
    GATH(va, qa)
    LQ(qb, 1)
    int b = 0;
    while (b + 2 <= nb){
      LQ(qa, b + 2)              // speculative reads stay inside filled csr capacity
      GATH(vb, qb)
      FMAB(va)
      LQ(qb, b + 3)
      GATH(va, qa)               // may gather next node's rows / pad rows; unused unless valid
      FMAB(vb)
      b += 2;
    }
    if (b < nb) FMAB(va)
#undef LQ
#undef GATH
#undef FMA1
#undef FMAB
  }

  // combine the two half-wave partial sums
  ax += __shfl_xor(ax, 32, 64);
  ay += __shfl_xor(ay, 32, 64);
  az += __shfl_xor(az, 32, 64);
  aw += __shfl_xor(aw, 32, 64);

  if (half == 0){
    const float dc = dis[wv];
    float b0 = bias[lf*4 + 0], b1 = bias[lf*4 + 1];
    float b2 = bias[lf*4 + 2], b3 = bias[lf*4 + 3];
    ull ov = (ull)((unsigned)f2bf(fmaf(dc, ax, b0)) | ((unsigned)f2bf(fmaf(dc, ay, b1)) << 16))
           | ((ull)((unsigned)f2bf(fmaf(dc, az, b2)) | ((unsigned)f2bf(fmaf(dc, aw, b3)) << 16)) << 32);
    __builtin_nontemporal_store(ov, (ull*)&outR[(size_t)wv*256 + col_ofs + lf*4]);
  }
}

// ---------- bf16 MFMA GEMM, m97-style 2-barrier loop ----------
// A [M x K] bf16 row-major (lda); AF32: A is f32, converted to bf16 during
// reg-staging (fuses the former cvt_x pass into GEMM1 -> -102MB traffic).
// Bt = B^T stored [BN_total x K] bf16.
// EPI 1: +bias, relu, bf16 store;
// EPI 2: A = 3 slabs (h|R1|R2, lda=256 each), +bias, fused log_softmax, f32 store;
// EPI 4: dual fp8 table store T[set][row][col] = fp8(vv * dis_set[row]).
template<int FM, int FN, int WGM, int WGN, int EPI, bool AF32>
__global__ __launch_bounds__(256, 2) void gemm_kernel(
    const unsigned short* __restrict__ A0, const float* __restrict__ Af,
    const unsigned short* __restrict__ A1, const unsigned short* __restrict__ A2,
    const unsigned short* __restrict__ Bt, const float* __restrict__ bias,
    void* __restrict__ Cout, int M, int K, int lda, int ldc,
    const float* __restrict__ d1, const float* __restrict__ d2, int ntab)
{
  constexpr int BM = WGM*FM*16;
  constexpr int BN = WGN*FN*16;
  constexpr int BK = 32;
  static_assert(BM == 128, "staging assumes BM==128");
  __shared__ unsigned short As[BM][BK];
  __shared__ unsigned short Bs[BN][BK];
  const int tid = threadIdx.x;
  const int w = tid >> 6, l = tid & 63;
  const int wr = w / WGN, wc = w % WGN;
  const int m0 = blockIdx.x*BM, n0 = blockIdx.y*BN;
  f32x4 acc[FM][FN] = {};
  const int nsteps = K / BK;
  for (int s = 0; s < nsteps; ++s){
    const int k0 = s*BK;
    const unsigned short* Asrc = A0;
    int kin = k0;
    if constexpr (EPI == 2){
      int slab = k0 >> 8;
      Asrc = (slab == 0) ? A0 : ((slab == 1) ? A1 : A2);
      kin = k0 & 255;
    }
    __syncthreads();
    if constexpr (AF32){
      #pragma unroll
      for (int j = 0; j < 2; ++j){         // A: load f32, cvt, store 16B to LDS
        int idx = j*256 + tid;
        int row = idx >> 2, kq = idx & 3;
        int rg = m0 + row; rg = (rg < M) ? rg : (M - 1);
        const float* src = Af + (size_t)rg*lda + kin + kq*8;
        float4 a = *(const float4*)src;
        float4 b2 = *(const float4*)(src + 4);
        ushort8v u;
        u[0] = f2bf(a.x);  u[1] = f2bf(a.y);  u[2] = f2bf(a.z);  u[3] = f2bf(a.w);
        u[4] = f2bf(b2.x); u[5] = f2bf(b2.y); u[6] = f2bf(b2.z); u[7] = f2bf(b2.w);
        *(ushort8v*)((char*)&As[0][0] + (size_t)idx*16) = u;
      }
    } else {
      #pragma unroll
      for (int j = 0; j < 2; ++j){         // A: 8KB = 2 x 4KB issues
        int idx = j*256 + tid;
        int row = idx >> 2, kq = idx & 3;
        int rg = m0 + row; rg = (rg < M) ? rg : (M - 1);
        load_lds16(Asrc + (size_t)rg*lda + kin + kq*8,
                   ((char*)&As[0][0]) + (size_t)(j*256 + w*64)*16);
      }
    }
    #pragma unroll
    for (int j = 0; j < BN/64; ++j){       // Bt: [n][k] layout, same pattern as A
      int idx = j*256 + tid;
      int row = idx >> 2, kq = idx & 3;
      load_lds16(Bt + (size_t)(n0 + row)*K + k0 + kq*8,
                 ((char*)&Bs[0][0]) + (size_t)(j*256 + w*64)*16);
    }
    __syncthreads();
    bf16x8 af[FM], bfr[FN];
    const int kofs = (l >> 4)*8, l16 = l & 15;
    #pragma unroll
    for (int mi = 0; mi < FM; ++mi)
      af[mi] = *(const bf16x8*)&As[wr*FM*16 + mi*16 + l16][kofs];
    #pragma unroll
    for (int ni = 0; ni < FN; ++ni)
      bfr[ni] = *(const bf16x8*)&Bs[wc*FN*16 + ni*16 + l16][kofs];
    #pragma unroll
    for (int mi = 0; mi < FM; ++mi)
      #pragma unroll
      for (int ni = 0; ni < FN; ++ni)
        acc[mi][ni] = __builtin_amdgcn_mfma_f32_16x16x32_bf16(af[mi], bfr[ni], acc[mi][ni], 0, 0, 0);
  }
  const int lg = l >> 4, lc = l & 15;
  if constexpr (EPI == 2){
    float* O = (float*)Cout;
    #pragma unroll
    for (int mi = 0; mi < FM; ++mi){
      #pragma unroll
      for (int i = 0; i < 4; ++i){
        int row = m0 + wr*FM*16 + mi*16 + lg*4 + i;
        float v[FN];
        float mx = -1e30f;
        #pragma unroll
        for (int ni = 0; ni < FN; ++ni){
          int col = ni*16 + lc;                       // WGN==1, n0==0
          v[ni] = acc[mi][ni][i] + ((col < 40) ? bias[col] : 0.f);
          if (col < 40) mx = fmaxf(mx, v[ni]);
        }
        #pragma unroll
        for (int d = 1; d < 16; d <<= 1) mx = fmaxf(mx, __shfl_xor(mx, d, 64));
        float se = 0.f;
        #pragma unroll
        for (int ni = 0; ni < FN; ++ni){
          int col = ni*16 + lc;
          if (col < 40) se += expf(v[ni] - mx);
        }
        #pragma unroll
        for (int d = 1; d < 16; d <<= 1) se += __shfl_xor(se, d, 64);
        float lse = logf(se);
        if (row < M){
          #pragma unroll
          for (int ni = 0; ni < FN; ++ni){
            int col = ni*16 + lc;
            if (col < 40) O[(size_t)row*40 + col] = v[ni] - mx - lse;
          }
        }
      }
    }
  } else if constexpr (EPI == 4){
    unsigned char* T = (unsigned char*)Cout;            // [2][ntab][128]
    #pragma unroll
    for (int mi = 0; mi < FM; ++mi){
      #pragma unroll
      for (int i = 0; i < 4; ++i){
        int row = m0 + wr*FM*16 + mi*16 + lg*4 + i;
        if (row >= M) continue;
        float s1 = d1[row], s2 = d2[row];
        #pragma unroll
        for (int ni = 0; ni < FN; ++ni){
          int col = n0 + wc*FN*16 + ni*16 + lc;        // [0,128)
          float vv = acc[mi][ni][i];
          unsigned p1 = (unsigned)__builtin_amdgcn_cvt_pk_fp8_f32(vv*s1, vv*s1, 0, false);
          unsigned p2 = (unsigned)__builtin_amdgcn_cvt_pk_fp8_f32(vv*s2, vv*s2, 0, false);
          T[(size_t)row*128 + col] = (unsigned char)(p1 & 0xff);
          T[((size_t)ntab + row)*128 + col] = (unsigned char)(p2 & 0xff);
        }
      }
    }
  } else {
    unsigned short* C = (unsigned short*)Cout;
    #pragma unroll
    for (int mi = 0; mi < FM; ++mi){
      #pragma unroll
      for (int i = 0; i < 4; ++i){
        int row = m0 + wr*FM*16 + mi*16 + lg*4 + i;
        if (row >= M) continue;
        #pragma unroll
        for (int ni = 0; ni < FN; ++ni){
          int col = n0 + wc*FN*16 + ni*16 + lc;
          float vv = acc[mi][ni][i];
          if constexpr (EPI == 1){ vv += bias[col]; vv = fmaxf(vv, 0.f); }
          C[(size_t)row*ldc + col] = f2bf(vv);
        }
      }
    }
  }
}

extern "C" void kernel_launch(void* const* d_in, const int* in_sizes, int n_in,
                              void* d_out, int out_size, void* d_ws, size_t ws_size,
                              hipStream_t stream)
{
  (void)n_in; (void)out_size;
  const float* x      = (const float*)d_in[0];
  const int*   ei1    = (const int*)d_in[1];
  const int*   ei2    = (const int*)d_in[2];
  const float* W_lin1 = (const float*)d_in[3];
  const float* b_lin1 = (const float*)d_in[4];
  const float* W_c1   = (const float*)d_in[5];
  const float* b_c1   = (const float*)d_in[6];
  const float* W_c2   = (const float*)d_in[7];
  const float* b_c2   = (const float*)d_in[8];
  const float* W_lin2 = (const float*)d_in[9];
  const float* b_lin2 = (const float*)d_in[10];

  const int N  = in_sizes[0] / 512;
  const int E1 = in_sizes[1] / 2;
  const int E2 = in_sizes[2] / 2;
  const int ntab = N + 1;                    // +1 zero row for pad edges
  const int NB = (N + 127) >> 7;             // destination buckets of 128 nodes
  // fixed per-bucket staging capacities (uniform edges: mean + >17 sigma)
  const int cap1r = (((E1 + NB - 1)/NB + 768) + 63) & ~63;
  const int cap2r = (((E2 + NB - 1)/NB + 1536) + 63) & ~63;

  char* base = (char*)d_ws;
  size_t off = 0;
  auto alloc = [&](size_t bytes) -> char* {
    off = (off + 255) & ~(size_t)255;
    char* r = base + off;
    off += bytes;
    return r;
  };
  // padded-CSR capacities in 4B records (pad <= 7 per node, + speculative slack)
  const size_t cap1 = (size_t)E1 + 8*(size_t)N + 64;
  const size_t cap2 = (size_t)E2 + 8*(size_t)N + 64;

  unsigned short* h    = (unsigned short*)alloc((size_t)N*256*2);
  unsigned char*  T    = (unsigned char*)alloc((size_t)2*ntab*128); // fp8 scaled tables
  unsigned short* R1   = (unsigned short*)alloc((size_t)N*256*2);
  unsigned short* R2   = (unsigned short*)alloc((size_t)N*256*2);
  unsigned short* Wt1  = (unsigned short*)alloc((size_t)256*512*2);
  unsigned short* Wtc1 = (unsigned short*)alloc((size_t)128*256*2);
  unsigned short* Wtc2 = (unsigned short*)alloc((size_t)128*256*2);
  unsigned short* Wtf  = (unsigned short*)alloc((size_t)64*768*2); // W_lin2^T padded to 64 cols
  int* degblk = (int*)alloc((size_t)2*N*4);
  int* deg1 = degblk, *deg2 = degblk + N;
  float* dis1 = (float*)alloc((size_t)N*4);
  float* dis2 = (float*)alloc((size_t)N*4);
  int* off1 = (int*)alloc((size_t)(N+1)*4);
  int* off2 = (int*)alloc((size_t)(N+1)*4);
  int* bsum  = (int*)alloc(128*4);
  int* bbase = (int*)alloc(128*4);
  int* bcur  = (int*)alloc((size_t)2*NB*4);
  unsigned* csr1 = (unsigned*)alloc(cap1*4);
  unsigned* csr2 = (unsigned*)alloc(cap2*4);
  unsigned* staging = (unsigned*)alloc((size_t)NB*((size_t)cap1r + cap2r)*4);
  if (off > ws_size) return;   // workspace insufficient -> visible validation failure

  int mt = (N + 127)/128;
  int cb = (N + 3)/4;

  // --- dense front: weight transposes + GEMM1 (reads x f32 directly, fused cvt) ---
  wtrans4_kernel<<<960, 256, 0, stream>>>(W_lin1, Wt1, W_c1, Wtc1, W_c2, Wtc2, W_lin2, Wtf);
  gemm_kernel<4,4,2,2,1,true><<<dim3(mt, 2), 256, 0, stream>>>(
      nullptr, x, nullptr, nullptr, Wt1, b_lin1, h, N, 512, 512, 256, nullptr, nullptr, 0);

  // --- graph preprocessing (bucketed, fixed-capacity staging) ---
  binit_kernel<<<(2*NB + 64 + 255)/256, 256, 0, stream>>>(
      bcur, NB, cap1r, cap2r,
      (unsigned*)(T + (size_t)N*128), (unsigned*)(T + ((size_t)ntab + N)*128));
  partA_kernel<<<dim3((E2 + PCH - 1)/PCH, 2), 256, 0, stream>>>(ei1, E1, ei2, E2, bcur, staging, NB);
  degB_kernel<<<dim3(NB, 2), 256, 0, stream>>>(staging, bcur, deg1, deg2, dis1, dis2,
                                               NB, N, cap1r, cap2r);
  int nch = (N + 1023)/1024;
  scan1_kernel<<<dim3(nch, 2), 1024, 0, stream>>>(deg1, deg2, off1, off2, bsum, N);
  scan2_kernel<<<1, 64, 0, stream>>>(bsum, bbase, nch, off1, off2, N);
  scan3_kernel<<<dim3(nch, 2), 1024, 0, stream>>>(deg1, deg2, off1, off2, bbase, N);
  partB_kernel<<<dim3(NB, 2), 256, 0, stream>>>(staging, bcur, off1, off2, csr1, csr2,
                                                NB, N, (unsigned)N, cap1r, cap2r);

  // --- layer 1: T = fp8(dis_set[r] * (h @ W_c1)[r]), then one conv pass ---
  gemm_kernel<4,4,2,2,4,false><<<dim3(mt, 1), 256, 0, stream>>>(
      h, nullptr, nullptr, nullptr, Wtc1, nullptr, T, N, 256, 256, 0, dis1, dis2, ntab);
  conv_kernel<<<dim3(cb, 2), 256, 0, stream>>>(off1, csr1, dis1, off2, csr2, dis2,
                                               T, b_c1, R1, N, ntab);
  // --- layer 2: T = fp8(dis_set[r] * (R1 @ W_c2)[r]), conv ---
  gemm_kernel<4,4,2,2,4,false><<<dim3(mt, 1), 256, 0, stream>>>(
      R1, nullptr, nullptr, nullptr, Wtc2, nullptr, T, N, 256, 256, 0, dis1, dis2, ntab);
  conv_kernel<<<dim3(cb, 2), 256, 0, stream>>>(off1, csr1, dis1, off2, csr2, dis2,
                                               T, b_c2, R2, N, ntab);
  // --- head: logits = [h|R1|R2] @ W_lin2 + b, fused log_softmax ---
  gemm_kernel<2,4,4,1,2,false><<<dim3(mt, 1), 256, 0, stream>>>(
      h, nullptr, R1, R2, Wtf, b_lin2, d_out, N, 768, 256, 40, nullptr, nullptr, 0);
}

// Round 12
// 261.926 us; speedup vs baseline: 3.7783x; 1.0526x over previous
//
#include <hip/hip_runtime.h>
#include <hip/hip_bf16.h>
#include <stdint.h>

typedef __attribute__((ext_vector_type(8))) short bf16x8;
typedef __attribute__((ext_vector_type(8))) unsigned short ushort8v;
typedef __attribute__((ext_vector_type(4))) float f32x4;
typedef __attribute__((ext_vector_type(2))) float f32x2;
typedef __attribute__((ext_vector_type(4))) unsigned int u32x4;
typedef unsigned long long ull;

__device__ __forceinline__ void load_lds16(const void* g, void* l){
  __builtin_amdgcn_global_load_lds((const __attribute__((address_space(1))) void*)g,
                                   (__attribute__((address_space(3))) void*)l, 16, 0, 0);
}

__device__ __forceinline__ float bf2f(unsigned int u){
  union { unsigned int i; float f; } x; x.i = u << 16; return x.f;
}
__device__ __forceinline__ unsigned short f2bf(float f){
  __hip_bfloat16 h = __float2bfloat16(f);
  unsigned short u;
  __builtin_memcpy(&u, &h, 2);
  return u;
}

// ---------- fused weight transposes + bucket-cursor init (one dispatch) ----------
__global__ void wtrans4_kernel(const float* __restrict__ W1, unsigned short* __restrict__ Wt1,
                               const float* __restrict__ Wc1, unsigned short* __restrict__ Wtc1,
                               const float* __restrict__ Wc2, unsigned short* __restrict__ Wtc2,
                               const float* __restrict__ Wf, unsigned short* __restrict__ Wtf,
                               int NB, int cap1r, int cap2r, int* __restrict__ bcur,
                               unsigned* __restrict__ Tz0, unsigned* __restrict__ Tz1){
  int idx = blockIdx.x*256 + threadIdx.x;
  if (idx >= 245760){                       // binit tail
    int i = idx - 245760;
    if (i < NB) bcur[i] = i*cap1r;
    else if (i < 2*NB) bcur[i] = NB*cap1r + (i - NB)*cap2r;
    else if (i < 2*NB + 32) Tz0[i - 2*NB] = 0u;
    else if (i < 2*NB + 64) Tz1[i - 2*NB - 32] = 0u;
    return;
  }
  const float* W; unsigned short* Wt; int K, N;
  if (idx < 131072){ W = W1; Wt = Wt1; K = 512; N = 256; }
  else if (idx < 163840){ idx -= 131072; W = Wc1; Wt = Wtc1; K = 256; N = 128; }
  else if (idx < 196608){ idx -= 163840; W = Wc2; Wt = Wtc2; K = 256; N = 128; }
  else { idx -= 196608; W = Wf; Wt = Wtf; K = 768; N = 40; }
  int nn = idx / K, kk = idx - nn*K;
  float v = (nn < N) ? W[(size_t)kk*N + nn] : 0.f;
  Wt[idx] = f2bf(v);
}

// ---------- graph preprocessing (bucketed, atomic-light, fixed-capacity) ----------
// Buckets of 128 destination nodes, fixed staging capacity per bucket
// (mean + >17 sigma for uniform-random edges -> overflow prob ~1e-50).
// partA partitions edges into staging; its cursors' final values double as
// per-bucket end markers for degB/partB. Each thread owns 16 contiguous
// edges, rows+cols vector-loaded up front (8 int4s in flight).

#define PCH 4096

// Pass A: partition PCH-edge chunks into bucket staging
__global__ __launch_bounds__(256) void partA_kernel(
    const int* __restrict__ ei1, int E1, const int* __restrict__ ei2, int E2,
    int* __restrict__ bcur, unsigned* __restrict__ staging, int NB)
{
  const int set = blockIdx.y;
  const int* __restrict__ ei = set ? ei2 : ei1;
  const int E = set ? E2 : E1;
  int* __restrict__ cur = bcur + set*NB;
  __shared__ int hist[400];
  __shared__ int resv[400];
  const int tid = threadIdx.x;
  const int base = blockIdx.x * PCH;
  if (base >= E) return;
  for (int b = tid; b < NB; b += 256) hist[b] = 0;
  __syncthreads();

  if (base + PCH <= E){
    // fast path: 16 edges/thread, rows+cols vector-loaded up front (8x int4 in flight)
    const int t0 = base + tid*16;
    int4 c[4], r[4];
    #pragma unroll
    for (int j = 0; j < 4; ++j) c[j] = *(const int4*)(ei + E + t0 + j*4);
    #pragma unroll
    for (int j = 0; j < 4; ++j) r[j] = *(const int4*)(ei + t0 + j*4);
    #pragma unroll
    for (int j = 0; j < 4; ++j){
      atomicAdd(&hist[c[j].x >> 7], 1); atomicAdd(&hist[c[j].y >> 7], 1);
      atomicAdd(&hist[c[j].z >> 7], 1); atomicAdd(&hist[c[j].w >> 7], 1);
    }
    __syncthreads();
    for (int b = tid; b < NB; b += 256){
      int hc = hist[b];
      resv[b] = hc ? atomicAdd(&cur[b], hc) : 0;
      hist[b] = 0;                      // reuse as local cursor
    }
    __syncthreads();
    #pragma unroll
    for (int j = 0; j < 4; ++j){
      int cc, rr, b, s;
      cc = c[j].x; rr = r[j].x; b = cc >> 7;
      s = resv[b] + atomicAdd(&hist[b], 1);
      staging[s] = ((unsigned)rr << 7) | (unsigned)(cc & 127);
      cc = c[j].y; rr = r[j].y; b = cc >> 7;
      s = resv[b] + atomicAdd(&hist[b], 1);
      staging[s] = ((unsigned)rr << 7) | (unsigned)(cc & 127);
      cc = c[j].z; rr = r[j].z; b = cc >> 7;
      s = resv[b] + atomicAdd(&hist[b], 1);
      staging[s] = ((unsigned)rr << 7) | (unsigned)(cc & 127);
      cc = c[j].w; rr = r[j].w; b = cc >> 7;
      s = resv[b] + atomicAdd(&hist[b], 1);
      staging[s] = ((unsigned)rr << 7) | (unsigned)(cc & 127);
    }
  } else {
    // tail path: guarded scalar
    for (int i = 0; i < PCH/256; ++i){
      int e = base + i*256 + tid;
      if (e < E) atomicAdd(&hist[ei[E + e] >> 7], 1);
    }
    __syncthreads();
    for (int b = tid; b < NB; b += 256){
      int hc = hist[b];
      resv[b] = hc ? atomicAdd(&cur[b], hc) : 0;
      hist[b] = 0;
    }
    __syncthreads();
    for (int i = 0; i < PCH/256; ++i){
      int e = base + i*256 + tid;
      if (e < E){
        int c = ei[E + e], r = ei[e];
        int b = c >> 7;
        int s = resv[b] + atomicAdd(&hist[b], 1);
        staging[s] = ((unsigned)r << 7) | (unsigned)(c & 127);
      }
    }
  }
}

// per-node degrees + dis from staging: LDS counters, contiguous global writes
__global__ __launch_bounds__(256) void degB_kernel(
    const unsigned* __restrict__ staging, const int* __restrict__ bcur,
    int* __restrict__ deg1, int* __restrict__ deg2,
    float* __restrict__ dis1, float* __restrict__ dis2,
    int NB, int n, int cap1r, int cap2r)
{
  const int set = blockIdx.y;
  int* __restrict__ deg = set ? deg2 : deg1;
  float* __restrict__ dis = set ? dis2 : dis1;
  const int b = blockIdx.x;
  const int nodebase = b << 7;
  const int nn = min(128, n - nodebase);
  if (nn <= 0) return;
  __shared__ int cnt[128];
  const int tid = threadIdx.x;
  if (tid < 128) cnt[tid] = 0;
  __syncthreads();
  const int s0 = set ? (NB*cap1r + b*cap2r) : (b*cap1r);
  const int s1 = bcur[set*NB + b];
  for (int i = s0 + tid; i < s1; i += 256)
    atomicAdd(&cnt[staging[i] & 127], 1);
  __syncthreads();
  if (tid < nn){
    int c = cnt[tid];
    deg[nodebase + tid] = c;
    dis[nodebase + tid] = (c > 0) ? (1.0f/sqrtf((float)c)) : 0.f;
  }
}

// scans run on PADDED degrees: pdeg = (deg+7)&~7  (8-edge multiples per node)
__global__ void scan1_kernel(const int* __restrict__ deg1, const int* __restrict__ deg2,
                             int* __restrict__ off1, int* __restrict__ off2,
                             int* __restrict__ bsum, int n){
  __shared__ int s[1024];
  int set = blockIdx.y;
  const int* deg = set ? deg2 : deg1;
  int* off = set ? off2 : off1;
  int tid = threadIdx.x;
  int i = blockIdx.x*1024 + tid;
  int v = (i < n) ? ((deg[i] + 7) & ~7) : 0;
  s[tid] = v;
  __syncthreads();
  for (int o = 1; o < 1024; o <<= 1){
    int t = (tid >= o) ? s[tid - o] : 0;
    __syncthreads();
    s[tid] += t;
    __syncthreads();
  }
  if (i < n) off[i] = s[tid];          // inclusive, chunk-local (fixed in pass 3)
  if (tid == 1023) bsum[set*64 + blockIdx.x] = s[1023];
}

__global__ void scan2_kernel(const int* __restrict__ bsum, int* __restrict__ bbase,
                             int nch, int* __restrict__ off1, int* __restrict__ off2, int n){
  int set = threadIdx.x;
  if (set < 2){
    int run = 0;
    for (int j = 0; j < nch; ++j){ bbase[set*64 + j] = run; run += bsum[set*64 + j]; }
    (set ? off2 : off1)[n] = run;      // total padded edge count
  }
}

__global__ void scan3_kernel(const int* __restrict__ deg1, const int* __restrict__ deg2,
                             int* __restrict__ off1, int* __restrict__ off2,
                             const int* __restrict__ bbase, int n){
  int set = blockIdx.y;
  const int* deg = set ? deg2 : deg1;
  int* off = set ? off2 : off1;
  int i = blockIdx.x*1024 + threadIdx.x;
  if (i < n){
    int e = off[i] + bbase[set*64 + blockIdx.x];
    off[i] = e - ((deg[i] + 7) & ~7);  // exclusive global padded prefix
  }
}

// Pass B: per-bucket local scatter + padding (pad record = padrow);
// block 0 of each set also fills the speculative-prefetch slack past off[n]
__global__ __launch_bounds__(256) void partB_kernel(
    const unsigned* __restrict__ staging, const int* __restrict__ bcur,
    const int* __restrict__ off1, const int* __restrict__ off2,
    unsigned* __restrict__ csr1, unsigned* __restrict__ csr2,
    int NB, int n, unsigned padrow, int cap1r, int cap2r)
{
  const int set = blockIdx.y;
  const int* __restrict__ off = set ? off2 : off1;
  unsigned* __restrict__ csr = set ? csr2 : csr1;
  const int b = blockIdx.x;
  const int nodebase = b << 7;
  const int nn = min(128, n - nodebase);
  if (nn <= 0) return;
  __shared__ int offv[129];
  __shared__ int curl[128];
  const int tid = threadIdx.x;
  if (tid <= nn) offv[tid] = off[nodebase + tid];
  if (tid < 128) curl[tid] = 0;
  __syncthreads();
  const int s0 = set ? (NB*cap1r + b*cap2r) : (b*cap1r);
  const int s1 = bcur[set*NB + b];
  for (int i = s0 + tid; i < s1; i += 256){
    unsigned v = staging[i];
    int cl = v & 127;
    int p = offv[cl] + atomicAdd(&curl[cl], 1);
    csr[p] = v >> 7;
  }
  __syncthreads();
  for (int c = tid; c < nn; c += 256){
    int p1 = offv[c+1];
    for (int p = offv[c] + curl[c]; p < p1; ++p) csr[p] = padrow;
  }
  if (b == 0 && tid < 64) csr[off[n] + tid] = padrow;   // slack fill
}

// ---------- GCN aggregation: out[c] = dis[c] * sum_e T_set[r] + b ----------
// T_set rows are PRE-SCALED by dis_set[r] and stored fp8 e4m3: 128B/row = 2 lines
// per edge (vs 4 at bf16) -> halves beyond-L2 line traffic at the MSHR wall.
// Half-wave h consumes edges 8b+4h..8b+4h+3 (one contiguous uint4 record load);
// lane covers 4 features (4B gather). 2-stage pipeline, padded CSR (pad row = n).
__global__ __launch_bounds__(256) void conv_kernel(
    const int* __restrict__ off1, const unsigned* __restrict__ csr1, const float* __restrict__ dis1,
    const int* __restrict__ off2, const unsigned* __restrict__ csr2, const float* __restrict__ dis2,
    const unsigned char* __restrict__ Tbase,   // [2][ntab][128] fp8
    const float* __restrict__ bias, unsigned short* __restrict__ outR,
    int n, int ntab)
{
  const int set = blockIdx.y;
  const int* __restrict__ off = set ? off2 : off1;
  const float* __restrict__ dis = set ? dis2 : dis1;
  const unsigned* __restrict__ csrq = set ? csr2 : csr1;
  const int col_ofs = set ? 128 : 0;
  const unsigned* __restrict__ tab =
      (const unsigned*)(Tbase + (size_t)set * ntab * 128);

  int wv = blockIdx.x*4 + (threadIdx.x >> 6);
  if (wv >= n) return;
  const int l = threadIdx.x & 63;
  const int half = l >> 5, lf = l & 31;
  const int s = off[wv], e = off[wv+1];
  const int nb = (e - s) >> 3;               // 8-edge batches (exact, padded)
  const unsigned* cp = csrq + s + half*4;    // this half's 4 records per batch

  float ax = 0.f, ay = 0.f, az = 0.f, aw = 0.f;

  if (nb > 0){
    u32x4 qa, qb;
    unsigned va0, va1, va2, va3, vb0, vb1, vb2, vb3;

#define LQ(q, B) q = __builtin_nontemporal_load((const u32x4*)(cp + (B)*8));
#define GATH(v, q) \
    v##0 = tab[(size_t)q.x * 32 + lf]; \
    v##1 = tab[(size_t)q.y * 32 + lf]; \
    v##2 = tab[(size_t)q.z * 32 + lf]; \
    v##3 = tab[(size_t)q.w * 32 + lf];
#define FMA1(v) { \
    f32x2 lo = __builtin_amdgcn_cvt_pk_f32_fp8((int)v, false); \
    f32x2 hi = __builtin_amdgcn_cvt_pk_f32_fp8((int)v, true);  \
    ax += lo.x; ay += lo.y; az += hi.x; aw += hi.y; }
#define FMAB(v) { FMA1(v##0) FMA1(v##1) FMA1(v##2) FMA1(v##3) }

    LQ(qa, 0)
    GATH(va, qa)
    LQ(qb, 1)
    int b = 0;
    while (b + 2 <= nb){
      LQ(qa, b + 2)              // speculative reads stay inside filled csr capacity
      GATH(vb, qb)
      FMAB(va)
      LQ(qb, b + 3)
      GATH(va, qa)               // may gather next node's rows / pad rows; unused unless valid
      FMAB(vb)
      b += 2;
    }
    if (b < nb) FMAB(va)
#undef LQ
#undef GATH
#undef FMA1
#undef FMAB
  }

  // combine the two half-wave partial sums
  ax += __shfl_xor(ax, 32, 64);
  ay += __shfl_xor(ay, 32, 64);
  az += __shfl_xor(az, 32, 64);
  aw += __shfl_xor(aw, 32, 64);

  if (half == 0){
    const float dc = dis[wv];
    float b0 = bias[lf*4 + 0], b1 = bias[lf*4 + 1];
    float b2 = bias[lf*4 + 2], b3 = bias[lf*4 + 3];
    ull ov = (ull)((unsigned)f2bf(fmaf(dc, ax, b0)) | ((unsigned)f2bf(fmaf(dc, ay, b1)) << 16))
           | ((ull)((unsigned)f2bf(fmaf(dc, az, b2)) | ((unsigned)f2bf(fmaf(dc, aw, b3)) << 16)) << 32);
    __builtin_nontemporal_store(ov, (ull*)&outR[(size_t)wv*256 + col_ofs + lf*4]);
  }
}

// ---------- bf16 MFMA GEMM, m97-style 2-barrier loop ----------
// Thread count = WGM*WGN*64 (256 for most instances; 512 for BN=256 GEMM1).
// A [M x K] bf16 row-major (lda); AF32: A is f32, converted to bf16 during
// reg-staging (fuses the cvt pass; BN=256 single-pass reads x ONCE).
// Bt = B^T stored [BN_total x K] bf16.
// EPI 1: +bias, relu, bf16 store;
// EPI 2: A = 3 slabs (h|R1|R2, lda=256 each), +bias, fused log_softmax, f32 store;
// EPI 4: dual fp8 table store T[set][row][col] = fp8(vv * dis_set[row]).
template<int FM, int FN, int WGM, int WGN, int EPI, bool AF32>
__global__ __launch_bounds__(WGM*WGN*64, (WGM*WGN*64) == 512 ? 4 : 2) void gemm_kernel(
    const unsigned short* __restrict__ A0, const float* __restrict__ Af,
    const unsigned short* __restrict__ A1, const unsigned short* __restrict__ A2,
    const unsigned short* __restrict__ Bt, const float* __restrict__ bias,
    void* __restrict__ Cout, int M, int K, int lda, int ldc,
    const float* __restrict__ d1, const float* __restrict__ d2, int ntab)
{
  constexpr int THREADS = WGM*WGN*64;
  constexpr int BM = WGM*FM*16;
  constexpr int BN = WGN*FN*16;
  constexpr int BK = 32;
  constexpr int AJ = (BM*BK/8)/THREADS;   // 16B chunks per thread for A
  constexpr int BJ = (BN*BK/8)/THREADS;   // 16B chunks per thread for B
  static_assert(BM == 128, "staging assumes BM==128");
  __shared__ unsigned short As[BM][BK];
  __shared__ unsigned short Bs[BN][BK];
  const int tid = threadIdx.x;
  const int w = tid >> 6, l = tid & 63;
  const int wr = w / WGN, wc = w % WGN;
  const int m0 = blockIdx.x*BM, n0 = blockIdx.y*BN;
  f32x4 acc[FM][FN] = {};
  const int nsteps = K / BK;
  for (int s = 0; s < nsteps; ++s){
    const int k0 = s*BK;
    const unsigned short* Asrc = A0;
    int kin = k0;
    if constexpr (EPI == 2){
      int slab = k0 >> 8;
      Asrc = (slab == 0) ? A0 : ((slab == 1) ? A1 : A2);
      kin = k0 & 255;
    }
    __syncthreads();
    if constexpr (AF32){
      #pragma unroll
      for (int j = 0; j < AJ; ++j){        // A: load f32, cvt, store 16B to LDS
        int idx = j*THREADS + tid;
        int row = idx >> 2, kq = idx & 3;
        int rg = m0 + row; rg = (rg < M) ? rg : (M - 1);
        const float* src = Af + (size_t)rg*lda + kin + kq*8;
        float4 a = *(const float4*)src;
        float4 b2 = *(const float4*)(src + 4);
        ushort8v u;
        u[0] = f2bf(a.x);  u[1] = f2bf(a.y);  u[2] = f2bf(a.z);  u[3] = f2bf(a.w);
        u[4] = f2bf(b2.x); u[5] = f2bf(b2.y); u[6] = f2bf(b2.z); u[7] = f2bf(b2.w);
        *(ushort8v*)((char*)&As[0][0] + (size_t)idx*16) = u;
      }
    } else {
      #pragma unroll
      for (int j = 0; j < AJ; ++j){        // A: async 16B global->LDS
        int idx = j*THREADS + tid;
        int row = idx >> 2, kq = idx & 3;
        int rg = m0 + row; rg = (rg < M) ? rg : (M - 1);
        load_lds16(Asrc + (size_t)rg*lda + kin + kq*8,
                   ((char*)&As[0][0]) + (size_t)(j*THREADS + w*64)*16);
      }
    }
    #pragma unroll
    for (int j = 0; j < BJ; ++j){          // Bt: [n][k] layout, same pattern as A
      int idx = j*THREADS + tid;
      int row = idx >> 2, kq = idx & 3;
      load_lds16(Bt + (size_t)(n0 + row)*K + k0 + kq*8,
                 ((char*)&Bs[0][0]) + (size_t)(j*THREADS + w*64)*16);
    }
    __syncthreads();
    bf16x8 af[FM], bfr[FN];
    const int kofs = (l >> 4)*8, l16 = l & 15;
    #pragma unroll
    for (int mi = 0; mi < FM; ++mi)
      af[mi] = *(const bf16x8*)&As[wr*FM*16 + mi*16 + l16][kofs];
    #pragma unroll
    for (int ni = 0; ni < FN; ++ni)
      bfr[ni] = *(const bf16x8*)&Bs[wc*FN*16 + ni*16 + l16][kofs];
    #pragma unroll
    for (int mi = 0; mi < FM; ++mi)
      #pragma unroll
      for (int ni = 0; ni < FN; ++ni)
        acc[mi][ni] = __builtin_amdgcn_mfma_f32_16x16x32_bf16(af[mi], bfr[ni], acc[mi][ni], 0, 0, 0);
  }
  const int lg = l >> 4, lc = l & 15;
  if constexpr (EPI == 2){
    float* O = (float*)Cout;
    #pragma unroll
    for (int mi = 0; mi < FM; ++mi){
      #pragma unroll
      for (int i = 0; i < 4; ++i){
        int row = m0 + wr*FM*16 + mi*16 + lg*4 + i;
        float v[FN];
        float mx = -1e30f;
        #pragma unroll
        for (int ni = 0; ni < FN; ++ni){
          int col = ni*16 + lc;                       // WGN==1, n0==0
          v[ni] = acc[mi][ni][i] + ((col < 40) ? bias[col] : 0.f);
          if (col < 40) mx = fmaxf(mx, v[ni]);
        }
        #pragma unroll
        for (int d = 1; d < 16; d <<= 1) mx = fmaxf(mx, __shfl_xor(mx, d, 64));
        float se = 0.f;
        #pragma unroll
        for (int ni = 0; ni < FN; ++ni){
          int col = ni*16 + lc;
          if (col < 40) se += expf(v[ni] - mx);
        }
        #pragma unroll
        for (int d = 1; d < 16; d <<= 1) se += __shfl_xor(se, d, 64);
        float lse = logf(se);
        if (row < M){
          #pragma unroll
          for (int ni = 0; ni < FN; ++ni){
            int col = ni*16 + lc;
            if (col < 40) O[(size_t)row*40 + col] = v[ni] - mx - lse;
          }
        }
      }
    }
  } else if constexpr (EPI == 4){
    unsigned char* T = (unsigned char*)Cout;            // [2][ntab][128]
    #pragma unroll
    for (int mi = 0; mi < FM; ++mi){
      #pragma unroll
      for (int i = 0; i < 4; ++i){
        int row = m0 + wr*FM*16 + mi*16 + lg*4 + i;
        if (row >= M) continue;
        float s1 = d1[row], s2 = d2[row];
        #pragma unroll
        for (int ni = 0; ni < FN; ++ni){
          int col = n0 + wc*FN*16 + ni*16 + lc;        // [0,128)
          float vv = acc[mi][ni][i];
          unsigned p1 = (unsigned)__builtin_amdgcn_cvt_pk_fp8_f32(vv*s1, vv*s1, 0, false);
          unsigned p2 = (unsigned)__builtin_amdgcn_cvt_pk_fp8_f32(vv*s2, vv*s2, 0, false);
          T[(size_t)row*128 + col] = (unsigned char)(p1 & 0xff);
          T[((size_t)ntab + row)*128 + col] = (unsigned char)(p2 & 0xff);
        }
      }
    }
  } else {
    unsigned short* C = (unsigned short*)Cout;
    #pragma unroll
    for (int mi = 0; mi < FM; ++mi){
      #pragma unroll
      for (int i = 0; i < 4; ++i){
        int row = m0 + wr*FM*16 + mi*16 + lg*4 + i;
        if (row >= M) continue;
        #pragma unroll
        for (int ni = 0; ni < FN; ++ni){
          int col = n0 + wc*FN*16 + ni*16 + lc;
          float vv = acc[mi][ni][i];
          if constexpr (EPI == 1){ vv += bias[col]; vv = fmaxf(vv, 0.f); }
          C[(size_t)row*ldc + col] = f2bf(vv);
        }
      }
    }
  }
}

extern "C" void kernel_launch(void* const* d_in, const int* in_sizes, int n_in,
                              void* d_out, int out_size, void* d_ws, size_t ws_size,
                              hipStream_t stream)
{
  (void)n_in; (void)out_size;
  const float* x      = (const float*)d_in[0];
  const int*   ei1    = (const int*)d_in[1];
  const int*   ei2    = (const int*)d_in[2];
  const float* W_lin1 = (const float*)d_in[3];
  const float* b_lin1 = (const float*)d_in[4];
  const float* W_c1   = (const float*)d_in[5];
  const float* b_c1   = (const float*)d_in[6];
  const float* W_c2   = (const float*)d_in[7];
  const float* b_c2   = (const float*)d_in[8];
  const float* W_lin2 = (const float*)d_in[9];
  const float* b_lin2 = (const float*)d_in[10];

  const int N  = in_sizes[0] / 512;
  const int E1 = in_sizes[1] / 2;
  const int E2 = in_sizes[2] / 2;
  const int ntab = N + 1;                    // +1 zero row for pad edges
  const int NB = (N + 127) >> 7;             // destination buckets of 128 nodes
  // fixed per-bucket staging capacities (uniform edges: mean + >17 sigma)
  const int cap1r = (((E1 + NB - 1)/NB + 768) + 63) & ~63;
  const int cap2r = (((E2 + NB - 1)/NB + 1536) + 63) & ~63;

  char* base = (char*)d_ws;
  size_t off = 0;
  auto alloc = [&](size_t bytes) -> char* {
    off = (off + 255) & ~(size_t)255;
    char* r = base + off;
    off += bytes;
    return r;
  };
  // padded-CSR capacities in 4B records (pad <= 7 per node, + speculative slack)
  const size_t cap1 = (size_t)E1 + 8*(size_t)N + 64;
  const size_t cap2 = (size_t)E2 + 8*(size_t)N + 64;

  unsigned short* h    = (unsigned short*)alloc((size_t)N*256*2);
  unsigned char*  T    = (unsigned char*)alloc((size_t)2*ntab*128); // fp8 scaled tables
  unsigned short* R1   = (unsigned short*)alloc((size_t)N*256*2);
  unsigned short* R2   = (unsigned short*)alloc((size_t)N*256*2);
  unsigned short* Wt1  = (unsigned short*)alloc((size_t)256*512*2);
  unsigned short* Wtc1 = (unsigned short*)alloc((size_t)128*256*2);
  unsigned short* Wtc2 = (unsigned short*)alloc((size_t)128*256*2);
  unsigned short* Wtf  = (unsigned short*)alloc((size_t)64*768*2); // W_lin2^T padded to 64 cols
  int* degblk = (int*)alloc((size_t)2*N*4);
  int* deg1 = degblk, *deg2 = degblk + N;
  float* dis1 = (float*)alloc((size_t)N*4);
  float* dis2 = (float*)alloc((size_t)N*4);
  int* off1 = (int*)alloc((size_t)(N+1)*4);
  int* off2 = (int*)alloc((size_t)(N+1)*4);
  int* bsum  = (int*)alloc(128*4);
  int* bbase = (int*)alloc(128*4);
  int* bcur  = (int*)alloc((size_t)2*NB*4);
  unsigned* csr1 = (unsigned*)alloc(cap1*4);
  unsigned* csr2 = (unsigned*)alloc(cap2*4);
  unsigned* staging = (unsigned*)alloc((size_t)NB*((size_t)cap1r + cap2r)*4);
  if (off > ws_size) return;   // workspace insufficient -> visible validation failure

  int mt = (N + 127)/128;
  int cb = (N + 3)/4;

  // --- fused weight transposes + bucket-cursor init ---
  wtrans4_kernel<<<(245760 + 2*NB + 64 + 255)/256, 256, 0, stream>>>(
      W_lin1, Wt1, W_c1, Wtc1, W_c2, Wtc2, W_lin2, Wtf,
      NB, cap1r, cap2r, bcur,
      (unsigned*)(T + (size_t)N*128), (unsigned*)(T + ((size_t)ntab + N)*128));
  // h = relu(x @ W_lin1 + b): BN=256 single pass, x f32 read ONCE (fused cvt)
  gemm_kernel<4,4,2,4,1,true><<<dim3(mt, 1), 512, 0, stream>>>(
      nullptr, x, nullptr, nullptr, Wt1, b_lin1, h, N, 512, 512, 256, nullptr, nullptr, 0);

  // --- graph preprocessing (bucketed, fixed-capacity staging) ---
  partA_kernel<<<dim3((E2 + PCH - 1)/PCH, 2), 256, 0, stream>>>(ei1, E1, ei2, E2, bcur, staging, NB);
  degB_kernel<<<dim3(NB, 2), 256, 0, stream>>>(staging, bcur, deg1, deg2, dis1, dis2,
                                               NB, N, cap1r, cap2r);
  int nch = (N + 1023)/1024;
  scan1_kernel<<<dim3(nch, 2), 1024, 0, stream>>>(deg1, deg2, off1, off2, bsum, N);
  scan2_kernel<<<1, 64, 0, stream>>>(bsum, bbase, nch, off1, off2, N);
  scan3_kernel<<<dim3(nch, 2), 1024, 0, stream>>>(deg1, deg2, off1, off2, bbase, N);
  partB_kernel<<<dim3(NB, 2), 256, 0, stream>>>(staging, bcur, off1, off2, csr1, csr2,
                                                NB, N, (unsigned)N, cap1r, cap2r);

  // --- layer 1: T = fp8(dis_set[r] * (h @ W_c1)[r]), then one conv pass ---
  gemm_kernel<4,4,2,2,4,false><<<dim3(mt, 1), 256, 0, stream>>>(
      h, nullptr, nullptr, nullptr, Wtc1, nullptr, T, N, 256, 256, 0, dis1, dis2, ntab);
  conv_kernel<<<dim3(cb, 2), 256, 0, stream>>>(off1, csr1, dis1, off2, csr2, dis2,
                                               T, b_c1, R1, N, ntab);
  // --- layer 2: T = fp8(dis_set[r] * (R1 @ W_c2)[r]), conv ---
  gemm_kernel<4,4,2,2,4,false><<<dim3(mt, 1), 256, 0, stream>>>(
      R1, nullptr, nullptr, nullptr, Wtc2, nullptr, T, N, 256, 256, 0, dis1, dis2, ntab);
  conv_kernel<<<dim3(cb, 2), 256, 0, stream>>>(off1, csr1, dis1, off2, csr2, dis2,
                                               T, b_c2, R2, N, ntab);
  // --- head: logits = [h|R1|R2] @ W_lin2 + b, fused log_softmax ---
  gemm_kernel<2,4,4,1,2,false><<<dim3(mt, 1), 256, 0, stream>>>(
      h, nullptr, R1, R2, Wtf, b_lin2, d_out, N, 768, 256, 40, nullptr, nullptr, 0);
}

// Round 13
// 248.180 us; speedup vs baseline: 3.9875x; 1.0554x over previous
//
#include <hip/hip_runtime.h>
#include <hip/hip_bf16.h>
#include <stdint.h>

typedef __attribute__((ext_vector_type(8))) short bf16x8;
typedef __attribute__((ext_vector_type(8))) unsigned short ushort8v;
typedef __attribute__((ext_vector_type(4))) float f32x4;
typedef __attribute__((ext_vector_type(2))) float f32x2;
typedef __attribute__((ext_vector_type(4))) unsigned int u32x4;
typedef unsigned long long ull;

__device__ __forceinline__ void load_lds16(const void* g, void* l){
  __builtin_amdgcn_global_load_lds((const __attribute__((address_space(1))) void*)g,
                                   (__attribute__((address_space(3))) void*)l, 16, 0, 0);
}

__device__ __forceinline__ float bf2f(unsigned int u){
  union { unsigned int i; float f; } x; x.i = u << 16; return x.f;
}
__device__ __forceinline__ unsigned short f2bf(float f){
  __hip_bfloat16 h = __float2bfloat16(f);
  unsigned short u;
  __builtin_memcpy(&u, &h, 2);
  return u;
}

// ---------- fused weight transposes + bucket-cursor init (one dispatch) ----------
__global__ void wtrans4_kernel(const float* __restrict__ W1, unsigned short* __restrict__ Wt1,
                               const float* __restrict__ Wc1, unsigned short* __restrict__ Wtc1,
                               const float* __restrict__ Wc2, unsigned short* __restrict__ Wtc2,
                               const float* __restrict__ Wf, unsigned short* __restrict__ Wtf,
                               int NB, int cap1r, int cap2r, int* __restrict__ bcur,
                               unsigned* __restrict__ Tz0, unsigned* __restrict__ Tz1){
  int idx = blockIdx.x*256 + threadIdx.x;
  if (idx >= 245760){                       // binit tail
    int i = idx - 245760;
    if (i < NB) bcur[i] = i*cap1r;
    else if (i < 2*NB) bcur[i] = NB*cap1r + (i - NB)*cap2r;
    else if (i < 2*NB + 32) Tz0[i - 2*NB] = 0u;
    else if (i < 2*NB + 64) Tz1[i - 2*NB - 32] = 0u;
    return;
  }
  const float* W; unsigned short* Wt; int K, N;
  if (idx < 131072){ W = W1; Wt = Wt1; K = 512; N = 256; }
  else if (idx < 163840){ idx -= 131072; W = Wc1; Wt = Wtc1; K = 256; N = 128; }
  else if (idx < 196608){ idx -= 163840; W = Wc2; Wt = Wtc2; K = 256; N = 128; }
  else { idx -= 196608; W = Wf; Wt = Wtf; K = 768; N = 40; }
  int nn = idx / K, kk = idx - nn*K;
  float v = (nn < N) ? W[(size_t)kk*N + nn] : 0.f;
  Wt[idx] = f2bf(v);
}

// ---------- graph preprocessing (bucketed, atomic-light, fixed-capacity) ----------
#define PCH 4096

// Pass A: partition PCH-edge chunks into bucket staging
__global__ __launch_bounds__(256) void partA_kernel(
    const int* __restrict__ ei1, int E1, const int* __restrict__ ei2, int E2,
    int* __restrict__ bcur, unsigned* __restrict__ staging, int NB)
{
  const int set = blockIdx.y;
  const int* __restrict__ ei = set ? ei2 : ei1;
  const int E = set ? E2 : E1;
  int* __restrict__ cur = bcur + set*NB;
  __shared__ int hist[400];
  __shared__ int resv[400];
  const int tid = threadIdx.x;
  const int base = blockIdx.x * PCH;
  if (base >= E) return;
  for (int b = tid; b < NB; b += 256) hist[b] = 0;
  __syncthreads();

  if (base + PCH <= E){
    // fast path: 16 edges/thread, rows+cols vector-loaded up front (8x int4 in flight)
    const int t0 = base + tid*16;
    int4 c[4], r[4];
    #pragma unroll
    for (int j = 0; j < 4; ++j) c[j] = *(const int4*)(ei + E + t0 + j*4);
    #pragma unroll
    for (int j = 0; j < 4; ++j) r[j] = *(const int4*)(ei + t0 + j*4);
    #pragma unroll
    for (int j = 0; j < 4; ++j){
      atomicAdd(&hist[c[j].x >> 7], 1); atomicAdd(&hist[c[j].y >> 7], 1);
      atomicAdd(&hist[c[j].z >> 7], 1); atomicAdd(&hist[c[j].w >> 7], 1);
    }
    __syncthreads();
    for (int b = tid; b < NB; b += 256){
      int hc = hist[b];
      resv[b] = hc ? atomicAdd(&cur[b], hc) : 0;
      hist[b] = 0;                      // reuse as local cursor
    }
    __syncthreads();
    #pragma unroll
    for (int j = 0; j < 4; ++j){
      int cc, rr, b, s;
      cc = c[j].x; rr = r[j].x; b = cc >> 7;
      s = resv[b] + atomicAdd(&hist[b], 1);
      staging[s] = ((unsigned)rr << 7) | (unsigned)(cc & 127);
      cc = c[j].y; rr = r[j].y; b = cc >> 7;
      s = resv[b] + atomicAdd(&hist[b], 1);
      staging[s] = ((unsigned)rr << 7) | (unsigned)(cc & 127);
      cc = c[j].z; rr = r[j].z; b = cc >> 7;
      s = resv[b] + atomicAdd(&hist[b], 1);
      staging[s] = ((unsigned)rr << 7) | (unsigned)(cc & 127);
      cc = c[j].w; rr = r[j].w; b = cc >> 7;
      s = resv[b] + atomicAdd(&hist[b], 1);
      staging[s] = ((unsigned)rr << 7) | (unsigned)(cc & 127);
    }
  } else {
    // tail path: guarded scalar
    for (int i = 0; i < PCH/256; ++i){
      int e = base + i*256 + tid;
      if (e < E) atomicAdd(&hist[ei[E + e] >> 7], 1);
    }
    __syncthreads();
    for (int b = tid; b < NB; b += 256){
      int hc = hist[b];
      resv[b] = hc ? atomicAdd(&cur[b], hc) : 0;
      hist[b] = 0;
    }
    __syncthreads();
    for (int i = 0; i < PCH/256; ++i){
      int e = base + i*256 + tid;
      if (e < E){
        int c = ei[E + e], r = ei[e];
        int b = c >> 7;
        int s = resv[b] + atomicAdd(&hist[b], 1);
        staging[s] = ((unsigned)r << 7) | (unsigned)(c & 127);
      }
    }
  }
}

// per-node degrees + dis from staging: LDS counters, contiguous global writes
__global__ __launch_bounds__(256) void degB_kernel(
    const unsigned* __restrict__ staging, const int* __restrict__ bcur,
    int* __restrict__ deg1, int* __restrict__ deg2,
    float* __restrict__ dis1, float* __restrict__ dis2,
    int NB, int n, int cap1r, int cap2r)
{
  const int set = blockIdx.y;
  int* __restrict__ deg = set ? deg2 : deg1;
  float* __restrict__ dis = set ? dis2 : dis1;
  const int b = blockIdx.x;
  const int nodebase = b << 7;
  const int nn = min(128, n - nodebase);
  if (nn <= 0) return;
  __shared__ int cnt[128];
  const int tid = threadIdx.x;
  if (tid < 128) cnt[tid] = 0;
  __syncthreads();
  const int s0 = set ? (NB*cap1r + b*cap2r) : (b*cap1r);
  const int s1 = bcur[set*NB + b];
  for (int i = s0 + tid; i < s1; i += 256)
    atomicAdd(&cnt[staging[i] & 127], 1);
  __syncthreads();
  if (tid < nn){
    int c = cnt[tid];
    deg[nodebase + tid] = c;
    dis[nodebase + tid] = (c > 0) ? (1.0f/sqrtf((float)c)) : 0.f;
  }
}

// scans run on PADDED degrees: pdeg = (deg+7)&~7  (8-edge multiples per node)
__global__ void scan1_kernel(const int* __restrict__ deg1, const int* __restrict__ deg2,
                             int* __restrict__ off1, int* __restrict__ off2,
                             int* __restrict__ bsum, int n){
  __shared__ int s[1024];
  int set = blockIdx.y;
  const int* deg = set ? deg2 : deg1;
  int* off = set ? off2 : off1;
  int tid = threadIdx.x;
  int i = blockIdx.x*1024 + tid;
  int v = (i < n) ? ((deg[i] + 7) & ~7) : 0;
  s[tid] = v;
  __syncthreads();
  for (int o = 1; o < 1024; o <<= 1){
    int t = (tid >= o) ? s[tid - o] : 0;
    __syncthreads();
    s[tid] += t;
    __syncthreads();
  }
  if (i < n) off[i] = s[tid];          // inclusive, chunk-local (fixed in pass 3)
  if (tid == 1023) bsum[set*64 + blockIdx.x] = s[1023];
}

__global__ void scan2_kernel(const int* __restrict__ bsum, int* __restrict__ bbase,
                             int nch, int* __restrict__ off1, int* __restrict__ off2, int n){
  int set = threadIdx.x;
  if (set < 2){
    int run = 0;
    for (int j = 0; j < nch; ++j){ bbase[set*64 + j] = run; run += bsum[set*64 + j]; }
    (set ? off2 : off1)[n] = run;      // total padded edge count
  }
}

__global__ void scan3_kernel(const int* __restrict__ deg1, const int* __restrict__ deg2,
                             int* __restrict__ off1, int* __restrict__ off2,
                             const int* __restrict__ bbase, int n){
  int set = blockIdx.y;
  const int* deg = set ? deg2 : deg1;
  int* off = set ? off2 : off1;
  int i = blockIdx.x*1024 + threadIdx.x;
  if (i < n){
    int e = off[i] + bbase[set*64 + blockIdx.x];
    off[i] = e - ((deg[i] + 7) & ~7);  // exclusive global padded prefix
  }
}

// Pass B: per-bucket local scatter + padding (pad record = padrow);
// block 0 of each set also fills the speculative-prefetch slack past off[n]
__global__ __launch_bounds__(256) void partB_kernel(
    const unsigned* __restrict__ staging, const int* __restrict__ bcur,
    const int* __restrict__ off1, const int* __restrict__ off2,
    unsigned* __restrict__ csr1, unsigned* __restrict__ csr2,
    int NB, int n, unsigned padrow, int cap1r, int cap2r)
{
  const int set = blockIdx.y;
  const int* __restrict__ off = set ? off2 : off1;
  unsigned* __restrict__ csr = set ? csr2 : csr1;
  const int b = blockIdx.x;
  const int nodebase = b << 7;
  const int nn = min(128, n - nodebase);
  if (nn <= 0) return;
  __shared__ int offv[129];
  __shared__ int curl[128];
  const int tid = threadIdx.x;
  if (tid <= nn) offv[tid] = off[nodebase + tid];
  if (tid < 128) curl[tid] = 0;
  __syncthreads();
  const int s0 = set ? (NB*cap1r + b*cap2r) : (b*cap1r);
  const int s1 = bcur[set*NB + b];
  for (int i = s0 + tid; i < s1; i += 256){
    unsigned v = staging[i];
    int cl = v & 127;
    int p = offv[cl] + atomicAdd(&curl[cl], 1);
    csr[p] = v >> 7;
  }
  __syncthreads();
  for (int c = tid; c < nn; c += 256){
    int p1 = offv[c+1];
    for (int p = offv[c] + curl[c]; p < p1; ++p) csr[p] = padrow;
  }
  if (b == 0 && tid < 64) csr[off[n] + tid] = padrow;   // slack fill
}

// ---------- GCN aggregation: out[c] = dis[c] * sum_e T_set[r] + b ----------
// T rows PRE-SCALED by dis_set[r], fp8 e4m3 (128B/row = 2 lines/edge).
// KN consecutive nodes per wave: padded CSR is contiguous across nodes, so
// one 2-stage pipeline streams the whole range with NO per-node restarts;
// node boundaries (register-cached offsets, shfl-indexed) emit output --
// wave-uniform, no divergence. Kills Poisson degree imbalance (sigma/sqrt(KN)).
#define KN 8
__global__ __launch_bounds__(256) void conv_kernel(
    const int* __restrict__ off1, const unsigned* __restrict__ csr1, const float* __restrict__ dis1,
    const int* __restrict__ off2, const unsigned* __restrict__ csr2, const float* __restrict__ dis2,
    const unsigned char* __restrict__ Tbase,   // [2][ntab][128] fp8
    const float* __restrict__ bias, unsigned short* __restrict__ outR,
    int n, int ntab)
{
  const int set = blockIdx.y;
  const int* __restrict__ off = set ? off2 : off1;
  const float* __restrict__ dis = set ? dis2 : dis1;
  const unsigned* __restrict__ csrq = set ? csr2 : csr1;
  const int col_ofs = set ? 128 : 0;
  const unsigned* __restrict__ tab =
      (const unsigned*)(Tbase + (size_t)set * ntab * 128);

  const int wv0 = (blockIdx.x*4 + (threadIdx.x >> 6)) * KN;
  if (wv0 >= n) return;
  const int wend = min(n, wv0 + KN);
  const int l = threadIdx.x & 63;
  const int half = l >> 5, lf = l & 31;
  const float b0 = bias[lf*4 + 0], b1 = bias[lf*4 + 1];
  const float b2 = bias[lf*4 + 2], b3 = bias[lf*4 + 3];

  // lanes 0..KN hold off[wv0 .. wend] (clamped); shfl-indexed boundary cache
  const int offs = off[wv0 + min(l, wend - wv0)];
  const int cstart = __shfl(offs, 0, 64);
  const int pend   = __shfl(offs, wend - wv0, 64);
  int node = wv0;
  int nxt  = __shfl(offs, min(1, wend - wv0), 64);

  float ax = 0.f, ay = 0.f, az = 0.f, aw = 0.f;

#define EMIT_NODE { \
    float rx = ax + __shfl_xor(ax, 32, 64); \
    float ry = ay + __shfl_xor(ay, 32, 64); \
    float rz = az + __shfl_xor(az, 32, 64); \
    float rw = aw + __shfl_xor(aw, 32, 64); \
    if (half == 0){ \
      const float dc = dis[node]; \
      ull ov = (ull)((unsigned)f2bf(fmaf(dc, rx, b0)) | ((unsigned)f2bf(fmaf(dc, ry, b1)) << 16)) \
             | ((ull)((unsigned)f2bf(fmaf(dc, rz, b2)) | ((unsigned)f2bf(fmaf(dc, rw, b3)) << 16)) << 32); \
      __builtin_nontemporal_store(ov, (ull*)&outR[(size_t)node*256 + col_ofs + lf*4]); \
    } \
    ax = ay = az = aw = 0.f; }
#define DRAIN(CUR) \
    while (node < wend && (CUR) == nxt){ \
      EMIT_NODE \
      ++node; \
      nxt = __shfl(offs, min(node + 1 - wv0, KN), 64); \
    }

  DRAIN(cstart)                              // leading empty nodes

  const int nbat = (pend - cstart) >> 3;     // 8-edge batches, exact (padded)
  if (nbat > 0){
    const unsigned* cp = csrq + cstart + half*4;
    u32x4 qa, qb;
    unsigned va0, va1, va2, va3, vb0, vb1, vb2, vb3;

#define LQ(q, B) q = __builtin_nontemporal_load((const u32x4*)(cp + (B)*8));
#define GATH(v, q) \
    v##0 = tab[(size_t)q.x * 32 + lf]; \
    v##1 = tab[(size_t)q.y * 32 + lf]; \
    v##2 = tab[(size_t)q.z * 32 + lf]; \
    v##3 = tab[(size_t)q.w * 32 + lf];
#define FMA1(v) { \
    f32x2 lo = __builtin_amdgcn_cvt_pk_f32_fp8((int)v, false); \
    f32x2 hi = __builtin_amdgcn_cvt_pk_f32_fp8((int)v, true);  \
    ax += lo.x; ay += lo.y; az += hi.x; aw += hi.y; }
#define FMAB(v) { FMA1(v##0) FMA1(v##1) FMA1(v##2) FMA1(v##3) }

    LQ(qa, 0)
    GATH(va, qa)
    LQ(qb, 1)
    int b = 0;
    while (b + 2 <= nbat){
      LQ(qa, b + 2)              // speculative reads stay inside filled csr capacity
      GATH(vb, qb)
      FMAB(va)
      DRAIN(cstart + (b + 1)*8)
      LQ(qb, b + 3)
      GATH(va, qa)               // may gather next wave's rows / pad rows; unused unless valid
      FMAB(vb)
      DRAIN(cstart + (b + 2)*8)
      b += 2;
    }
    if (b < nbat){
      FMAB(va)
      DRAIN(cstart + nbat*8)
    }
#undef LQ
#undef GATH
#undef FMA1
#undef FMAB
  }
  // all remaining nodes (if any) are empty-tailed; DRAIN above emitted them.
  while (node < wend){ EMIT_NODE ++node; }
#undef EMIT_NODE
#undef DRAIN
}

// ---------- bf16 MFMA GEMM, m97-style 2-barrier loop ----------
// Thread count = WGM*WGN*64 (256 for most instances; 512 for BN=256 GEMM1).
// A [M x K] bf16 row-major (lda); AF32: A is f32, converted to bf16 during
// reg-staging (fuses the cvt pass; BN=256 single-pass reads x ONCE).
// Bt = B^T stored [BN_total x K] bf16.
// EPI 1: +bias, relu, bf16 store;
// EPI 2: A = 3 slabs (h|R1|R2, lda=256 each), +bias, fused log_softmax, f32 store;
// EPI 4: dual fp8 table store T[set][row][col] = fp8(vv * dis_set[row]).
template<int FM, int FN, int WGM, int WGN, int EPI, bool AF32>
__global__ __launch_bounds__(WGM*WGN*64, (WGM*WGN*64) == 512 ? 4 : 2) void gemm_kernel(
    const unsigned short* __restrict__ A0, const float* __restrict__ Af,
    const unsigned short* __restrict__ A1, const unsigned short* __restrict__ A2,
    const unsigned short* __restrict__ Bt, const float* __restrict__ bias,
    void* __restrict__ Cout, int M, int K, int lda, int ldc,
    const float* __restrict__ d1, const float* __restrict__ d2, int ntab)
{
  constexpr int THREADS = WGM*WGN*64;
  constexpr int BM = WGM*FM*16;
  constexpr int BN = WGN*FN*16;
  constexpr int BK = 32;
  constexpr int AJ = (BM*BK/8)/THREADS;   // 16B chunks per thread for A
  constexpr int BJ = (BN*BK/8)/THREADS;   // 16B chunks per thread for B
  static_assert(BM == 128, "staging assumes BM==128");
  __shared__ unsigned short As[BM][BK];
  __shared__ unsigned short Bs[BN][BK];
  const int tid = threadIdx.x;
  const int w = tid >> 6, l = tid & 63;
  const int wr = w / WGN, wc = w % WGN;
  const int m0 = blockIdx.x*BM, n0 = blockIdx.y*BN;
  f32x4 acc[FM][FN] = {};
  const int nsteps = K / BK;
  for (int s = 0; s < nsteps; ++s){
    const int k0 = s*BK;
    const unsigned short* Asrc = A0;
    int kin = k0;
    if constexpr (EPI == 2){
      int slab = k0 >> 8;
      Asrc = (slab == 0) ? A0 : ((slab == 1) ? A1 : A2);
      kin = k0 & 255;
    }
    __syncthreads();
    if constexpr (AF32){
      #pragma unroll
      for (int j = 0; j < AJ; ++j){        // A: load f32, cvt, store 16B to LDS
        int idx = j*THREADS + tid;
        int row = idx >> 2, kq = idx & 3;
        int rg = m0 + row; rg = (rg < M) ? rg : (M - 1);
        const float* src = Af + (size_t)rg*lda + kin + kq*8;
        float4 a = *(const float4*)src;
        float4 b2 = *(const float4*)(src + 4);
        ushort8v u;
        u[0] = f2bf(a.x);  u[1] = f2bf(a.y);  u[2] = f2bf(a.z);  u[3] = f2bf(a.w);
        u[4] = f2bf(b2.x); u[5] = f2bf(b2.y); u[6] = f2bf(b2.z); u[7] = f2bf(b2.w);
        *(ushort8v*)((char*)&As[0][0] + (size_t)idx*16) = u;
      }
    } else {
      #pragma unroll
      for (int j = 0; j < AJ; ++j){        // A: async 16B global->LDS
        int idx = j*THREADS + tid;
        int row = idx >> 2, kq = idx & 3;
        int rg = m0 + row; rg = (rg < M) ? rg : (M - 1);
        load_lds16(Asrc + (size_t)rg*lda + kin + kq*8,
                   ((char*)&As[0][0]) + (size_t)(j*THREADS + w*64)*16);
      }
    }
    #pragma unroll
    for (int j = 0; j < BJ; ++j){          // Bt: [n][k] layout, same pattern as A
      int idx = j*THREADS + tid;
      int row = idx >> 2, kq = idx & 3;
      load_lds16(Bt + (size_t)(n0 + row)*K + k0 + kq*8,
                 ((char*)&Bs[0][0]) + (size_t)(j*THREADS + w*64)*16);
    }
    __syncthreads();
    bf16x8 af[FM], bfr[FN];
    const int kofs = (l >> 4)*8, l16 = l & 15;
    #pragma unroll
    for (int mi = 0; mi < FM; ++mi)
      af[mi] = *(const bf16x8*)&As[wr*FM*16 + mi*16 + l16][kofs];
    #pragma unroll
    for (int ni = 0; ni < FN; ++ni)
      bfr[ni] = *(const bf16x8*)&Bs[wc*FN*16 + ni*16 + l16][kofs];
    #pragma unroll
    for (int mi = 0; mi < FM; ++mi)
      #pragma unroll
      for (int ni = 0; ni < FN; ++ni)
        acc[mi][ni] = __builtin_amdgcn_mfma_f32_16x16x32_bf16(af[mi], bfr[ni], acc[mi][ni], 0, 0, 0);
  }
  const int lg = l >> 4, lc = l & 15;
  if constexpr (EPI == 2){
    float* O = (float*)Cout;
    #pragma unroll
    for (int mi = 0; mi < FM; ++mi){
      #pragma unroll
      for (int i = 0; i < 4; ++i){
        int row = m0 + wr*FM*16 + mi*16 + lg*4 + i;
        float v[FN];
        float mx = -1e30f;
        #pragma unroll
        for (int ni = 0; ni < FN; ++ni){
          int col = ni*16 + lc;                       // WGN==1, n0==0
          v[ni] = acc[mi][ni][i] + ((col < 40) ? bias[col] : 0.f);
          if (col < 40) mx = fmaxf(mx, v[ni]);
        }
        #pragma unroll
        for (int d = 1; d < 16; d <<= 1) mx = fmaxf(mx, __shfl_xor(mx, d, 64));
        float se = 0.f;
        #pragma unroll
        for (int ni = 0; ni < FN; ++ni){
          int col = ni*16 + lc;
          if (col < 40) se += expf(v[ni] - mx);
        }
        #pragma unroll
        for (int d = 1; d < 16; d <<= 1) se += __shfl_xor(se, d, 64);
        float lse = logf(se);
        if (row < M){
          #pragma unroll
          for (int ni = 0; ni < FN; ++ni){
            int col = ni*16 + lc;
            if (col < 40) O[(size_t)row*40 + col] = v[ni] - mx - lse;
          }
        }
      }
    }
  } else if constexpr (EPI == 4){
    unsigned char* T = (unsigned char*)Cout;            // [2][ntab][128]
    #pragma unroll
    for (int mi = 0; mi < FM; ++mi){
      #pragma unroll
      for (int i = 0; i < 4; ++i){
        int row = m0 + wr*FM*16 + mi*16 + lg*4 + i;
        if (row >= M) continue;
        float s1 = d1[row], s2 = d2[row];
        #pragma unroll
        for (int ni = 0; ni < FN; ++ni){
          int col = n0 + wc*FN*16 + ni*16 + lc;        // [0,128)
          float vv = acc[mi][ni][i];
          unsigned p1 = (unsigned)__builtin_amdgcn_cvt_pk_fp8_f32(vv*s1, vv*s1, 0, false);
          unsigned p2 = (unsigned)__builtin_amdgcn_cvt_pk_fp8_f32(vv*s2, vv*s2, 0, false);
          T[(size_t)row*128 + col] = (unsigned char)(p1 & 0xff);
          T[((size_t)ntab + row)*128 + col] = (unsigned char)(p2 & 0xff);
        }
      }
    }
  } else {
    unsigned short* C = (unsigned short*)Cout;
    #pragma unroll
    for (int mi = 0; mi < FM; ++mi){
      #pragma unroll
      for (int i = 0; i < 4; ++i){
        int row = m0 + wr*FM*16 + mi*16 + lg*4 + i;
        if (row >= M) continue;
        #pragma unroll
        for (int ni = 0; ni < FN; ++ni){
          int col = n0 + wc*FN*16 + ni*16 + lc;
          float vv = acc[mi][ni][i];
          if constexpr (EPI == 1){ vv += bias[col]; vv = fmaxf(vv, 0.f); }
          C[(size_t)row*ldc + col] = f2bf(vv);
        }
      }
    }
  }
}

extern "C" void kernel_launch(void* const* d_in, const int* in_sizes, int n_in,
                              void* d_out, int out_size, void* d_ws, size_t ws_size,
                              hipStream_t stream)
{
  (void)n_in; (void)out_size;
  const float* x      = (const float*)d_in[0];
  const int*   ei1    = (const int*)d_in[1];
  const int*   ei2    = (const int*)d_in[2];
  const float* W_lin1 = (const float*)d_in[3];
  const float* b_lin1 = (const float*)d_in[4];
  const float* W_c1   = (const float*)d_in[5];
  const float* b_c1   = (const float*)d_in[6];
  const float* W_c2   = (const float*)d_in[7];
  const float* b_c2   = (const float*)d_in[8];
  const float* W_lin2 = (const float*)d_in[9];
  const float* b_lin2 = (const float*)d_in[10];

  const int N  = in_sizes[0] / 512;
  const int E1 = in_sizes[1] / 2;
  const int E2 = in_sizes[2] / 2;
  const int ntab = N + 1;                    // +1 zero row for pad edges
  const int NB = (N + 127) >> 7;             // destination buckets of 128 nodes
  // fixed per-bucket staging capacities (uniform edges: mean + >17 sigma)
  const int cap1r = (((E1 + NB - 1)/NB + 768) + 63) & ~63;
  const int cap2r = (((E2 + NB - 1)/NB + 1536) + 63) & ~63;

  char* base = (char*)d_ws;
  size_t off = 0;
  auto alloc = [&](size_t bytes) -> char* {
    off = (off + 255) & ~(size_t)255;
    char* r = base + off;
    off += bytes;
    return r;
  };
  // padded-CSR capacities in 4B records (pad <= 7 per node, + speculative slack)
  const size_t cap1 = (size_t)E1 + 8*(size_t)N + 64;
  const size_t cap2 = (size_t)E2 + 8*(size_t)N + 64;

  unsigned short* h    = (unsigned short*)alloc((size_t)N*256*2);
  unsigned char*  T    = (unsigned char*)alloc((size_t)2*ntab*128); // fp8 scaled tables
  unsigned short* R1   = (unsigned short*)alloc((size_t)N*256*2);
  unsigned short* R2   = (unsigned short*)alloc((size_t)N*256*2);
  unsigned short* Wt1  = (unsigned short*)alloc((size_t)256*512*2);
  unsigned short* Wtc1 = (unsigned short*)alloc((size_t)128*256*2);
  unsigned short* Wtc2 = (unsigned short*)alloc((size_t)128*256*2);
  unsigned short* Wtf  = (unsigned short*)alloc((size_t)64*768*2); // W_lin2^T padded to 64 cols
  int* degblk = (int*)alloc((size_t)2*N*4);
  int* deg1 = degblk, *deg2 = degblk + N;
  float* dis1 = (float*)alloc((size_t)N*4);
  float* dis2 = (float*)alloc((size_t)N*4);
  int* off1 = (int*)alloc((size_t)(N+1)*4);
  int* off2 = (int*)alloc((size_t)(N+1)*4);
  int* bsum  = (int*)alloc(128*4);
  int* bbase = (int*)alloc(128*4);
  int* bcur  = (int*)alloc((size_t)2*NB*4);
  unsigned* csr1 = (unsigned*)alloc(cap1*4);
  unsigned* csr2 = (unsigned*)alloc(cap2*4);
  unsigned* staging = (unsigned*)alloc((size_t)NB*((size_t)cap1r + cap2r)*4);
  if (off > ws_size) return;   // workspace insufficient -> visible validation failure

  int mt = (N + 127)/128;
  int nwv = (N + KN - 1)/KN;
  int cb = (nwv + 3)/4;

  // --- fused weight transposes + bucket-cursor init ---
  wtrans4_kernel<<<(245760 + 2*NB + 64 + 255)/256, 256, 0, stream>>>(
      W_lin1, Wt1, W_c1, Wtc1, W_c2, Wtc2, W_lin2, Wtf,
      NB, cap1r, cap2r, bcur,
      (unsigned*)(T + (size_t)N*128), (unsigned*)(T + ((size_t)ntab + N)*128));
  // h = relu(x @ W_lin1 + b): BN=256 single pass, x f32 read ONCE (fused cvt)
  gemm_kernel<4,4,2,4,1,true><<<dim3(mt, 1), 512, 0, stream>>>(
      nullptr, x, nullptr, nullptr, Wt1, b_lin1, h, N, 512, 512, 256, nullptr, nullptr, 0);

  // --- graph preprocessing (bucketed, fixed-capacity staging) ---
  partA_kernel<<<dim3((E2 + PCH - 1)/PCH, 2), 256, 0, stream>>>(ei1, E1, ei2, E2, bcur, staging, NB);
  degB_kernel<<<dim3(NB, 2), 256, 0, stream>>>(staging, bcur, deg1, deg2, dis1, dis2,
                                               NB, N, cap1r, cap2r);
  int nch = (N + 1023)/1024;
  scan1_kernel<<<dim3(nch, 2), 1024, 0, stream>>>(deg1, deg2, off1, off2, bsum, N);
  scan2_kernel<<<1, 64, 0, stream>>>(bsum, bbase, nch, off1, off2, N);
  scan3_kernel<<<dim3(nch, 2), 1024, 0, stream>>>(deg1, deg2, off1, off2, bbase, N);
  partB_kernel<<<dim3(NB, 2), 256, 0, stream>>>(staging, bcur, off1, off2, csr1, csr2,
                                                NB, N, (unsigned)N, cap1r, cap2r);

  // --- layer 1: T = fp8(dis_set[r] * (h @ W_c1)[r]), then one conv pass ---
  gemm_kernel<4,4,2,2,4,false><<<dim3(mt, 1), 256, 0, stream>>>(
      h, nullptr, nullptr, nullptr, Wtc1, nullptr, T, N, 256, 256, 0, dis1, dis2, ntab);
  conv_kernel<<<dim3(cb, 2), 256, 0, stream>>>(off1, csr1, dis1, off2, csr2, dis2,
                                               T, b_c1, R1, N, ntab);
  // --- layer 2: T = fp8(dis_set[r] * (R1 @ W_c2)[r]), conv ---
  gemm_kernel<4,4,2,2,4,false><<<dim3(mt, 1), 256, 0, stream>>>(
      R1, nullptr, nullptr, nullptr, Wtc2, nullptr, T, N, 256, 256, 0, dis1, dis2, ntab);
  conv_kernel<<<dim3(cb, 2), 256, 0, stream>>>(off1, csr1, dis1, off2, csr2, dis2,
                                               T, b_c2, R2, N, ntab);
  // --- head: logits = [h|R1|R2] @ W_lin2 + b, fused log_softmax ---
  gemm_kernel<2,4,4,1,2,false><<<dim3(mt, 1), 256, 0, stream>>>(
      h, nullptr, R1, R2, Wtf, b_lin2, d_out, N, 768, 256, 40, nullptr, nullptr, 0);
}

// Round 14
// 239.335 us; speedup vs baseline: 4.1349x; 1.0370x over previous
//
#include <hip/hip_runtime.h>
#include <hip/hip_bf16.h>
#include <stdint.h>
#include <math.h>

typedef __attribute__((ext_vector_type(8))) short bf16x8;
typedef __attribute__((ext_vector_type(8))) unsigned short ushort8v;
typedef __attribute__((ext_vector_type(4))) float f32x4;
typedef __attribute__((ext_vector_type(2))) float f32x2;
typedef __attribute__((ext_vector_type(4))) unsigned int u32x4;
typedef unsigned long long ull;

__device__ __forceinline__ void load_lds16(const void* g, void* l){
  __builtin_amdgcn_global_load_lds((const __attribute__((address_space(1))) void*)g,
                                   (__attribute__((address_space(3))) void*)l, 16, 0, 0);
}

__device__ __forceinline__ float bf2f(unsigned int u){
  union { unsigned int i; float f; } x; x.i = u << 16; return x.f;
}
__device__ __forceinline__ unsigned short f2bf(float f){
  __hip_bfloat16 h = __float2bfloat16(f);
  unsigned short u;
  __builtin_memcpy(&u, &h, 2);
  return u;
}

// ---------- fused weight transposes + bucket-cursor init (one dispatch) ----------
__global__ void wtrans4_kernel(const float* __restrict__ W1, unsigned short* __restrict__ Wt1,
                               const float* __restrict__ Wc1, unsigned short* __restrict__ Wtc1,
                               const float* __restrict__ Wc2, unsigned short* __restrict__ Wtc2,
                               const float* __restrict__ Wf, unsigned short* __restrict__ Wtf,
                               int NB, int cap1r, int cap2r, int* __restrict__ bcur,
                               unsigned* __restrict__ Tz0, unsigned* __restrict__ Tz1){
  int idx = blockIdx.x*256 + threadIdx.x;
  if (idx >= 245760){                       // binit tail
    int i = idx - 245760;
    if (i < NB) bcur[i] = i*cap1r;
    else if (i < 2*NB) bcur[i] = NB*cap1r + (i - NB)*cap2r;
    else if (i < 2*NB + 32) Tz0[i - 2*NB] = 0u;
    else if (i < 2*NB + 64) Tz1[i - 2*NB - 32] = 0u;
    return;
  }
  const float* W; unsigned short* Wt; int K, N;
  if (idx < 131072){ W = W1; Wt = Wt1; K = 512; N = 256; }
  else if (idx < 163840){ idx -= 131072; W = Wc1; Wt = Wtc1; K = 256; N = 128; }
  else if (idx < 196608){ idx -= 163840; W = Wc2; Wt = Wtc2; K = 256; N = 128; }
  else { idx -= 196608; W = Wf; Wt = Wtf; K = 768; N = 40; }
  int nn = idx / K, kk = idx - nn*K;
  float v = (nn < N) ? W[(size_t)kk*N + nn] : 0.f;
  Wt[idx] = f2bf(v);
}

// ---------- graph preprocessing (bucketed, atomic-light, fixed-capacity) ----------
// Buckets of 128 destination nodes. Staging AND the final CSR are both
// bucket-strided with fixed +17sigma capacities -> NO global scans needed.
// partA partitions edges into staging; degpartB (one kernel) then counts,
// LDS-scans the 128 padded degrees, writes dis + per-bucket goff[129]
// (absolute record offsets incl. bucket end), scatters into csr with LDS
// cursors, pads each node to an 8-multiple, and fills 64 slack records
// past the used end (covers conv's speculative prefetch).
#define PCH 4096

// Pass A: partition PCH-edge chunks into bucket staging
__global__ __launch_bounds__(256) void partA_kernel(
    const int* __restrict__ ei1, int E1, const int* __restrict__ ei2, int E2,
    int* __restrict__ bcur, unsigned* __restrict__ staging, int NB)
{
  const int set = blockIdx.y;
  const int* __restrict__ ei = set ? ei2 : ei1;
  const int E = set ? E2 : E1;
  int* __restrict__ cur = bcur + set*NB;
  __shared__ int hist[400];
  __shared__ int resv[400];
  const int tid = threadIdx.x;
  const int base = blockIdx.x * PCH;
  if (base >= E) return;
  for (int b = tid; b < NB; b += 256) hist[b] = 0;
  __syncthreads();

  if (base + PCH <= E){
    // fast path: 16 edges/thread, rows+cols vector-loaded up front (8x int4 in flight)
    const int t0 = base + tid*16;
    int4 c[4], r[4];
    #pragma unroll
    for (int j = 0; j < 4; ++j) c[j] = *(const int4*)(ei + E + t0 + j*4);
    #pragma unroll
    for (int j = 0; j < 4; ++j) r[j] = *(const int4*)(ei + t0 + j*4);
    #pragma unroll
    for (int j = 0; j < 4; ++j){
      atomicAdd(&hist[c[j].x >> 7], 1); atomicAdd(&hist[c[j].y >> 7], 1);
      atomicAdd(&hist[c[j].z >> 7], 1); atomicAdd(&hist[c[j].w >> 7], 1);
    }
    __syncthreads();
    for (int b = tid; b < NB; b += 256){
      int hc = hist[b];
      resv[b] = hc ? atomicAdd(&cur[b], hc) : 0;
      hist[b] = 0;                      // reuse as local cursor
    }
    __syncthreads();
    #pragma unroll
    for (int j = 0; j < 4; ++j){
      int cc, rr, b, s;
      cc = c[j].x; rr = r[j].x; b = cc >> 7;
      s = resv[b] + atomicAdd(&hist[b], 1);
      staging[s] = ((unsigned)rr << 7) | (unsigned)(cc & 127);
      cc = c[j].y; rr = r[j].y; b = cc >> 7;
      s = resv[b] + atomicAdd(&hist[b], 1);
      staging[s] = ((unsigned)rr << 7) | (unsigned)(cc & 127);
      cc = c[j].z; rr = r[j].z; b = cc >> 7;
      s = resv[b] + atomicAdd(&hist[b], 1);
      staging[s] = ((unsigned)rr << 7) | (unsigned)(cc & 127);
      cc = c[j].w; rr = r[j].w; b = cc >> 7;
      s = resv[b] + atomicAdd(&hist[b], 1);
      staging[s] = ((unsigned)rr << 7) | (unsigned)(cc & 127);
    }
  } else {
    // tail path: guarded scalar
    for (int i = 0; i < PCH/256; ++i){
      int e = base + i*256 + tid;
      if (e < E) atomicAdd(&hist[ei[E + e] >> 7], 1);
    }
    __syncthreads();
    for (int b = tid; b < NB; b += 256){
      int hc = hist[b];
      resv[b] = hc ? atomicAdd(&cur[b], hc) : 0;
      hist[b] = 0;
    }
    __syncthreads();
    for (int i = 0; i < PCH/256; ++i){
      int e = base + i*256 + tid;
      if (e < E){
        int c = ei[E + e], r = ei[e];
        int b = c >> 7;
        int s = resv[b] + atomicAdd(&hist[b], 1);
        staging[s] = ((unsigned)r << 7) | (unsigned)(c & 127);
      }
    }
  }
}

// Fused: count + LDS scan + dis/goff write + local scatter + pad + slack fill.
// goff layout: [b*129 + local] = absolute record offset of node start;
// slot 128 = bucket end-of-used. csr is bucket-strided (capb records/bucket).
__global__ __launch_bounds__(256) void degpartB_kernel(
    const unsigned* __restrict__ staging, const int* __restrict__ bcur,
    float* __restrict__ dis1, float* __restrict__ dis2,
    int* __restrict__ goff1, int* __restrict__ goff2,
    unsigned* __restrict__ csr1, unsigned* __restrict__ csr2,
    int NB, int n, unsigned padrow, int cap1r, int cap2r, int capb1, int capb2)
{
  const int set = blockIdx.y;
  float* __restrict__ dis = set ? dis2 : dis1;
  int* __restrict__ goff = set ? goff2 : goff1;
  unsigned* __restrict__ csr = set ? csr2 : csr1;
  const int capb = set ? capb2 : capb1;
  const int b = blockIdx.x;
  const int nodebase = b << 7;
  const int nn = min(128, n - nodebase);
  if (nn <= 0) return;
  __shared__ int cnt[128];
  __shared__ int offv[129];
  __shared__ int curl[128];
  const int tid = threadIdx.x;
  if (tid < 128) cnt[tid] = 0;
  __syncthreads();
  const int s0 = set ? (NB*cap1r + b*cap2r) : (b*cap1r);
  const int s1 = bcur[set*NB + b];
  for (int i = s0 + tid; i < s1; i += 256)
    atomicAdd(&cnt[staging[i] & 127], 1);
  __syncthreads();
  // Hillis-Steele inclusive scan of padded counts (128 entries, in curl)
  int pc = 0;
  if (tid < 128){ pc = (cnt[tid] + 7) & ~7; curl[tid] = pc; }
  __syncthreads();
  for (int o = 1; o < 128; o <<= 1){
    int t = 0;
    if (tid < 128 && tid >= o) t = curl[tid - o];
    __syncthreads();
    if (tid < 128) curl[tid] += t;
    __syncthreads();
  }
  const int cbase = b * capb;
  if (tid < 128){
    offv[tid] = cbase + curl[tid] - pc;       // exclusive start
    if (tid == 127) offv[128] = cbase + curl[127];
  }
  __syncthreads();
  if (tid <= 128) goff[b*129 + tid] = offv[tid];
  if (tid < nn){
    int c = cnt[tid];
    dis[nodebase + tid] = (c > 0) ? (1.0f/sqrtf((float)c)) : 0.f;
  }
  if (tid < 128) curl[tid] = 0;
  __syncthreads();
  // local scatter with LDS cursors (no global atomics)
  for (int i = s0 + tid; i < s1; i += 256){
    unsigned v = staging[i];
    int cl = v & 127;
    int p = offv[cl] + atomicAdd(&curl[cl], 1);
    csr[p] = v >> 7;
  }
  __syncthreads();
  // pad each node to its 8-multiple region; fill 64 slack records past end
  for (int c = tid; c < 128; c += 256){
    int p1 = offv[c + 1];
    for (int p = offv[c] + cnt[c]; p < p1; ++p) csr[p] = padrow;
  }
  if (tid < 64) csr[offv[128] + tid] = padrow;
}

// ---------- GCN aggregation: out[c] = dis[c] * sum_e T_set[r] + b ----------
// T rows PRE-SCALED by dis_set[r], fp8 e4m3 (128B/row = 2 lines/edge).
// KN consecutive nodes per wave stream one contiguous padded-CSR range through
// a 2-stage pipeline with no restarts; node boundaries via shfl-indexed
// register cache (wave-uniform). goff is bucket-local (129-stride); KN | 128
// so a wave never crosses a bucket.
#define KN 8
__global__ __launch_bounds__(256) void conv_kernel(
    const int* __restrict__ goff1, const unsigned* __restrict__ csr1, const float* __restrict__ dis1,
    const int* __restrict__ goff2, const unsigned* __restrict__ csr2, const float* __restrict__ dis2,
    const unsigned char* __restrict__ Tbase,   // [2][ntab][128] fp8
    const float* __restrict__ bias, unsigned short* __restrict__ outR,
    int n, int ntab)
{
  const int set = blockIdx.y;
  const int* __restrict__ goff = set ? goff2 : goff1;
  const float* __restrict__ dis = set ? dis2 : dis1;
  const unsigned* __restrict__ csrq = set ? csr2 : csr1;
  const int col_ofs = set ? 128 : 0;
  const unsigned* __restrict__ tab =
      (const unsigned*)(Tbase + (size_t)set * ntab * 128);

  const int wv0 = (blockIdx.x*4 + (threadIdx.x >> 6)) * KN;
  if (wv0 >= n) return;
  const int wend = min(n, wv0 + KN);
  const int l = threadIdx.x & 63;
  const int half = l >> 5, lf = l & 31;
  const float b0 = bias[lf*4 + 0], b1 = bias[lf*4 + 1];
  const float b2 = bias[lf*4 + 2], b3 = bias[lf*4 + 3];

  // lanes 0..KN hold goff[node .. bucket-local]; shfl-indexed boundary cache
  const int gbase = (wv0 >> 7)*129 + (wv0 & 127);
  const int offs = goff[gbase + min(l, wend - wv0)];
  const int cstart = __shfl(offs, 0, 64);
  const int pend   = __shfl(offs, wend - wv0, 64);
  int node = wv0;
  int nxt  = __shfl(offs, min(1, wend - wv0), 64);

  float ax = 0.f, ay = 0.f, az = 0.f, aw = 0.f;

#define EMIT_NODE { \
    float rx = ax + __shfl_xor(ax, 32, 64); \
    float ry = ay + __shfl_xor(ay, 32, 64); \
    float rz = az + __shfl_xor(az, 32, 64); \
    float rw = aw + __shfl_xor(aw, 32, 64); \
    if (half == 0){ \
      const float dc = dis[node]; \
      ull ov = (ull)((unsigned)f2bf(fmaf(dc, rx, b0)) | ((unsigned)f2bf(fmaf(dc, ry, b1)) << 16)) \
             | ((ull)((unsigned)f2bf(fmaf(dc, rz, b2)) | ((unsigned)f2bf(fmaf(dc, rw, b3)) << 16)) << 32); \
      __builtin_nontemporal_store(ov, (ull*)&outR[(size_t)node*256 + col_ofs + lf*4]); \
    } \
    ax = ay = az = aw = 0.f; }
#define DRAIN(CUR) \
    while (node < wend && (CUR) == nxt){ \
      EMIT_NODE \
      ++node; \
      nxt = __shfl(offs, min(node + 1 - wv0, KN), 64); \
    }

  DRAIN(cstart)                              // leading empty nodes

  const int nbat = (pend - cstart) >> 3;     // 8-edge batches, exact (padded)
  if (nbat > 0){
    const unsigned* cp = csrq + cstart + half*4;
    u32x4 qa, qb;
    unsigned va0, va1, va2, va3, vb0, vb1, vb2, vb3;

#define LQ(q, B) q = __builtin_nontemporal_load((const u32x4*)(cp + (B)*8));
#define GATH(v, q) \
    v##0 = tab[(size_t)q.x * 32 + lf]; \
    v##1 = tab[(size_t)q.y * 32 + lf]; \
    v##2 = tab[(size_t)q.z * 32 + lf]; \
    v##3 = tab[(size_t)q.w * 32 + lf];
#define FMA1(v) { \
    f32x2 lo = __builtin_amdgcn_cvt_pk_f32_fp8((int)v, false); \
    f32x2 hi = __builtin_amdgcn_cvt_pk_f32_fp8((int)v, true);  \
    ax += lo.x; ay += lo.y; az += hi.x; aw += hi.y; }
#define FMAB(v) { FMA1(v##0) FMA1(v##1) FMA1(v##2) FMA1(v##3) }

    LQ(qa, 0)
    GATH(va, qa)
    LQ(qb, 1)
    int b = 0;
    while (b + 2 <= nbat){
      LQ(qa, b + 2)              // speculative reads stay inside filled bucket (64-slack)
      GATH(vb, qb)
      FMAB(va)
      DRAIN(cstart + (b + 1)*8)
      LQ(qb, b + 3)
      GATH(va, qa)               // pad/slack rows hit the zeroed T row; harmless
      FMAB(vb)
      DRAIN(cstart + (b + 2)*8)
      b += 2;
    }
    if (b < nbat){
      FMAB(va)
      DRAIN(cstart + nbat*8)
    }
#undef LQ
#undef GATH
#undef FMA1
#undef FMAB
  }
  while (node < wend){ EMIT_NODE ++node; }
#undef EMIT_NODE
#undef DRAIN
}

// ---------- bf16 MFMA GEMM, m97-style 2-barrier loop ----------
// Thread count = WGM*WGN*64 (256 for most instances; 512 for BN=256 GEMM1).
// A [M x K] bf16 row-major (lda); AF32: A is f32, converted to bf16 during
// reg-staging (fuses the cvt pass; BN=256 single-pass reads x ONCE).
// Bt = B^T stored [BN_total x K] bf16.
// EPI 1: +bias, relu, bf16 store;
// EPI 2: A = 3 slabs (h|R1|R2, lda=256 each), +bias, fused log_softmax, f32 store;
// EPI 4: dual fp8 table store T[set][row][col] = fp8(vv * dis_set[row]).
template<int FM, int FN, int WGM, int WGN, int EPI, bool AF32>
__global__ __launch_bounds__(WGM*WGN*64, (WGM*WGN*64) == 512 ? 4 : 2) void gemm_kernel(
    const unsigned short* __restrict__ A0, const float* __restrict__ Af,
    const unsigned short* __restrict__ A1, const unsigned short* __restrict__ A2,
    const unsigned short* __restrict__ Bt, const float* __restrict__ bias,
    void* __restrict__ Cout, int M, int K, int lda, int ldc,
    const float* __restrict__ d1, const float* __restrict__ d2, int ntab)
{
  constexpr int THREADS = WGM*WGN*64;
  constexpr int BM = WGM*FM*16;
  constexpr int BN = WGN*FN*16;
  constexpr int BK = 32;
  constexpr int AJ = (BM*BK/8)/THREADS;   // 16B chunks per thread for A
  constexpr int BJ = (BN*BK/8)/THREADS;   // 16B chunks per thread for B
  static_assert(BM == 128, "staging assumes BM==128");
  __shared__ unsigned short As[BM][BK];
  __shared__ unsigned short Bs[BN][BK];
  const int tid = threadIdx.x;
  const int w = tid >> 6, l = tid & 63;
  const int wr = w / WGN, wc = w % WGN;
  const int m0 = blockIdx.x*BM, n0 = blockIdx.y*BN;
  f32x4 acc[FM][FN] = {};
  const int nsteps = K / BK;
  for (int s = 0; s < nsteps; ++s){
    const int k0 = s*BK;
    const unsigned short* Asrc = A0;
    int kin = k0;
    if constexpr (EPI == 2){
      int slab = k0 >> 8;
      Asrc = (slab == 0) ? A0 : ((slab == 1) ? A1 : A2);
      kin = k0 & 255;
    }
    __syncthreads();
    if constexpr (AF32){
      #pragma unroll
      for (int j = 0; j < AJ; ++j){        // A: load f32, cvt, store 16B to LDS
        int idx = j*THREADS + tid;
        int row = idx >> 2, kq = idx & 3;
        int rg = m0 + row; rg = (rg < M) ? rg : (M - 1);
        const float* src = Af + (size_t)rg*lda + kin + kq*8;
        float4 a = *(const float4*)src;
        float4 b2 = *(const float4*)(src + 4);
        ushort8v u;
        u[0] = f2bf(a.x);  u[1] = f2bf(a.y);  u[2] = f2bf(a.z);  u[3] = f2bf(a.w);
        u[4] = f2bf(b2.x); u[5] = f2bf(b2.y); u[6] = f2bf(b2.z); u[7] = f2bf(b2.w);
        *(ushort8v*)((char*)&As[0][0] + (size_t)idx*16) = u;
      }
    } else {
      #pragma unroll
      for (int j = 0; j < AJ; ++j){        // A: async 16B global->LDS
        int idx = j*THREADS + tid;
        int row = idx >> 2, kq = idx & 3;
        int rg = m0 + row; rg = (rg < M) ? rg : (M - 1);
        load_lds16(Asrc + (size_t)rg*lda + kin + kq*8,
                   ((char*)&As[0][0]) + (size_t)(j*THREADS + w*64)*16);
      }
    }
    #pragma unroll
    for (int j = 0; j < BJ; ++j){          // Bt: [n][k] layout, same pattern as A
      int idx = j*THREADS + tid;
      int row = idx >> 2, kq = idx & 3;
      load_lds16(Bt + (size_t)(n0 + row)*K + k0 + kq*8,
                 ((char*)&Bs[0][0]) + (size_t)(j*THREADS + w*64)*16);
    }
    __syncthreads();
    bf16x8 af[FM], bfr[FN];
    const int kofs = (l >> 4)*8, l16 = l & 15;
    #pragma unroll
    for (int mi = 0; mi < FM; ++mi)
      af[mi] = *(const bf16x8*)&As[wr*FM*16 + mi*16 + l16][kofs];
    #pragma unroll
    for (int ni = 0; ni < FN; ++ni)
      bfr[ni] = *(const bf16x8*)&Bs[wc*FN*16 + ni*16 + l16][kofs];
    #pragma unroll
    for (int mi = 0; mi < FM; ++mi)
      #pragma unroll
      for (int ni = 0; ni < FN; ++ni)
        acc[mi][ni] = __builtin_amdgcn_mfma_f32_16x16x32_bf16(af[mi], bfr[ni], acc[mi][ni], 0, 0, 0);
  }
  const int lg = l >> 4, lc = l & 15;
  if constexpr (EPI == 2){
    float* O = (float*)Cout;
    #pragma unroll
    for (int mi = 0; mi < FM; ++mi){
      #pragma unroll
      for (int i = 0; i < 4; ++i){
        int row = m0 + wr*FM*16 + mi*16 + lg*4 + i;
        float v[FN];
        float mx = -1e30f;
        #pragma unroll
        for (int ni = 0; ni < FN; ++ni){
          int col = ni*16 + lc;                       // WGN==1, n0==0
          v[ni] = acc[mi][ni][i] + ((col < 40) ? bias[col] : 0.f);
          if (col < 40) mx = fmaxf(mx, v[ni]);
        }
        #pragma unroll
        for (int d = 1; d < 16; d <<= 1) mx = fmaxf(mx, __shfl_xor(mx, d, 64));
        float se = 0.f;
        #pragma unroll
        for (int ni = 0; ni < FN; ++ni){
          int col = ni*16 + lc;
          if (col < 40) se += expf(v[ni] - mx);
        }
        #pragma unroll
        for (int d = 1; d < 16; d <<= 1) se += __shfl_xor(se, d, 64);
        float lse = logf(se);
        if (row < M){
          #pragma unroll
          for (int ni = 0; ni < FN; ++ni){
            int col = ni*16 + lc;
            if (col < 40) O[(size_t)row*40 + col] = v[ni] - mx - lse;
          }
        }
      }
    }
  } else if constexpr (EPI == 4){
    unsigned char* T = (unsigned char*)Cout;            // [2][ntab][128]
    #pragma unroll
    for (int mi = 0; mi < FM; ++mi){
      #pragma unroll
      for (int i = 0; i < 4; ++i){
        int row = m0 + wr*FM*16 + mi*16 + lg*4 + i;
        if (row >= M) continue;
        float s1 = d1[row], s2 = d2[row];
        #pragma unroll
        for (int ni = 0; ni < FN; ++ni){
          int col = n0 + wc*FN*16 + ni*16 + lc;        // [0,128)
          float vv = acc[mi][ni][i];
          unsigned p1 = (unsigned)__builtin_amdgcn_cvt_pk_fp8_f32(vv*s1, vv*s1, 0, false);
          unsigned p2 = (unsigned)__builtin_amdgcn_cvt_pk_fp8_f32(vv*s2, vv*s2, 0, false);
          T[(size_t)row*128 + col] = (unsigned char)(p1 & 0xff);
          T[((size_t)ntab + row)*128 + col] = (unsigned char)(p2 & 0xff);
        }
      }
    }
  } else {
    unsigned short* C = (unsigned short*)Cout;
    #pragma unroll
    for (int mi = 0; mi < FM; ++mi){
      #pragma unroll
      for (int i = 0; i < 4; ++i){
        int row = m0 + wr*FM*16 + mi*16 + lg*4 + i;
        if (row >= M) continue;
        #pragma unroll
        for (int ni = 0; ni < FN; ++ni){
          int col = n0 + wc*FN*16 + ni*16 + lc;
          float vv = acc[mi][ni][i];
          if constexpr (EPI == 1){ vv += bias[col]; vv = fmaxf(vv, 0.f); }
          C[(size_t)row*ldc + col] = f2bf(vv);
        }
      }
    }
  }
}

extern "C" void kernel_launch(void* const* d_in, const int* in_sizes, int n_in,
                              void* d_out, int out_size, void* d_ws, size_t ws_size,
                              hipStream_t stream)
{
  (void)n_in; (void)out_size;
  const float* x      = (const float*)d_in[0];
  const int*   ei1    = (const int*)d_in[1];
  const int*   ei2    = (const int*)d_in[2];
  const float* W_lin1 = (const float*)d_in[3];
  const float* b_lin1 = (const float*)d_in[4];
  const float* W_c1   = (const float*)d_in[5];
  const float* b_c1   = (const float*)d_in[6];
  const float* W_c2   = (const float*)d_in[7];
  const float* b_c2   = (const float*)d_in[8];
  const float* W_lin2 = (const float*)d_in[9];
  const float* b_lin2 = (const float*)d_in[10];

  const int N  = in_sizes[0] / 512;
  const int E1 = in_sizes[1] / 2;
  const int E2 = in_sizes[2] / 2;
  const int ntab = N + 1;                    // +1 zero row for pad edges
  const int NB = (N + 127) >> 7;             // destination buckets of 128 nodes
  // fixed per-bucket staging capacities (uniform edges: mean + >17 sigma)
  const int cap1r = (((E1 + NB - 1)/NB + 768) + 63) & ~63;
  const int cap2r = (((E2 + NB - 1)/NB + 1536) + 63) & ~63;
  // fixed per-bucket CSR capacities: mean + 17 sigma + max pad (7*128) + 64 slack
  const int mb1 = (int)(128.0*E1/N), mb2 = (int)(128.0*E2/N);
  const int capb1 = (mb1 + (int)(17.0*sqrt((double)mb1)) + 896 + 64 + 63) & ~63;
  const int capb2 = (mb2 + (int)(17.0*sqrt((double)mb2)) + 896 + 64 + 63) & ~63;

  char* base = (char*)d_ws;
  size_t off = 0;
  auto alloc = [&](size_t bytes) -> char* {
    off = (off + 255) & ~(size_t)255;
    char* r = base + off;
    off += bytes;
    return r;
  };

  unsigned short* h    = (unsigned short*)alloc((size_t)N*256*2);
  unsigned char*  T    = (unsigned char*)alloc((size_t)2*ntab*128); // fp8 scaled tables
  unsigned short* R1   = (unsigned short*)alloc((size_t)N*256*2);
  unsigned short* R2   = (unsigned short*)alloc((size_t)N*256*2);
  unsigned short* Wt1  = (unsigned short*)alloc((size_t)256*512*2);
  unsigned short* Wtc1 = (unsigned short*)alloc((size_t)128*256*2);
  unsigned short* Wtc2 = (unsigned short*)alloc((size_t)128*256*2);
  unsigned short* Wtf  = (unsigned short*)alloc((size_t)64*768*2); // W_lin2^T padded to 64 cols
  float* dis1 = (float*)alloc((size_t)N*4);
  float* dis2 = (float*)alloc((size_t)N*4);
  int* goff1 = (int*)alloc((size_t)NB*129*4);
  int* goff2 = (int*)alloc((size_t)NB*129*4);
  int* bcur  = (int*)alloc((size_t)2*NB*4);
  unsigned* csr1 = (unsigned*)alloc((size_t)NB*capb1*4);
  unsigned* csr2 = (unsigned*)alloc((size_t)NB*capb2*4);
  unsigned* staging = (unsigned*)alloc((size_t)NB*((size_t)cap1r + cap2r)*4);
  if (off > ws_size) return;   // workspace insufficient -> visible validation failure

  int mt = (N + 127)/128;
  int nwv = (N + KN - 1)/KN;
  int cb = (nwv + 3)/4;

  // --- fused weight transposes + bucket-cursor init ---
  wtrans4_kernel<<<(245760 + 2*NB + 64 + 255)/256, 256, 0, stream>>>(
      W_lin1, Wt1, W_c1, Wtc1, W_c2, Wtc2, W_lin2, Wtf,
      NB, cap1r, cap2r, bcur,
      (unsigned*)(T + (size_t)N*128), (unsigned*)(T + ((size_t)ntab + N)*128));
  // h = relu(x @ W_lin1 + b): BN=256 single pass, x f32 read ONCE (fused cvt)
  gemm_kernel<4,4,2,4,1,true><<<dim3(mt, 1), 512, 0, stream>>>(
      nullptr, x, nullptr, nullptr, Wt1, b_lin1, h, N, 512, 512, 256, nullptr, nullptr, 0);

  // --- graph preprocessing: partition, then fused count/scan/scatter ---
  partA_kernel<<<dim3((E2 + PCH - 1)/PCH, 2), 256, 0, stream>>>(ei1, E1, ei2, E2, bcur, staging, NB);
  degpartB_kernel<<<dim3(NB, 2), 256, 0, stream>>>(staging, bcur, dis1, dis2, goff1, goff2,
                                                   csr1, csr2, NB, N, (unsigned)N,
                                                   cap1r, cap2r, capb1, capb2);

  // --- layer 1: T = fp8(dis_set[r] * (h @ W_c1)[r]), then one conv pass ---
  gemm_kernel<4,4,2,2,4,false><<<dim3(mt, 1), 256, 0, stream>>>(
      h, nullptr, nullptr, nullptr, Wtc1, nullptr, T, N, 256, 256, 0, dis1, dis2, ntab);
  conv_kernel<<<dim3(cb, 2), 256, 0, stream>>>(goff1, csr1, dis1, goff2, csr2, dis2,
                                               T, b_c1, R1, N, ntab);
  // --- layer 2: T = fp8(dis_set[r] * (R1 @ W_c2)[r]), conv ---
  gemm_kernel<4,4,2,2,4,false><<<dim3(mt, 1), 256, 0, stream>>>(
      R1, nullptr, nullptr, nullptr, Wtc2, nullptr, T, N, 256, 256, 0, dis1, dis2, ntab);
  conv_kernel<<<dim3(cb, 2), 256, 0, stream>>>(goff1, csr1, dis1, goff2, csr2, dis2,
                                               T, b_c2, R2, N, ntab);
  // --- head: logits = [h|R1|R2] @ W_lin2 + b, fused log_softmax ---
  gemm_kernel<2,4,4,1,2,false><<<dim3(mt, 1), 256, 0, stream>>>(
      h, nullptr, R1, R2, Wtf, b_lin2, d_out, N, 768, 256, 40, nullptr, nullptr, 0);
}